// Round 5
// baseline (1198.030 us; speedup 1.0000x reference)
//
#include <hip/hip_runtime.h>
#include <hip/hip_bf16.h>
#include <math.h>

#define B_ 8
#define T_ 12
#define N_ 500
#define D_ 64
#define K_ 20
#define M_ (B_*T_)              // 96
#define MND_ 3072000            // M_*N_*D_

// workspace layout (float offsets)
#define XS_OFF  0ul                     // 3 stages x 2 mix x MND_
#define AGG_OFF (6ul*MND_)              // 4 x MND_
#define WC_OFF  (AGG_OFF + 4ul*MND_)    // 8*2*4096
#define WD_OFF  (WC_OFF + 65536ul)
#define BC_OFF  (WD_OFF + 65536ul)      // 8*2*64
#define BD_OFF  (BC_OFF + 1024ul)
// bf16 hi/lo buffers (sized in float units; 2 ushorts per float unit)
#define AT_HI_OFF (BD_OFF + 1024ul)         // 2*512*512 ushort = 262144 f-units
#define AT_LO_OFF (AT_HI_OFF + 262144ul)
#define XT_HI_OFF (AT_LO_OFF + 262144ul)    // 2*96*64*512 ushort = 3145728 f-units
#define XT_LO_OFF (XT_HI_OFF + 3145728ul)
// end: 37,668,864 floats = 150.7 MB

using f4 = __attribute__((ext_vector_type(4))) float;
typedef __attribute__((ext_vector_type(8))) short bf16x8;
typedef __attribute__((ext_vector_type(4))) float f32x4;

__device__ inline void split_bf16(float v, ushort& h, ushort& l) {
    __hip_bfloat16 bh = __float2bfloat16(v);
    float fh = __bfloat162float(bh);
    __hip_bfloat16 bl = __float2bfloat16(v - fh);
    h = *reinterpret_cast<ushort*>(&bh);
    l = *reinterpret_cast<ushort*>(&bl);
}

// ---------------- K1: fuse head-mixture weights ----------------
__global__ __launch_bounds__(256) void fuse_weights(
        const float* __restrict__ aw, const float* __restrict__ Bw,
        const float* __restrict__ ab, const float* __restrict__ Bb,
        float* __restrict__ wc, float* __restrict__ wd,
        float* __restrict__ bc, float* __restrict__ bd) {
    int e = blockIdx.x * 256 + threadIdx.x;
    if (e < 131072) {
        int dd = e & 4095; int l = (e >> 12) & 1; int r = (e >> 13) & 7; int cd = e >> 16;
        float s = 0.f;
        #pragma unroll
        for (int h = 0; h < 4; ++h)
            s += aw[((cd*8 + r)*4 + h)*2 + l] * Bw[(h*2 + l)*4096 + dd];
        (cd ? wd : wc)[(r*2 + l)*4096 + dd] = s;
    } else {
        int e2 = e - 131072;
        if (e2 < 2048) {
            int d = e2 & 63; int l = (e2 >> 6) & 1; int r = (e2 >> 7) & 7; int cd = e2 >> 10;
            float s = 0.f;
            #pragma unroll
            for (int h = 0; h < 4; ++h)
                s += ab[((cd*8 + r)*4 + h)*2 + l] * Bb[(h*2 + l)*64 + d];
            (cd ? bd : bc)[(r*2 + l)*64 + d] = s;
        }
    }
}

// ---------------- K2: [B,D,N,T] -> [M,N,D] transpose ----------------
__global__ __launch_bounds__(256) void transpose_in(
        const float* __restrict__ x0, const float* __restrict__ x1,
        float* __restrict__ xs) {
    int bid = blockIdx.x;
    int n = bid % N_; int b = (bid / N_) % B_; int i = bid / (N_ * B_);
    const float* __restrict__ x = i ? x1 : x0;
    float* __restrict__ xo = xs + (size_t)i * MND_;
    __shared__ float tile[64][13];
    #pragma unroll
    for (int q = 0; q < 3; ++q) {
        int e = q * 256 + threadIdx.x;       // 0..767
        int d = e / 12, t = e % 12;
        tile[d][t] = x[(((size_t)b * D_ + d) * N_ + n) * T_ + t];
    }
    __syncthreads();
    #pragma unroll
    for (int q = 0; q < 3; ++q) {
        int e = q * 256 + threadIdx.x;
        int t = e >> 6, d = e & 63;
        xo[(((size_t)b * T_ + t) * N_ + n) * D_ + d] = tile[d][t];
    }
}

// ---------------- K3a: adjT bf16 hi/lo prep: AT[t][mm][n] = graphs[t][n][mm], padded 512x512 ----------------
__global__ __launch_bounds__(256) void adj_prep(
        const float* __restrict__ graphs,
        ushort* __restrict__ AT_hi, ushort* __restrict__ AT_lo) {
    int t = blockIdx.z;
    int n0 = blockIdx.x * 32, mm0 = blockIdx.y * 32;
    __shared__ float tile[32][33];
    int cc = threadIdx.x & 31, rr = threadIdx.x >> 5;   // 8 rows per iter
    #pragma unroll
    for (int it = 0; it < 4; ++it) {
        int n = n0 + it * 8 + rr, mm = mm0 + cc;
        tile[it * 8 + rr][cc] = (n < N_ && mm < N_)
            ? graphs[(size_t)t * 250000 + (size_t)n * 500 + mm] : 0.f;
    }
    __syncthreads();
    #pragma unroll
    for (int it = 0; it < 4; ++it) {
        int mml = it * 8 + rr, nl = cc;
        float v = tile[nl][mml];
        ushort h, l; split_bf16(v, h, l);
        size_t idx = (size_t)t * 262144 + (size_t)(mm0 + mml) * 512 + n0 + nl;
        AT_hi[idx] = h; AT_lo[idx] = l;
    }
}

// ---------------- K3b: X transpose-cast: XT[i][m][d][n(512)] hi/lo from xs[i][m][n][d] ----------------
__global__ __launch_bounds__(256) void xt_cast(
        const float* __restrict__ xs,
        ushort* __restrict__ XT_hi, ushort* __restrict__ XT_lo) {
    int i = blockIdx.z, m = blockIdx.y, c = blockIdx.x;  // c = n-chunk (0..7)
    int n0 = c * 64;
    __shared__ float tile[64][65];
    int d = threadIdx.x & 63, r4 = threadIdx.x >> 6;     // 4 n-rows per iter
    const float* __restrict__ src = xs + (size_t)i * MND_ + (size_t)m * 32000;
    #pragma unroll
    for (int it = 0; it < 16; ++it) {
        int nl = it * 4 + r4; int n = n0 + nl;
        tile[nl][d] = (n < N_) ? src[(size_t)n * 64 + d] : 0.f;
    }
    __syncthreads();
    size_t base = (size_t)(i * 96 + m) * 64 * 512 + n0;
    #pragma unroll
    for (int it = 0; it < 16; ++it) {
        int dl = it * 4 + r4; int nl = threadIdx.x & 63;
        float v = tile[nl][dl];
        ushort h, l; split_bf16(v, h, l);
        XT_hi[base + (size_t)dl * 512 + nl] = h;
        XT_lo[base + (size_t)dl * 512 + nl] = l;
    }
}

// ---------------- K3c: aggregation via MFMA, LDS-free ----------------
__global__ __launch_bounds__(64) void aggregate_mfma(
        const ushort* __restrict__ AT_hi, const ushort* __restrict__ AT_lo,
        const ushort* __restrict__ XT_hi, const ushort* __restrict__ XT_lo,
        float* __restrict__ agg) {
    const int cmb = blockIdx.z;          // t*2 + j
    const int t = cmb >> 1, j = cmb & 1;
    const int m = blockIdx.y;
    const int mm0 = blockIdx.x * 64;
    const int lane = threadIdx.x;
    const int lr = lane & 15;
    const int lk = (lane >> 4) * 8;

    const ushort* __restrict__ A_h = AT_hi + (size_t)t * 262144 + (size_t)(mm0 + lr) * 512 + lk;
    const ushort* __restrict__ A_l = AT_lo + (size_t)t * 262144 + (size_t)(mm0 + lr) * 512 + lk;
    const ushort* __restrict__ B_h = XT_hi + ((size_t)(j * 96 + m) * 64 + lr) * 512 + lk;
    const ushort* __restrict__ B_l = XT_lo + ((size_t)(j * 96 + m) * 64 + lr) * 512 + lk;

    f32x4 acc[4][4] = {};

    for (int k0 = 0; k0 < 512; k0 += 32) {
        bf16x8 ah[4], al[4], bh[4], bl[4];
        #pragma unroll
        for (int f = 0; f < 4; ++f) {
            ah[f] = *(const bf16x8*)(A_h + (size_t)f * 8192 + k0);   // f*16 rows * 512
            al[f] = *(const bf16x8*)(A_l + (size_t)f * 8192 + k0);
            bh[f] = *(const bf16x8*)(B_h + (size_t)f * 8192 + k0);
            bl[f] = *(const bf16x8*)(B_l + (size_t)f * 8192 + k0);
        }
        #pragma unroll
        for (int fi = 0; fi < 4; ++fi)
            #pragma unroll
            for (int fj = 0; fj < 4; ++fj)
                acc[fi][fj] = __builtin_amdgcn_mfma_f32_16x16x32_bf16(ah[fi], bh[fj], acc[fi][fj], 0, 0, 0);
        #pragma unroll
        for (int fi = 0; fi < 4; ++fi)
            #pragma unroll
            for (int fj = 0; fj < 4; ++fj)
                acc[fi][fj] = __builtin_amdgcn_mfma_f32_16x16x32_bf16(ah[fi], bl[fj], acc[fi][fj], 0, 0, 0);
        #pragma unroll
        for (int fi = 0; fi < 4; ++fi)
            #pragma unroll
            for (int fj = 0; fj < 4; ++fj)
                acc[fi][fj] = __builtin_amdgcn_mfma_f32_16x16x32_bf16(al[fi], bh[fj], acc[fi][fj], 0, 0, 0);
    }

    float* __restrict__ O = agg + (size_t)cmb * MND_ + (size_t)m * 32000;
    #pragma unroll
    for (int fi = 0; fi < 4; ++fi) {
        #pragma unroll
        for (int reg = 0; reg < 4; ++reg) {
            int row = mm0 + fi * 16 + (lane >> 4) * 4 + reg;
            if (row < N_) {
                #pragma unroll
                for (int fj = 0; fj < 4; ++fj)
                    O[(size_t)row * 64 + fj * 16 + lr] = acc[fi][fj][reg];
            }
        }
    }
}

// ---------------- K4: combine ----------------
__global__ __launch_bounds__(256) void combine(
        const float* __restrict__ agg,
        const float* __restrict__ wc, const float* __restrict__ wd,
        const float* __restrict__ bcv, const float* __restrict__ bdv,
        float* __restrict__ xs_out, int l) {
    const int i = blockIdx.y;
    const int row0 = blockIdx.x * 64;
    const int tid = threadIdx.x;
    const int ty = tid >> 4;            // row quad
    const int tx = tid & 15;            // d quad
    const int d0 = tx * 4;
    const size_t rbase = (size_t)(row0 + ty * 4) * 64;
    float hacc[4][4] = {};

    for (int t = 0; t < 2; ++t) {
        #pragma unroll
        for (int j = 0; j < 2; ++j) {
            const int rel = (t * 2 + i) * 2 + j;
            const float* __restrict__ Wc = wc + (size_t)(rel * 2 + l) * 4096 + d0;
            const float* __restrict__ Aj = agg + (size_t)(t * 2 + j) * MND_ + rbase;
            f4 cacc[4];
            {
                f4 bv = *(const f4*)&bcv[(rel * 2 + l) * 64 + d0];
                #pragma unroll
                for (int r = 0; r < 4; ++r) cacc[r] = bv;
            }
            for (int k4 = 0; k4 < 16; ++k4) {
                f4 a[4], w[4];
                #pragma unroll
                for (int r = 0; r < 4; ++r) a[r] = *(const f4*)&Aj[(size_t)r * 64 + k4 * 4];
                #pragma unroll
                for (int kk = 0; kk < 4; ++kk) w[kk] = *(const f4*)&Wc[(size_t)(k4 * 4 + kk) * 64];
                #pragma unroll
                for (int r = 0; r < 4; ++r)
                    #pragma unroll
                    for (int kk = 0; kk < 4; ++kk)
                        cacc[r] += a[r][kk] * w[kk];
            }
            #pragma unroll
            for (int r = 0; r < 4; ++r)
                #pragma unroll
                for (int dd = 0; dd < 4; ++dd)
                    hacc[r][dd] += fmaxf(cacc[r][dd], 0.f);

            if (j != i) {
                const float* __restrict__ Wd = wd + (size_t)(rel * 2 + l) * 4096 + d0;
                const float* __restrict__ Ai = agg + (size_t)(t * 2 + i) * MND_ + rbase;
                f4 dacc[4];
                f4 bv = *(const f4*)&bdv[(rel * 2 + l) * 64 + d0];
                #pragma unroll
                for (int r = 0; r < 4; ++r) dacc[r] = bv;
                for (int k4 = 0; k4 < 16; ++k4) {
                    f4 aj[4], ai[4], w[4];
                    #pragma unroll
                    for (int r = 0; r < 4; ++r) aj[r] = *(const f4*)&Aj[(size_t)r * 64 + k4 * 4];
                    #pragma unroll
                    for (int r = 0; r < 4; ++r) ai[r] = *(const f4*)&Ai[(size_t)r * 64 + k4 * 4];
                    #pragma unroll
                    for (int kk = 0; kk < 4; ++kk) w[kk] = *(const f4*)&Wd[(size_t)(k4 * 4 + kk) * 64];
                    #pragma unroll
                    for (int r = 0; r < 4; ++r) {
                        f4 df = aj[r] - ai[r];
                        #pragma unroll
                        for (int kk = 0; kk < 4; ++kk)
                            dacc[r] += df[kk] * w[kk];
                    }
                }
                #pragma unroll
                for (int r = 0; r < 4; ++r)
                    #pragma unroll
                    for (int dd = 0; dd < 4; ++dd)
                        hacc[r][dd] += tanhf(dacc[r][dd]);
            } else {
                f4 bv = *(const f4*)&bdv[(rel * 2 + l) * 64 + d0];
                float tb[4];
                #pragma unroll
                for (int dd = 0; dd < 4; ++dd) tb[dd] = tanhf(bv[dd]);
                #pragma unroll
                for (int r = 0; r < 4; ++r)
                    #pragma unroll
                    for (int dd = 0; dd < 4; ++dd)
                        hacc[r][dd] += tb[dd];
            }
        }
    }
    float* __restrict__ Ho = xs_out + (size_t)i * MND_ + rbase + d0;
    #pragma unroll
    for (int r = 0; r < 4; ++r) {
        f4 v;
        #pragma unroll
        for (int dd = 0; dd < 4; ++dd) v[dd] = hacc[r][dd];
        *(f4*)&Ho[(size_t)r * 64] = v;
    }
}

// ---------------- K5: summarize ----------------
// Proven structure (round 3/4) with higher MLP: 24-row staging (LDS ~19.8KB ->
// 8 blocks/CU cap, was 4) and 2-way accumulator split (dependent-FMA chain
// 20 -> 10). Gather loop shape, loop order, XCD swizzle, indexing unchanged.
__global__ __launch_bounds__(192) void summarize(
        const float* __restrict__ XS, const int* __restrict__ nbr,
        const float* __restrict__ nw, float* __restrict__ out) {
    // grid = 2016 = 8 XCD * 252.  work id: (i,b) outer, then t, then tile.
    int wg = (blockIdx.x & 7) * 252 + (blockIdx.x >> 3);
    int grp = wg / 126;            // 0..15 = i*8 + b
    int rem = wg % 126;            // t*63 + tile
    int i = grp >> 3, b = grp & 7;
    int t = rem / 63;
    int tile = rem % 63;
    int n0 = tile * 8;
    int tid = threadIdx.x;
    int l = tid >> 6, d = tid & 63;

    __shared__ int   nb_s[8][20];
    __shared__ float w_s[8][20];
    __shared__ float staged[24][193];   // 18.5 KB

    if (tid < 160) {
        int nn = tid / 20, k = tid % 20;
        int n = n0 + nn;
        nb_s[nn][k] = (n < N_) ? nbr[((size_t)t * N_ + n) * K_ + k] : 0;
        w_s[nn][k]  = (n < N_) ? nw[((size_t)t * N_ + n) * K_ + k] : 0.f;
    }
    __syncthreads();

    const float* __restrict__ Xbase = XS + ((size_t)l * 2 + i) * MND_ + (size_t)b * T_ * N_ * D_ + d;
    size_t obase = ((size_t)(i * 8 + b) * 384 + (size_t)t * 192) * 6000 + (size_t)n0 * 12;

    #pragma unroll
    for (int pass = 0; pass < 4; ++pass) {
        const int nnb = pass * 2;
        // p-major, tt innermost (proven order); split accumulator pair.
        for (int q = 0; q < 24; ++q) {
            int nn = nnb + q / 12, tt = q % 12;
            if (n0 + nn >= N_) break;
            const float* __restrict__ Xm = Xbase + (size_t)tt * N_ * D_;
            float acc0 = 0.f, acc1 = 0.f;
            #pragma unroll
            for (int k = 0; k < 10; ++k) {
                acc0 = fmaf(Xm[(size_t)nb_s[nn][k] * D_], w_s[nn][k], acc0);
                acc1 = fmaf(Xm[(size_t)nb_s[nn][k + 10] * D_], w_s[nn][k + 10], acc1);
            }
            staged[q][tid] = acc0 + acc1;
        }
        __syncthreads();
        int plim = (N_ - n0 - nnb) * 12;
        if (plim > 24) plim = 24;
        if (plim > 0) {
            for (int it = 0; it < 24; ++it) {
                int e = it * 192 + tid;
                int c2 = e / 24, q = e % 24;
                if (q < plim)
                    out[obase + (size_t)c2 * 6000 + (size_t)nnb * 12 + q] = staged[q][c2];
            }
        }
        __syncthreads();
    }
}

extern "C" void kernel_launch(void* const* d_in, const int* in_sizes, int n_in,
                              void* d_out, int out_size, void* d_ws, size_t ws_size,
                              hipStream_t stream) {
    const float* x0     = (const float*)d_in[0];
    const float* x1     = (const float*)d_in[1];
    const float* graphs = (const float*)d_in[2];
    const int*   nbr    = (const int*)d_in[3];
    const float* nwt    = (const float*)d_in[4];
    const float* aw     = (const float*)d_in[5];
    const float* Bw     = (const float*)d_in[6];
    const float* ab     = (const float*)d_in[7];
    const float* Bb     = (const float*)d_in[8];
    float* out = (float*)d_out;
    float* ws  = (float*)d_ws;

    float* XS  = ws + XS_OFF;
    float* AGG = ws + AGG_OFF;
    float* WC  = ws + WC_OFF;
    float* WD  = ws + WD_OFF;
    float* BC  = ws + BC_OFF;
    float* BD  = ws + BD_OFF;
    ushort* ATh = (ushort*)(ws + AT_HI_OFF);
    ushort* ATl = (ushort*)(ws + AT_LO_OFF);
    ushort* XTh = (ushort*)(ws + XT_HI_OFF);
    ushort* XTl = (ushort*)(ws + XT_LO_OFF);

    fuse_weights<<<520, 256, 0, stream>>>(aw, Bw, ab, Bb, WC, WD, BC, BD);
    transpose_in<<<8000, 256, 0, stream>>>(x0, x1, XS);
    adj_prep<<<dim3(16, 16, 2), 256, 0, stream>>>(graphs, ATh, ATl);
    for (int l = 0; l < 2; ++l) {
        xt_cast<<<dim3(8, 96, 2), 256, 0, stream>>>(XS + (size_t)l * 2 * MND_, XTh, XTl);
        aggregate_mfma<<<dim3(8, 96, 4), 64, 0, stream>>>(ATh, ATl, XTh, XTl, AGG);
        combine<<<dim3(750, 2), 256, 0, stream>>>(AGG, WC, WD, BC, BD,
                                                  XS + (size_t)(l + 1) * 2 * MND_, l);
    }
    summarize<<<2016, 192, 0, stream>>>(XS, nbr, nwt, out);
}

// Round 6
// 801.247 us; speedup vs baseline: 1.4952x; 1.4952x over previous
//
#include <hip/hip_runtime.h>
#include <hip/hip_bf16.h>
#include <math.h>

#define B_ 8
#define T_ 12
#define N_ 500
#define D_ 64
#define K_ 20
#define M_ (B_*T_)              // 96
#define MND_ 3072000            // M_*N_*D_

// workspace layout (float offsets)
#define XS_OFF  0ul                     // 3 stages x 2 mix x MND_
#define AGG_OFF (6ul*MND_)              // 4 x MND_
#define WC_OFF  (AGG_OFF + 4ul*MND_)    // 8*2*4096
#define WD_OFF  (WC_OFF + 65536ul)
#define BC_OFF  (WD_OFF + 65536ul)      // 8*2*64
#define BD_OFF  (BC_OFF + 1024ul)
// bf16 hi/lo buffers (sized in float units; 2 ushorts per float unit)
#define AT_HI_OFF (BD_OFF + 1024ul)         // 2*512*512 ushort = 262144 f-units
#define AT_LO_OFF (AT_HI_OFF + 262144ul)
#define XT_HI_OFF (AT_LO_OFF + 262144ul)    // 2*96*64*512 ushort = 3145728 f-units
#define XT_LO_OFF (XT_HI_OFF + 3145728ul)
// end: 37,668,864 floats = 150.7 MB

using f4 = __attribute__((ext_vector_type(4))) float;
typedef __attribute__((ext_vector_type(8))) short bf16x8;
typedef __attribute__((ext_vector_type(4))) float f32x4;

__device__ inline void split_bf16(float v, ushort& h, ushort& l) {
    __hip_bfloat16 bh = __float2bfloat16(v);
    float fh = __bfloat162float(bh);
    __hip_bfloat16 bl = __float2bfloat16(v - fh);
    h = *reinterpret_cast<ushort*>(&bh);
    l = *reinterpret_cast<ushort*>(&bl);
}

// fast tanh: 1 - 2/(e^{2x}+1).  v_exp_f32 + v_rcp_f32; exact at +-inf saturation.
__device__ inline float fast_tanh(float x) {
    float u = __expf(2.0f * x);
    return 1.0f - 2.0f * __builtin_amdgcn_rcpf(u + 1.0f);
}

// ---------------- K1: fuse head-mixture weights ----------------
__global__ __launch_bounds__(256) void fuse_weights(
        const float* __restrict__ aw, const float* __restrict__ Bw,
        const float* __restrict__ ab, const float* __restrict__ Bb,
        float* __restrict__ wc, float* __restrict__ wd,
        float* __restrict__ bc, float* __restrict__ bd) {
    int e = blockIdx.x * 256 + threadIdx.x;
    if (e < 131072) {
        int dd = e & 4095; int l = (e >> 12) & 1; int r = (e >> 13) & 7; int cd = e >> 16;
        float s = 0.f;
        #pragma unroll
        for (int h = 0; h < 4; ++h)
            s += aw[((cd*8 + r)*4 + h)*2 + l] * Bw[(h*2 + l)*4096 + dd];
        (cd ? wd : wc)[(r*2 + l)*4096 + dd] = s;
    } else {
        int e2 = e - 131072;
        if (e2 < 2048) {
            int d = e2 & 63; int l = (e2 >> 6) & 1; int r = (e2 >> 7) & 7; int cd = e2 >> 10;
            float s = 0.f;
            #pragma unroll
            for (int h = 0; h < 4; ++h)
                s += ab[((cd*8 + r)*4 + h)*2 + l] * Bb[(h*2 + l)*64 + d];
            (cd ? bd : bc)[(r*2 + l)*64 + d] = s;
        }
    }
}

// ---------------- K2: [B,D,N,T] -> [M,N,D] transpose ----------------
__global__ __launch_bounds__(256) void transpose_in(
        const float* __restrict__ x0, const float* __restrict__ x1,
        float* __restrict__ xs) {
    int bid = blockIdx.x;
    int n = bid % N_; int b = (bid / N_) % B_; int i = bid / (N_ * B_);
    const float* __restrict__ x = i ? x1 : x0;
    float* __restrict__ xo = xs + (size_t)i * MND_;
    __shared__ float tile[64][13];
    #pragma unroll
    for (int q = 0; q < 3; ++q) {
        int e = q * 256 + threadIdx.x;       // 0..767
        int d = e / 12, t = e % 12;
        tile[d][t] = x[(((size_t)b * D_ + d) * N_ + n) * T_ + t];
    }
    __syncthreads();
    #pragma unroll
    for (int q = 0; q < 3; ++q) {
        int e = q * 256 + threadIdx.x;
        int t = e >> 6, d = e & 63;
        xo[(((size_t)b * T_ + t) * N_ + n) * D_ + d] = tile[d][t];
    }
}

// ---------------- K3a: adjT bf16 hi/lo prep: AT[t][mm][n] = graphs[t][n][mm], padded 512x512 ----------------
__global__ __launch_bounds__(256) void adj_prep(
        const float* __restrict__ graphs,
        ushort* __restrict__ AT_hi, ushort* __restrict__ AT_lo) {
    int t = blockIdx.z;
    int n0 = blockIdx.x * 32, mm0 = blockIdx.y * 32;
    __shared__ float tile[32][33];
    int cc = threadIdx.x & 31, rr = threadIdx.x >> 5;   // 8 rows per iter
    #pragma unroll
    for (int it = 0; it < 4; ++it) {
        int n = n0 + it * 8 + rr, mm = mm0 + cc;
        tile[it * 8 + rr][cc] = (n < N_ && mm < N_)
            ? graphs[(size_t)t * 250000 + (size_t)n * 500 + mm] : 0.f;
    }
    __syncthreads();
    #pragma unroll
    for (int it = 0; it < 4; ++it) {
        int mml = it * 8 + rr, nl = cc;
        float v = tile[nl][mml];
        ushort h, l; split_bf16(v, h, l);
        size_t idx = (size_t)t * 262144 + (size_t)(mm0 + mml) * 512 + n0 + nl;
        AT_hi[idx] = h; AT_lo[idx] = l;
    }
}

// ---------------- K3b: X transpose-cast: XT[i][m][d][n(512)] hi/lo from xs[i][m][n][d] ----------------
__global__ __launch_bounds__(256) void xt_cast(
        const float* __restrict__ xs,
        ushort* __restrict__ XT_hi, ushort* __restrict__ XT_lo) {
    int i = blockIdx.z, m = blockIdx.y, c = blockIdx.x;  // c = n-chunk (0..7)
    int n0 = c * 64;
    __shared__ float tile[64][65];
    int d = threadIdx.x & 63, r4 = threadIdx.x >> 6;     // 4 n-rows per iter
    const float* __restrict__ src = xs + (size_t)i * MND_ + (size_t)m * 32000;
    #pragma unroll
    for (int it = 0; it < 16; ++it) {
        int nl = it * 4 + r4; int n = n0 + nl;
        tile[nl][d] = (n < N_) ? src[(size_t)n * 64 + d] : 0.f;
    }
    __syncthreads();
    size_t base = (size_t)(i * 96 + m) * 64 * 512 + n0;
    #pragma unroll
    for (int it = 0; it < 16; ++it) {
        int dl = it * 4 + r4; int nl = threadIdx.x & 63;
        float v = tile[nl][dl];
        ushort h, l; split_bf16(v, h, l);
        XT_hi[base + (size_t)dl * 512 + nl] = h;
        XT_lo[base + (size_t)dl * 512 + nl] = l;
    }
}

// ---------------- K3c: aggregation via MFMA, LDS-free ----------------
__global__ __launch_bounds__(64) void aggregate_mfma(
        const ushort* __restrict__ AT_hi, const ushort* __restrict__ AT_lo,
        const ushort* __restrict__ XT_hi, const ushort* __restrict__ XT_lo,
        float* __restrict__ agg) {
    const int cmb = blockIdx.z;          // t*2 + j
    const int t = cmb >> 1, j = cmb & 1;
    const int m = blockIdx.y;
    const int mm0 = blockIdx.x * 64;
    const int lane = threadIdx.x;
    const int lr = lane & 15;
    const int lk = (lane >> 4) * 8;

    const ushort* __restrict__ A_h = AT_hi + (size_t)t * 262144 + (size_t)(mm0 + lr) * 512 + lk;
    const ushort* __restrict__ A_l = AT_lo + (size_t)t * 262144 + (size_t)(mm0 + lr) * 512 + lk;
    const ushort* __restrict__ B_h = XT_hi + ((size_t)(j * 96 + m) * 64 + lr) * 512 + lk;
    const ushort* __restrict__ B_l = XT_lo + ((size_t)(j * 96 + m) * 64 + lr) * 512 + lk;

    f32x4 acc[4][4] = {};

    for (int k0 = 0; k0 < 512; k0 += 32) {
        bf16x8 ah[4], al[4], bh[4], bl[4];
        #pragma unroll
        for (int f = 0; f < 4; ++f) {
            ah[f] = *(const bf16x8*)(A_h + (size_t)f * 8192 + k0);   // f*16 rows * 512
            al[f] = *(const bf16x8*)(A_l + (size_t)f * 8192 + k0);
            bh[f] = *(const bf16x8*)(B_h + (size_t)f * 8192 + k0);
            bl[f] = *(const bf16x8*)(B_l + (size_t)f * 8192 + k0);
        }
        #pragma unroll
        for (int fi = 0; fi < 4; ++fi)
            #pragma unroll
            for (int fj = 0; fj < 4; ++fj)
                acc[fi][fj] = __builtin_amdgcn_mfma_f32_16x16x32_bf16(ah[fi], bh[fj], acc[fi][fj], 0, 0, 0);
        #pragma unroll
        for (int fi = 0; fi < 4; ++fi)
            #pragma unroll
            for (int fj = 0; fj < 4; ++fj)
                acc[fi][fj] = __builtin_amdgcn_mfma_f32_16x16x32_bf16(ah[fi], bl[fj], acc[fi][fj], 0, 0, 0);
        #pragma unroll
        for (int fi = 0; fi < 4; ++fi)
            #pragma unroll
            for (int fj = 0; fj < 4; ++fj)
                acc[fi][fj] = __builtin_amdgcn_mfma_f32_16x16x32_bf16(al[fi], bh[fj], acc[fi][fj], 0, 0, 0);
    }

    float* __restrict__ O = agg + (size_t)cmb * MND_ + (size_t)m * 32000;
    #pragma unroll
    for (int fi = 0; fi < 4; ++fi) {
        #pragma unroll
        for (int reg = 0; reg < 4; ++reg) {
            int row = mm0 + fi * 16 + (lane >> 4) * 4 + reg;
            if (row < N_) {
                #pragma unroll
                for (int fj = 0; fj < 4; ++fj)
                    O[(size_t)row * 64 + fj * 16 + lr] = acc[fi][fj][reg];
            }
        }
    }
}

// ---------------- K4: combine ----------------
__global__ __launch_bounds__(256) void combine(
        const float* __restrict__ agg,
        const float* __restrict__ wc, const float* __restrict__ wd,
        const float* __restrict__ bcv, const float* __restrict__ bdv,
        float* __restrict__ xs_out, int l) {
    const int i = blockIdx.y;
    const int row0 = blockIdx.x * 64;
    const int tid = threadIdx.x;
    const int ty = tid >> 4;            // row quad
    const int tx = tid & 15;            // d quad
    const int d0 = tx * 4;
    const size_t rbase = (size_t)(row0 + ty * 4) * 64;
    float hacc[4][4] = {};

    for (int t = 0; t < 2; ++t) {
        #pragma unroll
        for (int j = 0; j < 2; ++j) {
            const int rel = (t * 2 + i) * 2 + j;
            const float* __restrict__ Wc = wc + (size_t)(rel * 2 + l) * 4096 + d0;
            const float* __restrict__ Aj = agg + (size_t)(t * 2 + j) * MND_ + rbase;
            f4 cacc[4];
            {
                f4 bv = *(const f4*)&bcv[(rel * 2 + l) * 64 + d0];
                #pragma unroll
                for (int r = 0; r < 4; ++r) cacc[r] = bv;
            }
            for (int k4 = 0; k4 < 16; ++k4) {
                f4 a[4], w[4];
                #pragma unroll
                for (int r = 0; r < 4; ++r) a[r] = *(const f4*)&Aj[(size_t)r * 64 + k4 * 4];
                #pragma unroll
                for (int kk = 0; kk < 4; ++kk) w[kk] = *(const f4*)&Wc[(size_t)(k4 * 4 + kk) * 64];
                #pragma unroll
                for (int r = 0; r < 4; ++r)
                    #pragma unroll
                    for (int kk = 0; kk < 4; ++kk)
                        cacc[r] += a[r][kk] * w[kk];
            }
            #pragma unroll
            for (int r = 0; r < 4; ++r)
                #pragma unroll
                for (int dd = 0; dd < 4; ++dd)
                    hacc[r][dd] += fmaxf(cacc[r][dd], 0.f);

            if (j != i) {
                const float* __restrict__ Wd = wd + (size_t)(rel * 2 + l) * 4096 + d0;
                const float* __restrict__ Ai = agg + (size_t)(t * 2 + i) * MND_ + rbase;
                f4 dacc[4];
                f4 bv = *(const f4*)&bdv[(rel * 2 + l) * 64 + d0];
                #pragma unroll
                for (int r = 0; r < 4; ++r) dacc[r] = bv;
                for (int k4 = 0; k4 < 16; ++k4) {
                    f4 aj[4], ai[4], w[4];
                    #pragma unroll
                    for (int r = 0; r < 4; ++r) aj[r] = *(const f4*)&Aj[(size_t)r * 64 + k4 * 4];
                    #pragma unroll
                    for (int r = 0; r < 4; ++r) ai[r] = *(const f4*)&Ai[(size_t)r * 64 + k4 * 4];
                    #pragma unroll
                    for (int kk = 0; kk < 4; ++kk) w[kk] = *(const f4*)&Wd[(size_t)(k4 * 4 + kk) * 64];
                    #pragma unroll
                    for (int r = 0; r < 4; ++r) {
                        f4 df = aj[r] - ai[r];
                        #pragma unroll
                        for (int kk = 0; kk < 4; ++kk)
                            dacc[r] += df[kk] * w[kk];
                    }
                }
                #pragma unroll
                for (int r = 0; r < 4; ++r)
                    #pragma unroll
                    for (int dd = 0; dd < 4; ++dd)
                        hacc[r][dd] += fast_tanh(dacc[r][dd]);
            } else {
                f4 bv = *(const f4*)&bdv[(rel * 2 + l) * 64 + d0];
                float tb[4];
                #pragma unroll
                for (int dd = 0; dd < 4; ++dd) tb[dd] = fast_tanh(bv[dd]);
                #pragma unroll
                for (int r = 0; r < 4; ++r)
                    #pragma unroll
                    for (int dd = 0; dd < 4; ++dd)
                        hacc[r][dd] += tb[dd];
            }
        }
    }
    float* __restrict__ Ho = xs_out + (size_t)i * MND_ + rbase + d0;
    #pragma unroll
    for (int r = 0; r < 4; ++r) {
        f4 v;
        #pragma unroll
        for (int dd = 0; dd < 4; ++dd) v[dd] = hacc[r][dd];
        *(f4*)&Ho[(size_t)r * 64] = v;
    }
}

// ---------------- K5: summarize ----------------
// Round-4 proven structure (48-row staging, barrier-free 48-iter gather loop,
// XCD swizzle) + p-unroll-by-2: two independent 20-FMA chains -> 40 loads in
// flight per wave. No barrier/phase/flush changes.
__global__ __launch_bounds__(192) void summarize(
        const float* __restrict__ XS, const int* __restrict__ nbr,
        const float* __restrict__ nw, float* __restrict__ out) {
    // grid = 2016 = 8 XCD * 252.  work id: (i,b) outer, then t, then tile.
    int wg = (blockIdx.x & 7) * 252 + (blockIdx.x >> 3);
    int grp = wg / 126;            // 0..15 = i*8 + b
    int rem = wg % 126;            // t*63 + tile
    int i = grp >> 3, b = grp & 7;
    int t = rem / 63;
    int tile = rem % 63;
    int n0 = tile * 8;
    int tid = threadIdx.x;
    int l = tid >> 6, d = tid & 63;

    __shared__ int   nb_s[8][20];
    __shared__ float w_s[8][20];
    __shared__ float staged[48][193];   // 37.1 KB

    if (tid < 160) {
        int nn = tid / 20, k = tid % 20;
        int n = n0 + nn;
        nb_s[nn][k] = (n < N_) ? nbr[((size_t)t * N_ + n) * K_ + k] : 0;
        w_s[nn][k]  = (n < N_) ? nw[((size_t)t * N_ + n) * K_ + k] : 0.f;
    }
    __syncthreads();

    const float* __restrict__ Xbase = XS + ((size_t)l * 2 + i) * MND_ + (size_t)b * T_ * N_ * D_ + d;
    size_t obase = ((size_t)(i * 8 + b) * 384 + (size_t)t * 192) * 6000 + (size_t)n0 * 12;

    #pragma unroll
    for (int half = 0; half < 2; ++half) {
        const int nnb = half * 4;
        for (int p = 0; p < 48; p += 2) {
            int nn0 = nnb + p / 12,       tt0 = p % 12;
            int nn1 = nnb + (p + 1) / 12, tt1 = (p + 1) % 12;
            bool v0 = (n0 + nn0 < N_), v1 = (n0 + nn1 < N_);
            const float* __restrict__ Xm0 = Xbase + (size_t)tt0 * N_ * D_;
            const float* __restrict__ Xm1 = Xbase + (size_t)tt1 * N_ * D_;
            if (v0 && v1) {
                float a0 = 0.f, a1 = 0.f;
                #pragma unroll
                for (int k = 0; k < K_; ++k) {
                    a0 = fmaf(Xm0[(size_t)nb_s[nn0][k] * D_], w_s[nn0][k], a0);
                    a1 = fmaf(Xm1[(size_t)nb_s[nn1][k] * D_], w_s[nn1][k], a1);
                }
                staged[p][tid] = a0;
                staged[p + 1][tid] = a1;
            } else if (v0) {
                float a0 = 0.f;
                #pragma unroll
                for (int k = 0; k < K_; ++k)
                    a0 = fmaf(Xm0[(size_t)nb_s[nn0][k] * D_], w_s[nn0][k], a0);
                staged[p][tid] = a0;
            }
        }
        __syncthreads();
        int plim = (N_ - n0 - nnb) * 12;
        if (plim > 48) plim = 48;
        if (plim > 0) {
            for (int it = 0; it < 48; ++it) {
                int e = it * 192 + tid;
                int c2 = e / 48, q = e % 48;
                if (q < plim)
                    out[obase + (size_t)c2 * 6000 + (size_t)nnb * 12 + q] = staged[q][c2];
            }
        }
        __syncthreads();
    }
}

extern "C" void kernel_launch(void* const* d_in, const int* in_sizes, int n_in,
                              void* d_out, int out_size, void* d_ws, size_t ws_size,
                              hipStream_t stream) {
    const float* x0     = (const float*)d_in[0];
    const float* x1     = (const float*)d_in[1];
    const float* graphs = (const float*)d_in[2];
    const int*   nbr    = (const int*)d_in[3];
    const float* nwt    = (const float*)d_in[4];
    const float* aw     = (const float*)d_in[5];
    const float* Bw     = (const float*)d_in[6];
    const float* ab     = (const float*)d_in[7];
    const float* Bb     = (const float*)d_in[8];
    float* out = (float*)d_out;
    float* ws  = (float*)d_ws;

    float* XS  = ws + XS_OFF;
    float* AGG = ws + AGG_OFF;
    float* WC  = ws + WC_OFF;
    float* WD  = ws + WD_OFF;
    float* BC  = ws + BC_OFF;
    float* BD  = ws + BD_OFF;
    ushort* ATh = (ushort*)(ws + AT_HI_OFF);
    ushort* ATl = (ushort*)(ws + AT_LO_OFF);
    ushort* XTh = (ushort*)(ws + XT_HI_OFF);
    ushort* XTl = (ushort*)(ws + XT_LO_OFF);

    fuse_weights<<<520, 256, 0, stream>>>(aw, Bw, ab, Bb, WC, WD, BC, BD);
    transpose_in<<<8000, 256, 0, stream>>>(x0, x1, XS);
    adj_prep<<<dim3(16, 16, 2), 256, 0, stream>>>(graphs, ATh, ATl);
    for (int l = 0; l < 2; ++l) {
        xt_cast<<<dim3(8, 96, 2), 256, 0, stream>>>(XS + (size_t)l * 2 * MND_, XTh, XTl);
        aggregate_mfma<<<dim3(8, 96, 4), 64, 0, stream>>>(ATh, ATl, XTh, XTl, AGG);
        combine<<<dim3(750, 2), 256, 0, stream>>>(AGG, WC, WD, BC, BD,
                                                  XS + (size_t)(l + 1) * 2 * MND_, l);
    }
    summarize<<<2016, 192, 0, stream>>>(XS, nbr, nwt, out);
}

// Round 7
// 748.776 us; speedup vs baseline: 1.6000x; 1.0701x over previous
//
#include <hip/hip_runtime.h>
#include <hip/hip_bf16.h>
#include <math.h>

#define B_ 8
#define T_ 12
#define N_ 500
#define D_ 64
#define K_ 20
#define M_ (B_*T_)              // 96
#define MND_ 3072000            // M_*N_*D_

// workspace layout (float offsets)
#define XS_OFF  0ul                     // 3 stages x 2 mix x MND_
#define AGG_OFF (6ul*MND_)              // 4 x MND_
#define WC_OFF  (AGG_OFF + 4ul*MND_)    // 8*2*4096
#define WD_OFF  (WC_OFF + 65536ul)
#define BC_OFF  (WD_OFF + 65536ul)      // 8*2*64
#define BD_OFF  (BC_OFF + 1024ul)
// bf16 hi/lo buffers (sized in float units; 2 ushorts per float unit)
#define AT_HI_OFF (BD_OFF + 1024ul)         // 2*512*512 ushort = 262144 f-units
#define AT_LO_OFF (AT_HI_OFF + 262144ul)
#define XT_HI_OFF (AT_LO_OFF + 262144ul)    // 2*96*64*512 ushort = 3145728 f-units
#define XT_LO_OFF (XT_HI_OFF + 3145728ul)
// end: 37,668,864 floats = 150.7 MB

using f4 = __attribute__((ext_vector_type(4))) float;
typedef __attribute__((ext_vector_type(8))) short bf16x8;
typedef __attribute__((ext_vector_type(4))) float f32x4;

__device__ inline void split_bf16(float v, ushort& h, ushort& l) {
    __hip_bfloat16 bh = __float2bfloat16(v);
    float fh = __bfloat162float(bh);
    __hip_bfloat16 bl = __float2bfloat16(v - fh);
    h = *reinterpret_cast<ushort*>(&bh);
    l = *reinterpret_cast<ushort*>(&bl);
}

// fast tanh: 1 - 2/(e^{2x}+1).  v_exp_f32 + v_rcp_f32; exact at +-inf saturation.
__device__ inline float fast_tanh(float x) {
    float u = __expf(2.0f * x);
    return 1.0f - 2.0f * __builtin_amdgcn_rcpf(u + 1.0f);
}

// ---------------- K1: fuse head-mixture weights ----------------
__global__ __launch_bounds__(256) void fuse_weights(
        const float* __restrict__ aw, const float* __restrict__ Bw,
        const float* __restrict__ ab, const float* __restrict__ Bb,
        float* __restrict__ wc, float* __restrict__ wd,
        float* __restrict__ bc, float* __restrict__ bd) {
    int e = blockIdx.x * 256 + threadIdx.x;
    if (e < 131072) {
        int dd = e & 4095; int l = (e >> 12) & 1; int r = (e >> 13) & 7; int cd = e >> 16;
        float s = 0.f;
        #pragma unroll
        for (int h = 0; h < 4; ++h)
            s += aw[((cd*8 + r)*4 + h)*2 + l] * Bw[(h*2 + l)*4096 + dd];
        (cd ? wd : wc)[(r*2 + l)*4096 + dd] = s;
    } else {
        int e2 = e - 131072;
        if (e2 < 2048) {
            int d = e2 & 63; int l = (e2 >> 6) & 1; int r = (e2 >> 7) & 7; int cd = e2 >> 10;
            float s = 0.f;
            #pragma unroll
            for (int h = 0; h < 4; ++h)
                s += ab[((cd*8 + r)*4 + h)*2 + l] * Bb[(h*2 + l)*64 + d];
            (cd ? bd : bc)[(r*2 + l)*64 + d] = s;
        }
    }
}

// ---------------- K2: [B,D,N,T] -> [M,N,D] transpose ----------------
__global__ __launch_bounds__(256) void transpose_in(
        const float* __restrict__ x0, const float* __restrict__ x1,
        float* __restrict__ xs) {
    int bid = blockIdx.x;
    int n = bid % N_; int b = (bid / N_) % B_; int i = bid / (N_ * B_);
    const float* __restrict__ x = i ? x1 : x0;
    float* __restrict__ xo = xs + (size_t)i * MND_;
    __shared__ float tile[64][13];
    #pragma unroll
    for (int q = 0; q < 3; ++q) {
        int e = q * 256 + threadIdx.x;       // 0..767
        int d = e / 12, t = e % 12;
        tile[d][t] = x[(((size_t)b * D_ + d) * N_ + n) * T_ + t];
    }
    __syncthreads();
    #pragma unroll
    for (int q = 0; q < 3; ++q) {
        int e = q * 256 + threadIdx.x;
        int t = e >> 6, d = e & 63;
        xo[(((size_t)b * T_ + t) * N_ + n) * D_ + d] = tile[d][t];
    }
}

// ---------------- K3a: adjT bf16 hi/lo prep: AT[t][mm][n] = graphs[t][n][mm], padded 512x512 ----------------
__global__ __launch_bounds__(256) void adj_prep(
        const float* __restrict__ graphs,
        ushort* __restrict__ AT_hi, ushort* __restrict__ AT_lo) {
    int t = blockIdx.z;
    int n0 = blockIdx.x * 32, mm0 = blockIdx.y * 32;
    __shared__ float tile[32][33];
    int cc = threadIdx.x & 31, rr = threadIdx.x >> 5;   // 8 rows per iter
    #pragma unroll
    for (int it = 0; it < 4; ++it) {
        int n = n0 + it * 8 + rr, mm = mm0 + cc;
        tile[it * 8 + rr][cc] = (n < N_ && mm < N_)
            ? graphs[(size_t)t * 250000 + (size_t)n * 500 + mm] : 0.f;
    }
    __syncthreads();
    #pragma unroll
    for (int it = 0; it < 4; ++it) {
        int mml = it * 8 + rr, nl = cc;
        float v = tile[nl][mml];
        ushort h, l; split_bf16(v, h, l);
        size_t idx = (size_t)t * 262144 + (size_t)(mm0 + mml) * 512 + n0 + nl;
        AT_hi[idx] = h; AT_lo[idx] = l;
    }
}

// ---------------- K3b: X transpose-cast: XT[i][m][d][n(512)] hi/lo from xs[i][m][n][d] ----------------
__global__ __launch_bounds__(256) void xt_cast(
        const float* __restrict__ xs,
        ushort* __restrict__ XT_hi, ushort* __restrict__ XT_lo) {
    int i = blockIdx.z, m = blockIdx.y, c = blockIdx.x;  // c = n-chunk (0..7)
    int n0 = c * 64;
    __shared__ float tile[64][65];
    int d = threadIdx.x & 63, r4 = threadIdx.x >> 6;     // 4 n-rows per iter
    const float* __restrict__ src = xs + (size_t)i * MND_ + (size_t)m * 32000;
    #pragma unroll
    for (int it = 0; it < 16; ++it) {
        int nl = it * 4 + r4; int n = n0 + nl;
        tile[nl][d] = (n < N_) ? src[(size_t)n * 64 + d] : 0.f;
    }
    __syncthreads();
    size_t base = (size_t)(i * 96 + m) * 64 * 512 + n0;
    #pragma unroll
    for (int it = 0; it < 16; ++it) {
        int dl = it * 4 + r4; int nl = threadIdx.x & 63;
        float v = tile[nl][dl];
        ushort h, l; split_bf16(v, h, l);
        XT_hi[base + (size_t)dl * 512 + nl] = h;
        XT_lo[base + (size_t)dl * 512 + nl] = l;
    }
}

// ---------------- K3c: aggregation via MFMA, LDS-free ----------------
__global__ __launch_bounds__(64) void aggregate_mfma(
        const ushort* __restrict__ AT_hi, const ushort* __restrict__ AT_lo,
        const ushort* __restrict__ XT_hi, const ushort* __restrict__ XT_lo,
        float* __restrict__ agg) {
    const int cmb = blockIdx.z;          // t*2 + j
    const int t = cmb >> 1, j = cmb & 1;
    const int m = blockIdx.y;
    const int mm0 = blockIdx.x * 64;
    const int lane = threadIdx.x;
    const int lr = lane & 15;
    const int lk = (lane >> 4) * 8;

    const ushort* __restrict__ A_h = AT_hi + (size_t)t * 262144 + (size_t)(mm0 + lr) * 512 + lk;
    const ushort* __restrict__ A_l = AT_lo + (size_t)t * 262144 + (size_t)(mm0 + lr) * 512 + lk;
    const ushort* __restrict__ B_h = XT_hi + ((size_t)(j * 96 + m) * 64 + lr) * 512 + lk;
    const ushort* __restrict__ B_l = XT_lo + ((size_t)(j * 96 + m) * 64 + lr) * 512 + lk;

    f32x4 acc[4][4] = {};

    for (int k0 = 0; k0 < 512; k0 += 32) {
        bf16x8 ah[4], al[4], bh[4], bl[4];
        #pragma unroll
        for (int f = 0; f < 4; ++f) {
            ah[f] = *(const bf16x8*)(A_h + (size_t)f * 8192 + k0);   // f*16 rows * 512
            al[f] = *(const bf16x8*)(A_l + (size_t)f * 8192 + k0);
            bh[f] = *(const bf16x8*)(B_h + (size_t)f * 8192 + k0);
            bl[f] = *(const bf16x8*)(B_l + (size_t)f * 8192 + k0);
        }
        #pragma unroll
        for (int fi = 0; fi < 4; ++fi)
            #pragma unroll
            for (int fj = 0; fj < 4; ++fj)
                acc[fi][fj] = __builtin_amdgcn_mfma_f32_16x16x32_bf16(ah[fi], bh[fj], acc[fi][fj], 0, 0, 0);
        #pragma unroll
        for (int fi = 0; fi < 4; ++fi)
            #pragma unroll
            for (int fj = 0; fj < 4; ++fj)
                acc[fi][fj] = __builtin_amdgcn_mfma_f32_16x16x32_bf16(ah[fi], bl[fj], acc[fi][fj], 0, 0, 0);
        #pragma unroll
        for (int fi = 0; fi < 4; ++fi)
            #pragma unroll
            for (int fj = 0; fj < 4; ++fj)
                acc[fi][fj] = __builtin_amdgcn_mfma_f32_16x16x32_bf16(al[fi], bh[fj], acc[fi][fj], 0, 0, 0);
    }

    float* __restrict__ O = agg + (size_t)cmb * MND_ + (size_t)m * 32000;
    #pragma unroll
    for (int fi = 0; fi < 4; ++fi) {
        #pragma unroll
        for (int reg = 0; reg < 4; ++reg) {
            int row = mm0 + fi * 16 + (lane >> 4) * 4 + reg;
            if (row < N_) {
                #pragma unroll
                for (int fj = 0; fj < 4; ++fj)
                    O[(size_t)row * 64 + fj * 16 + lr] = acc[fi][fj][reg];
            }
        }
    }
}

// ---------------- K4: combine (merged c/d passes: Aj loaded once) ----------------
__global__ __launch_bounds__(256) void combine(
        const float* __restrict__ agg,
        const float* __restrict__ wc, const float* __restrict__ wd,
        const float* __restrict__ bcv, const float* __restrict__ bdv,
        float* __restrict__ xs_out, int l) {
    const int i = blockIdx.y;
    const int row0 = blockIdx.x * 64;
    const int tid = threadIdx.x;
    const int ty = tid >> 4;            // row quad
    const int tx = tid & 15;            // d quad
    const int d0 = tx * 4;
    const size_t rbase = (size_t)(row0 + ty * 4) * 64;
    float hacc[4][4] = {};

    for (int t = 0; t < 2; ++t) {
        #pragma unroll
        for (int j = 0; j < 2; ++j) {
            const int rel = (t * 2 + i) * 2 + j;
            const float* __restrict__ Wc = wc + (size_t)(rel * 2 + l) * 4096 + d0;
            const float* __restrict__ Aj = agg + (size_t)(t * 2 + j) * MND_ + rbase;
            f4 cacc[4];
            {
                f4 bv = *(const f4*)&bcv[(rel * 2 + l) * 64 + d0];
                #pragma unroll
                for (int r = 0; r < 4; ++r) cacc[r] = bv;
            }
            if (j != i) {
                const float* __restrict__ Wd = wd + (size_t)(rel * 2 + l) * 4096 + d0;
                const float* __restrict__ Ai = agg + (size_t)(t * 2 + i) * MND_ + rbase;
                f4 dacc[4];
                f4 bv = *(const f4*)&bdv[(rel * 2 + l) * 64 + d0];
                #pragma unroll
                for (int r = 0; r < 4; ++r) dacc[r] = bv;
                for (int k4 = 0; k4 < 16; ++k4) {
                    f4 aj[4], ai[4], wcv[4], wdv[4];
                    #pragma unroll
                    for (int r = 0; r < 4; ++r) aj[r] = *(const f4*)&Aj[(size_t)r * 64 + k4 * 4];
                    #pragma unroll
                    for (int r = 0; r < 4; ++r) ai[r] = *(const f4*)&Ai[(size_t)r * 64 + k4 * 4];
                    #pragma unroll
                    for (int kk = 0; kk < 4; ++kk) wcv[kk] = *(const f4*)&Wc[(size_t)(k4 * 4 + kk) * 64];
                    #pragma unroll
                    for (int kk = 0; kk < 4; ++kk) wdv[kk] = *(const f4*)&Wd[(size_t)(k4 * 4 + kk) * 64];
                    #pragma unroll
                    for (int r = 0; r < 4; ++r) {
                        f4 df = aj[r] - ai[r];
                        #pragma unroll
                        for (int kk = 0; kk < 4; ++kk) {
                            cacc[r] += aj[r][kk] * wcv[kk];
                            dacc[r] += df[kk] * wdv[kk];
                        }
                    }
                }
                #pragma unroll
                for (int r = 0; r < 4; ++r)
                    #pragma unroll
                    for (int dd = 0; dd < 4; ++dd) {
                        hacc[r][dd] += fmaxf(cacc[r][dd], 0.f);
                        hacc[r][dd] += fast_tanh(dacc[r][dd]);
                    }
            } else {
                for (int k4 = 0; k4 < 16; ++k4) {
                    f4 a[4], w[4];
                    #pragma unroll
                    for (int r = 0; r < 4; ++r) a[r] = *(const f4*)&Aj[(size_t)r * 64 + k4 * 4];
                    #pragma unroll
                    for (int kk = 0; kk < 4; ++kk) w[kk] = *(const f4*)&Wc[(size_t)(k4 * 4 + kk) * 64];
                    #pragma unroll
                    for (int r = 0; r < 4; ++r)
                        #pragma unroll
                        for (int kk = 0; kk < 4; ++kk)
                            cacc[r] += a[r][kk] * w[kk];
                }
                f4 bv = *(const f4*)&bdv[(rel * 2 + l) * 64 + d0];
                float tb[4];
                #pragma unroll
                for (int dd = 0; dd < 4; ++dd) tb[dd] = fast_tanh(bv[dd]);
                #pragma unroll
                for (int r = 0; r < 4; ++r)
                    #pragma unroll
                    for (int dd = 0; dd < 4; ++dd) {
                        hacc[r][dd] += fmaxf(cacc[r][dd], 0.f);
                        hacc[r][dd] += tb[dd];
                    }
            }
        }
    }
    float* __restrict__ Ho = xs_out + (size_t)i * MND_ + rbase + d0;
    #pragma unroll
    for (int r = 0; r < 4; ++r) {
        f4 v;
        #pragma unroll
        for (int dd = 0; dd < 4; ++dd) v[dd] = hacc[r][dd];
        *(f4*)&Ho[(size_t)r * 64] = v;
    }
}

// ---------------- K5: summarize ----------------
// Round-4 proven structure + 4-way p-unroll: 4 independent 20-FMA chains
// (80 loads in flight/wave), all sharing one nn -> one nb_s/w_s fetch feeds
// 4 gathers. Groups of 4 align with tt boundaries (4 | 12), so the validity
// guard stays wave-uniform. No barrier/phase/flush changes.
__global__ __launch_bounds__(192) void summarize(
        const float* __restrict__ XS, const int* __restrict__ nbr,
        const float* __restrict__ nw, float* __restrict__ out) {
    // grid = 2016 = 8 XCD * 252.  work id: (i,b) outer, then t, then tile.
    int wg = (blockIdx.x & 7) * 252 + (blockIdx.x >> 3);
    int grp = wg / 126;            // 0..15 = i*8 + b
    int rem = wg % 126;            // t*63 + tile
    int i = grp >> 3, b = grp & 7;
    int t = rem / 63;
    int tile = rem % 63;
    int n0 = tile * 8;
    int tid = threadIdx.x;
    int l = tid >> 6, d = tid & 63;

    __shared__ int   nb_s[8][20];
    __shared__ float w_s[8][20];
    __shared__ float staged[48][193];   // 37.1 KB

    if (tid < 160) {
        int nn = tid / 20, k = tid % 20;
        int n = n0 + nn;
        nb_s[nn][k] = (n < N_) ? nbr[((size_t)t * N_ + n) * K_ + k] : 0;
        w_s[nn][k]  = (n < N_) ? nw[((size_t)t * N_ + n) * K_ + k] : 0.f;
    }
    __syncthreads();

    const float* __restrict__ Xbase = XS + ((size_t)l * 2 + i) * MND_ + (size_t)b * T_ * N_ * D_ + d;
    size_t obase = ((size_t)(i * 8 + b) * 384 + (size_t)t * 192) * 6000 + (size_t)n0 * 12;

    #pragma unroll
    for (int half = 0; half < 2; ++half) {
        const int nnb = half * 4;
        for (int p = 0; p < 48; p += 4) {
            int nn = nnb + p / 12;           // same nn for all 4 (4 divides 12)
            int tt = p % 12;
            if (n0 + nn >= N_) break;
            const float* __restrict__ Xm0 = Xbase + (size_t)(tt + 0) * N_ * D_;
            const float* __restrict__ Xm1 = Xbase + (size_t)(tt + 1) * N_ * D_;
            const float* __restrict__ Xm2 = Xbase + (size_t)(tt + 2) * N_ * D_;
            const float* __restrict__ Xm3 = Xbase + (size_t)(tt + 3) * N_ * D_;
            float a0 = 0.f, a1 = 0.f, a2 = 0.f, a3 = 0.f;
            #pragma unroll
            for (int k = 0; k < K_; ++k) {
                size_t off = (size_t)nb_s[nn][k] * D_;
                float w = w_s[nn][k];
                a0 = fmaf(Xm0[off], w, a0);
                a1 = fmaf(Xm1[off], w, a1);
                a2 = fmaf(Xm2[off], w, a2);
                a3 = fmaf(Xm3[off], w, a3);
            }
            staged[p + 0][tid] = a0;
            staged[p + 1][tid] = a1;
            staged[p + 2][tid] = a2;
            staged[p + 3][tid] = a3;
        }
        __syncthreads();
        int plim = (N_ - n0 - nnb) * 12;
        if (plim > 48) plim = 48;
        if (plim > 0) {
            for (int it = 0; it < 48; ++it) {
                int e = it * 192 + tid;
                int c2 = e / 48, q = e % 48;
                if (q < plim)
                    out[obase + (size_t)c2 * 6000 + (size_t)nnb * 12 + q] = staged[q][c2];
            }
        }
        __syncthreads();
    }
}

extern "C" void kernel_launch(void* const* d_in, const int* in_sizes, int n_in,
                              void* d_out, int out_size, void* d_ws, size_t ws_size,
                              hipStream_t stream) {
    const float* x0     = (const float*)d_in[0];
    const float* x1     = (const float*)d_in[1];
    const float* graphs = (const float*)d_in[2];
    const int*   nbr    = (const int*)d_in[3];
    const float* nwt    = (const float*)d_in[4];
    const float* aw     = (const float*)d_in[5];
    const float* Bw     = (const float*)d_in[6];
    const float* ab     = (const float*)d_in[7];
    const float* Bb     = (const float*)d_in[8];
    float* out = (float*)d_out;
    float* ws  = (float*)d_ws;

    float* XS  = ws + XS_OFF;
    float* AGG = ws + AGG_OFF;
    float* WC  = ws + WC_OFF;
    float* WD  = ws + WD_OFF;
    float* BC  = ws + BC_OFF;
    float* BD  = ws + BD_OFF;
    ushort* ATh = (ushort*)(ws + AT_HI_OFF);
    ushort* ATl = (ushort*)(ws + AT_LO_OFF);
    ushort* XTh = (ushort*)(ws + XT_HI_OFF);
    ushort* XTl = (ushort*)(ws + XT_LO_OFF);

    fuse_weights<<<520, 256, 0, stream>>>(aw, Bw, ab, Bb, WC, WD, BC, BD);
    transpose_in<<<8000, 256, 0, stream>>>(x0, x1, XS);
    adj_prep<<<dim3(16, 16, 2), 256, 0, stream>>>(graphs, ATh, ATl);
    for (int l = 0; l < 2; ++l) {
        xt_cast<<<dim3(8, 96, 2), 256, 0, stream>>>(XS + (size_t)l * 2 * MND_, XTh, XTl);
        aggregate_mfma<<<dim3(8, 96, 4), 64, 0, stream>>>(ATh, ATl, XTh, XTl, AGG);
        combine<<<dim3(750, 2), 256, 0, stream>>>(AGG, WC, WD, BC, BD,
                                                  XS + (size_t)(l + 1) * 2 * MND_, l);
    }
    summarize<<<2016, 192, 0, stream>>>(XS, nbr, nwt, out);
}

// Round 8
// 706.586 us; speedup vs baseline: 1.6955x; 1.0597x over previous
//
#include <hip/hip_runtime.h>
#include <hip/hip_bf16.h>
#include <math.h>

#define B_ 8
#define T_ 12
#define N_ 500
#define D_ 64
#define K_ 20
#define M_ (B_*T_)              // 96
#define MND_ 3072000            // M_*N_*D_

// workspace layout (float offsets)
#define XS_OFF  0ul                     // 3 stages x 2 mix x MND_
#define AGG_OFF (6ul*MND_)              // 4 x MND_
#define WC_OFF  (AGG_OFF + 4ul*MND_)    // 8*2*4096
#define WD_OFF  (WC_OFF + 65536ul)
#define BC_OFF  (WD_OFF + 65536ul)      // 8*2*64
#define BD_OFF  (BC_OFF + 1024ul)
// bf16 hi/lo buffers (sized in float units; 2 ushorts per float unit)
#define AT_HI_OFF (BD_OFF + 1024ul)         // 2*512*512 ushort = 262144 f-units
#define AT_LO_OFF (AT_HI_OFF + 262144ul)
#define XT_HI_OFF (AT_LO_OFF + 262144ul)    // 2*96*64*512 ushort = 3145728 f-units
#define XT_LO_OFF (XT_HI_OFF + 3145728ul)
// end: 37,668,864 floats = 150.7 MB

using f4 = __attribute__((ext_vector_type(4))) float;
typedef __attribute__((ext_vector_type(8))) short bf16x8;
typedef __attribute__((ext_vector_type(8))) short short8;
typedef __attribute__((ext_vector_type(4))) float f32x4;

__device__ inline void split_bf16(float v, ushort& h, ushort& l) {
    __hip_bfloat16 bh = __float2bfloat16(v);
    float fh = __bfloat162float(bh);
    __hip_bfloat16 bl = __float2bfloat16(v - fh);
    h = *reinterpret_cast<ushort*>(&bh);
    l = *reinterpret_cast<ushort*>(&bl);
}

// fast tanh: 1 - 2/(e^{2x}+1).  v_exp_f32 + v_rcp_f32; exact at +-inf saturation.
__device__ inline float fast_tanh(float x) {
    float u = __expf(2.0f * x);
    return 1.0f - 2.0f * __builtin_amdgcn_rcpf(u + 1.0f);
}

// ---------------- K1: fuse head-mixture weights ----------------
__global__ __launch_bounds__(256) void fuse_weights(
        const float* __restrict__ aw, const float* __restrict__ Bw,
        const float* __restrict__ ab, const float* __restrict__ Bb,
        float* __restrict__ wc, float* __restrict__ wd,
        float* __restrict__ bc, float* __restrict__ bd) {
    int e = blockIdx.x * 256 + threadIdx.x;
    if (e < 131072) {
        int dd = e & 4095; int l = (e >> 12) & 1; int r = (e >> 13) & 7; int cd = e >> 16;
        float s = 0.f;
        #pragma unroll
        for (int h = 0; h < 4; ++h)
            s += aw[((cd*8 + r)*4 + h)*2 + l] * Bw[(h*2 + l)*4096 + dd];
        (cd ? wd : wc)[(r*2 + l)*4096 + dd] = s;
    } else {
        int e2 = e - 131072;
        if (e2 < 2048) {
            int d = e2 & 63; int l = (e2 >> 6) & 1; int r = (e2 >> 7) & 7; int cd = e2 >> 10;
            float s = 0.f;
            #pragma unroll
            for (int h = 0; h < 4; ++h)
                s += ab[((cd*8 + r)*4 + h)*2 + l] * Bb[(h*2 + l)*64 + d];
            (cd ? bd : bc)[(r*2 + l)*64 + d] = s;
        }
    }
}

// ---------------- K2: [B,D,N,T] -> [M,N,D] transpose ----------------
__global__ __launch_bounds__(256) void transpose_in(
        const float* __restrict__ x0, const float* __restrict__ x1,
        float* __restrict__ xs) {
    int bid = blockIdx.x;
    int n = bid % N_; int b = (bid / N_) % B_; int i = bid / (N_ * B_);
    const float* __restrict__ x = i ? x1 : x0;
    float* __restrict__ xo = xs + (size_t)i * MND_;
    __shared__ float tile[64][13];
    #pragma unroll
    for (int q = 0; q < 3; ++q) {
        int e = q * 256 + threadIdx.x;       // 0..767
        int d = e / 12, t = e % 12;
        tile[d][t] = x[(((size_t)b * D_ + d) * N_ + n) * T_ + t];
    }
    __syncthreads();
    #pragma unroll
    for (int q = 0; q < 3; ++q) {
        int e = q * 256 + threadIdx.x;
        int t = e >> 6, d = e & 63;
        xo[(((size_t)b * T_ + t) * N_ + n) * D_ + d] = tile[d][t];
    }
}

// ---------------- K3a: adjT bf16 hi/lo prep: AT[t][mm][n] = graphs[t][n][mm], padded 512x512 ----------------
__global__ __launch_bounds__(256) void adj_prep(
        const float* __restrict__ graphs,
        ushort* __restrict__ AT_hi, ushort* __restrict__ AT_lo) {
    int t = blockIdx.z;
    int n0 = blockIdx.x * 32, mm0 = blockIdx.y * 32;
    __shared__ float tile[32][33];
    int cc = threadIdx.x & 31, rr = threadIdx.x >> 5;   // 8 rows per iter
    #pragma unroll
    for (int it = 0; it < 4; ++it) {
        int n = n0 + it * 8 + rr, mm = mm0 + cc;
        tile[it * 8 + rr][cc] = (n < N_ && mm < N_)
            ? graphs[(size_t)t * 250000 + (size_t)n * 500 + mm] : 0.f;
    }
    __syncthreads();
    #pragma unroll
    for (int it = 0; it < 4; ++it) {
        int mml = it * 8 + rr, nl = cc;
        float v = tile[nl][mml];
        ushort h, l; split_bf16(v, h, l);
        size_t idx = (size_t)t * 262144 + (size_t)(mm0 + mml) * 512 + n0 + nl;
        AT_hi[idx] = h; AT_lo[idx] = l;
    }
}

// ---------------- K3b: X transpose-cast: XT[i][m][d][n(512)] hi/lo from xs[i][m][n][d] ----------------
// write phase vectorized: short8 (16B) stores, 8 consecutive n per store.
__global__ __launch_bounds__(256) void xt_cast(
        const float* __restrict__ xs,
        ushort* __restrict__ XT_hi, ushort* __restrict__ XT_lo) {
    int i = blockIdx.z, m = blockIdx.y, c = blockIdx.x;  // c = n-chunk (0..7)
    int n0 = c * 64;
    __shared__ float tile[64][65];
    int d = threadIdx.x & 63, r4 = threadIdx.x >> 6;     // 4 n-rows per iter
    const float* __restrict__ src = xs + (size_t)i * MND_ + (size_t)m * 32000;
    #pragma unroll
    for (int it = 0; it < 16; ++it) {
        int nl = it * 4 + r4; int n = n0 + nl;
        tile[nl][d] = (n < N_) ? src[(size_t)n * 64 + d] : 0.f;
    }
    __syncthreads();
    size_t base = (size_t)(i * 96 + m) * 64 * 512 + n0;
    // thread (dl, ng): dl = tid>>2, ng = tid&3; covers nl = ng*16 .. ng*16+15
    int dl = threadIdx.x >> 2, ng = threadIdx.x & 3;
    #pragma unroll
    for (int half = 0; half < 2; ++half) {
        int nlb = ng * 16 + half * 8;
        short8 hv, lv;
        #pragma unroll
        for (int q = 0; q < 8; ++q) {
            ushort h, l; split_bf16(tile[nlb + q][dl], h, l);
            hv[q] = (short)h; lv[q] = (short)l;
        }
        *(short8*)(XT_hi + base + (size_t)dl * 512 + nlb) = hv;
        *(short8*)(XT_lo + base + (size_t)dl * 512 + nlb) = lv;
    }
}

// ---------------- K3c: aggregation via MFMA, LDS-free ----------------
// XCD-bijective swizzle (3072 = 8 XCD * 384), mm0 innermost: the 8 blocks
// sharing one 256KB B panel run consecutively on ONE XCD (B fetched once per
// XCD, 8x L2 reuse); cmb outermost keeps one 1MB A tile hot per L2.
__global__ __launch_bounds__(64) void aggregate_mfma(
        const ushort* __restrict__ AT_hi, const ushort* __restrict__ AT_lo,
        const ushort* __restrict__ XT_hi, const ushort* __restrict__ XT_lo,
        float* __restrict__ agg) {
    int w = (blockIdx.x & 7) * 384 + (blockIdx.x >> 3);
    const int mm0 = (w & 7) * 64;
    int g = w >> 3;                  // 0..383
    const int m = g % 96;
    const int cmb = g / 96;          // t*2 + j
    const int t = cmb >> 1, j = cmb & 1;
    const int lane = threadIdx.x;
    const int lr = lane & 15;
    const int lk = (lane >> 4) * 8;

    const ushort* __restrict__ A_h = AT_hi + (size_t)t * 262144 + (size_t)(mm0 + lr) * 512 + lk;
    const ushort* __restrict__ A_l = AT_lo + (size_t)t * 262144 + (size_t)(mm0 + lr) * 512 + lk;
    const ushort* __restrict__ B_h = XT_hi + ((size_t)(j * 96 + m) * 64 + lr) * 512 + lk;
    const ushort* __restrict__ B_l = XT_lo + ((size_t)(j * 96 + m) * 64 + lr) * 512 + lk;

    f32x4 acc[4][4] = {};

    for (int k0 = 0; k0 < 512; k0 += 32) {
        bf16x8 ah[4], al[4], bh[4], bl[4];
        #pragma unroll
        for (int f = 0; f < 4; ++f) {
            ah[f] = *(const bf16x8*)(A_h + (size_t)f * 8192 + k0);   // f*16 rows * 512
            al[f] = *(const bf16x8*)(A_l + (size_t)f * 8192 + k0);
            bh[f] = *(const bf16x8*)(B_h + (size_t)f * 8192 + k0);
            bl[f] = *(const bf16x8*)(B_l + (size_t)f * 8192 + k0);
        }
        #pragma unroll
        for (int fi = 0; fi < 4; ++fi)
            #pragma unroll
            for (int fj = 0; fj < 4; ++fj)
                acc[fi][fj] = __builtin_amdgcn_mfma_f32_16x16x32_bf16(ah[fi], bh[fj], acc[fi][fj], 0, 0, 0);
        #pragma unroll
        for (int fi = 0; fi < 4; ++fi)
            #pragma unroll
            for (int fj = 0; fj < 4; ++fj)
                acc[fi][fj] = __builtin_amdgcn_mfma_f32_16x16x32_bf16(ah[fi], bl[fj], acc[fi][fj], 0, 0, 0);
        #pragma unroll
        for (int fi = 0; fi < 4; ++fi)
            #pragma unroll
            for (int fj = 0; fj < 4; ++fj)
                acc[fi][fj] = __builtin_amdgcn_mfma_f32_16x16x32_bf16(al[fi], bh[fj], acc[fi][fj], 0, 0, 0);
    }

    float* __restrict__ O = agg + (size_t)cmb * MND_ + (size_t)m * 32000;
    #pragma unroll
    for (int fi = 0; fi < 4; ++fi) {
        #pragma unroll
        for (int reg = 0; reg < 4; ++reg) {
            int row = mm0 + fi * 16 + (lane >> 4) * 4 + reg;
            if (row < N_) {
                #pragma unroll
                for (int fj = 0; fj < 4; ++fj)
                    O[(size_t)row * 64 + fj * 16 + lr] = acc[fi][fj][reg];
            }
        }
    }
}

// ---------------- K4: combine (merged c/d passes: Aj loaded once) ----------------
__global__ __launch_bounds__(256) void combine(
        const float* __restrict__ agg,
        const float* __restrict__ wc, const float* __restrict__ wd,
        const float* __restrict__ bcv, const float* __restrict__ bdv,
        float* __restrict__ xs_out, int l) {
    const int i = blockIdx.y;
    const int row0 = blockIdx.x * 64;
    const int tid = threadIdx.x;
    const int ty = tid >> 4;            // row quad
    const int tx = tid & 15;            // d quad
    const int d0 = tx * 4;
    const size_t rbase = (size_t)(row0 + ty * 4) * 64;
    float hacc[4][4] = {};

    for (int t = 0; t < 2; ++t) {
        #pragma unroll
        for (int j = 0; j < 2; ++j) {
            const int rel = (t * 2 + i) * 2 + j;
            const float* __restrict__ Wc = wc + (size_t)(rel * 2 + l) * 4096 + d0;
            const float* __restrict__ Aj = agg + (size_t)(t * 2 + j) * MND_ + rbase;
            f4 cacc[4];
            {
                f4 bv = *(const f4*)&bcv[(rel * 2 + l) * 64 + d0];
                #pragma unroll
                for (int r = 0; r < 4; ++r) cacc[r] = bv;
            }
            if (j != i) {
                const float* __restrict__ Wd = wd + (size_t)(rel * 2 + l) * 4096 + d0;
                const float* __restrict__ Ai = agg + (size_t)(t * 2 + i) * MND_ + rbase;
                f4 dacc[4];
                f4 bv = *(const f4*)&bdv[(rel * 2 + l) * 64 + d0];
                #pragma unroll
                for (int r = 0; r < 4; ++r) dacc[r] = bv;
                for (int k4 = 0; k4 < 16; ++k4) {
                    f4 aj[4], ai[4], wcv[4], wdv[4];
                    #pragma unroll
                    for (int r = 0; r < 4; ++r) aj[r] = *(const f4*)&Aj[(size_t)r * 64 + k4 * 4];
                    #pragma unroll
                    for (int r = 0; r < 4; ++r) ai[r] = *(const f4*)&Ai[(size_t)r * 64 + k4 * 4];
                    #pragma unroll
                    for (int kk = 0; kk < 4; ++kk) wcv[kk] = *(const f4*)&Wc[(size_t)(k4 * 4 + kk) * 64];
                    #pragma unroll
                    for (int kk = 0; kk < 4; ++kk) wdv[kk] = *(const f4*)&Wd[(size_t)(k4 * 4 + kk) * 64];
                    #pragma unroll
                    for (int r = 0; r < 4; ++r) {
                        f4 df = aj[r] - ai[r];
                        #pragma unroll
                        for (int kk = 0; kk < 4; ++kk) {
                            cacc[r] += aj[r][kk] * wcv[kk];
                            dacc[r] += df[kk] * wdv[kk];
                        }
                    }
                }
                #pragma unroll
                for (int r = 0; r < 4; ++r)
                    #pragma unroll
                    for (int dd = 0; dd < 4; ++dd) {
                        hacc[r][dd] += fmaxf(cacc[r][dd], 0.f);
                        hacc[r][dd] += fast_tanh(dacc[r][dd]);
                    }
            } else {
                for (int k4 = 0; k4 < 16; ++k4) {
                    f4 a[4], w[4];
                    #pragma unroll
                    for (int r = 0; r < 4; ++r) a[r] = *(const f4*)&Aj[(size_t)r * 64 + k4 * 4];
                    #pragma unroll
                    for (int kk = 0; kk < 4; ++kk) w[kk] = *(const f4*)&Wc[(size_t)(k4 * 4 + kk) * 64];
                    #pragma unroll
                    for (int r = 0; r < 4; ++r)
                        #pragma unroll
                        for (int kk = 0; kk < 4; ++kk)
                            cacc[r] += a[r][kk] * w[kk];
                }
                f4 bv = *(const f4*)&bdv[(rel * 2 + l) * 64 + d0];
                float tb[4];
                #pragma unroll
                for (int dd = 0; dd < 4; ++dd) tb[dd] = fast_tanh(bv[dd]);
                #pragma unroll
                for (int r = 0; r < 4; ++r)
                    #pragma unroll
                    for (int dd = 0; dd < 4; ++dd) {
                        hacc[r][dd] += fmaxf(cacc[r][dd], 0.f);
                        hacc[r][dd] += tb[dd];
                    }
            }
        }
    }
    float* __restrict__ Ho = xs_out + (size_t)i * MND_ + rbase + d0;
    #pragma unroll
    for (int r = 0; r < 4; ++r) {
        f4 v;
        #pragma unroll
        for (int dd = 0; dd < 4; ++dd) v[dd] = hacc[r][dd];
        *(f4*)&Ho[(size_t)r * 64] = v;
    }
}

// ---------------- K5: summarize (round-7 proven version) ----------------
__global__ __launch_bounds__(192) void summarize(
        const float* __restrict__ XS, const int* __restrict__ nbr,
        const float* __restrict__ nw, float* __restrict__ out) {
    // grid = 2016 = 8 XCD * 252.  work id: (i,b) outer, then t, then tile.
    int wg = (blockIdx.x & 7) * 252 + (blockIdx.x >> 3);
    int grp = wg / 126;            // 0..15 = i*8 + b
    int rem = wg % 126;            // t*63 + tile
    int i = grp >> 3, b = grp & 7;
    int t = rem / 63;
    int tile = rem % 63;
    int n0 = tile * 8;
    int tid = threadIdx.x;
    int l = tid >> 6, d = tid & 63;

    __shared__ int   nb_s[8][20];
    __shared__ float w_s[8][20];
    __shared__ float staged[48][193];   // 37.1 KB

    if (tid < 160) {
        int nn = tid / 20, k = tid % 20;
        int n = n0 + nn;
        nb_s[nn][k] = (n < N_) ? nbr[((size_t)t * N_ + n) * K_ + k] : 0;
        w_s[nn][k]  = (n < N_) ? nw[((size_t)t * N_ + n) * K_ + k] : 0.f;
    }
    __syncthreads();

    const float* __restrict__ Xbase = XS + ((size_t)l * 2 + i) * MND_ + (size_t)b * T_ * N_ * D_ + d;
    size_t obase = ((size_t)(i * 8 + b) * 384 + (size_t)t * 192) * 6000 + (size_t)n0 * 12;

    #pragma unroll
    for (int half = 0; half < 2; ++half) {
        const int nnb = half * 4;
        for (int p = 0; p < 48; p += 4) {
            int nn = nnb + p / 12;           // same nn for all 4 (4 divides 12)
            int tt = p % 12;
            if (n0 + nn >= N_) break;
            const float* __restrict__ Xm0 = Xbase + (size_t)(tt + 0) * N_ * D_;
            const float* __restrict__ Xm1 = Xbase + (size_t)(tt + 1) * N_ * D_;
            const float* __restrict__ Xm2 = Xbase + (size_t)(tt + 2) * N_ * D_;
            const float* __restrict__ Xm3 = Xbase + (size_t)(tt + 3) * N_ * D_;
            float a0 = 0.f, a1 = 0.f, a2 = 0.f, a3 = 0.f;
            #pragma unroll
            for (int k = 0; k < K_; ++k) {
                size_t off = (size_t)nb_s[nn][k] * D_;
                float w = w_s[nn][k];
                a0 = fmaf(Xm0[off], w, a0);
                a1 = fmaf(Xm1[off], w, a1);
                a2 = fmaf(Xm2[off], w, a2);
                a3 = fmaf(Xm3[off], w, a3);
            }
            staged[p + 0][tid] = a0;
            staged[p + 1][tid] = a1;
            staged[p + 2][tid] = a2;
            staged[p + 3][tid] = a3;
        }
        __syncthreads();
        int plim = (N_ - n0 - nnb) * 12;
        if (plim > 48) plim = 48;
        if (plim > 0) {
            for (int it = 0; it < 48; ++it) {
                int e = it * 192 + tid;
                int c2 = e / 48, q = e % 48;
                if (q < plim)
                    out[obase + (size_t)c2 * 6000 + (size_t)nnb * 12 + q] = staged[q][c2];
            }
        }
        __syncthreads();
    }
}

extern "C" void kernel_launch(void* const* d_in, const int* in_sizes, int n_in,
                              void* d_out, int out_size, void* d_ws, size_t ws_size,
                              hipStream_t stream) {
    const float* x0     = (const float*)d_in[0];
    const float* x1     = (const float*)d_in[1];
    const float* graphs = (const float*)d_in[2];
    const int*   nbr    = (const int*)d_in[3];
    const float* nwt    = (const float*)d_in[4];
    const float* aw     = (const float*)d_in[5];
    const float* Bw     = (const float*)d_in[6];
    const float* ab     = (const float*)d_in[7];
    const float* Bb     = (const float*)d_in[8];
    float* out = (float*)d_out;
    float* ws  = (float*)d_ws;

    float* XS  = ws + XS_OFF;
    float* AGG = ws + AGG_OFF;
    float* WC  = ws + WC_OFF;
    float* WD  = ws + WD_OFF;
    float* BC  = ws + BC_OFF;
    float* BD  = ws + BD_OFF;
    ushort* ATh = (ushort*)(ws + AT_HI_OFF);
    ushort* ATl = (ushort*)(ws + AT_LO_OFF);
    ushort* XTh = (ushort*)(ws + XT_HI_OFF);
    ushort* XTl = (ushort*)(ws + XT_LO_OFF);

    fuse_weights<<<520, 256, 0, stream>>>(aw, Bw, ab, Bb, WC, WD, BC, BD);
    transpose_in<<<8000, 256, 0, stream>>>(x0, x1, XS);
    adj_prep<<<dim3(16, 16, 2), 256, 0, stream>>>(graphs, ATh, ATl);
    for (int l = 0; l < 2; ++l) {
        xt_cast<<<dim3(8, 96, 2), 256, 0, stream>>>(XS + (size_t)l * 2 * MND_, XTh, XTl);
        aggregate_mfma<<<3072, 64, 0, stream>>>(ATh, ATl, XTh, XTl, AGG);
        combine<<<dim3(750, 2), 256, 0, stream>>>(AGG, WC, WD, BC, BD,
                                                  XS + (size_t)(l + 1) * 2 * MND_, l);
    }
    summarize<<<2016, 192, 0, stream>>>(XS, nbr, nwt, out);
}

// Round 9
// 686.892 us; speedup vs baseline: 1.7441x; 1.0287x over previous
//
#include <hip/hip_runtime.h>
#include <hip/hip_bf16.h>
#include <math.h>

#define B_ 8
#define T_ 12
#define N_ 500
#define D_ 64
#define K_ 20
#define M_ (B_*T_)              // 96
#define MND_ 3072000            // M_*N_*D_

// workspace layout (float offsets)
#define XS_OFF  0ul                     // 3 stages x 2 mix x MND_
#define AGG_OFF (6ul*MND_)              // 4 x MND_ (reused as XSB bf16 after combine l=1)
#define WC_OFF  (AGG_OFF + 4ul*MND_)    // 8*2*4096
#define WD_OFF  (WC_OFF + 65536ul)
#define BC_OFF  (WD_OFF + 65536ul)      // 8*2*64
#define BD_OFF  (BC_OFF + 1024ul)
// bf16 hi/lo buffers (sized in float units; 2 ushorts per float unit)
#define AT_HI_OFF (BD_OFF + 1024ul)         // 2*512*512 ushort = 262144 f-units
#define AT_LO_OFF (AT_HI_OFF + 262144ul)
#define XT_HI_OFF (AT_LO_OFF + 262144ul)    // 2*96*64*512 ushort = 3145728 f-units
#define XT_LO_OFF (XT_HI_OFF + 3145728ul)
// end: 37,668,864 floats = 150.7 MB

using f4 = __attribute__((ext_vector_type(4))) float;
typedef __attribute__((ext_vector_type(8))) short bf16x8;
typedef __attribute__((ext_vector_type(8))) short short8;
typedef __attribute__((ext_vector_type(4))) float f32x4;
typedef __attribute__((ext_vector_type(4))) unsigned short us4;

__device__ inline void split_bf16(float v, ushort& h, ushort& l) {
    __hip_bfloat16 bh = __float2bfloat16(v);
    float fh = __bfloat162float(bh);
    __hip_bfloat16 bl = __float2bfloat16(v - fh);
    h = *reinterpret_cast<ushort*>(&bh);
    l = *reinterpret_cast<ushort*>(&bl);
}

// fast tanh: 1 - 2/(e^{2x}+1).  v_exp_f32 + v_rcp_f32; exact at +-inf saturation.
__device__ inline float fast_tanh(float x) {
    float u = __expf(2.0f * x);
    return 1.0f - 2.0f * __builtin_amdgcn_rcpf(u + 1.0f);
}

// ---------------- K1: fuse head-mixture weights ----------------
__global__ __launch_bounds__(256) void fuse_weights(
        const float* __restrict__ aw, const float* __restrict__ Bw,
        const float* __restrict__ ab, const float* __restrict__ Bb,
        float* __restrict__ wc, float* __restrict__ wd,
        float* __restrict__ bc, float* __restrict__ bd) {
    int e = blockIdx.x * 256 + threadIdx.x;
    if (e < 131072) {
        int dd = e & 4095; int l = (e >> 12) & 1; int r = (e >> 13) & 7; int cd = e >> 16;
        float s = 0.f;
        #pragma unroll
        for (int h = 0; h < 4; ++h)
            s += aw[((cd*8 + r)*4 + h)*2 + l] * Bw[(h*2 + l)*4096 + dd];
        (cd ? wd : wc)[(r*2 + l)*4096 + dd] = s;
    } else {
        int e2 = e - 131072;
        if (e2 < 2048) {
            int d = e2 & 63; int l = (e2 >> 6) & 1; int r = (e2 >> 7) & 7; int cd = e2 >> 10;
            float s = 0.f;
            #pragma unroll
            for (int h = 0; h < 4; ++h)
                s += ab[((cd*8 + r)*4 + h)*2 + l] * Bb[(h*2 + l)*64 + d];
            (cd ? bd : bc)[(r*2 + l)*64 + d] = s;
        }
    }
}

// ---------------- K2: [B,D,N,T] -> [M,N,D] transpose ----------------
__global__ __launch_bounds__(256) void transpose_in(
        const float* __restrict__ x0, const float* __restrict__ x1,
        float* __restrict__ xs) {
    int bid = blockIdx.x;
    int n = bid % N_; int b = (bid / N_) % B_; int i = bid / (N_ * B_);
    const float* __restrict__ x = i ? x1 : x0;
    float* __restrict__ xo = xs + (size_t)i * MND_;
    __shared__ float tile[64][13];
    #pragma unroll
    for (int q = 0; q < 3; ++q) {
        int e = q * 256 + threadIdx.x;       // 0..767
        int d = e / 12, t = e % 12;
        tile[d][t] = x[(((size_t)b * D_ + d) * N_ + n) * T_ + t];
    }
    __syncthreads();
    #pragma unroll
    for (int q = 0; q < 3; ++q) {
        int e = q * 256 + threadIdx.x;
        int t = e >> 6, d = e & 63;
        xo[(((size_t)b * T_ + t) * N_ + n) * D_ + d] = tile[d][t];
    }
}

// ---------------- K3a: adjT bf16 hi/lo prep ----------------
__global__ __launch_bounds__(256) void adj_prep(
        const float* __restrict__ graphs,
        ushort* __restrict__ AT_hi, ushort* __restrict__ AT_lo) {
    int t = blockIdx.z;
    int n0 = blockIdx.x * 32, mm0 = blockIdx.y * 32;
    __shared__ float tile[32][33];
    int cc = threadIdx.x & 31, rr = threadIdx.x >> 5;   // 8 rows per iter
    #pragma unroll
    for (int it = 0; it < 4; ++it) {
        int n = n0 + it * 8 + rr, mm = mm0 + cc;
        tile[it * 8 + rr][cc] = (n < N_ && mm < N_)
            ? graphs[(size_t)t * 250000 + (size_t)n * 500 + mm] : 0.f;
    }
    __syncthreads();
    #pragma unroll
    for (int it = 0; it < 4; ++it) {
        int mml = it * 8 + rr, nl = cc;
        float v = tile[nl][mml];
        ushort h, l; split_bf16(v, h, l);
        size_t idx = (size_t)t * 262144 + (size_t)(mm0 + mml) * 512 + n0 + nl;
        AT_hi[idx] = h; AT_lo[idx] = l;
    }
}

// ---------------- K3b: X transpose-cast (short8 vector stores) ----------------
__global__ __launch_bounds__(256) void xt_cast(
        const float* __restrict__ xs,
        ushort* __restrict__ XT_hi, ushort* __restrict__ XT_lo) {
    int i = blockIdx.z, m = blockIdx.y, c = blockIdx.x;  // c = n-chunk (0..7)
    int n0 = c * 64;
    __shared__ float tile[64][65];
    int d = threadIdx.x & 63, r4 = threadIdx.x >> 6;     // 4 n-rows per iter
    const float* __restrict__ src = xs + (size_t)i * MND_ + (size_t)m * 32000;
    #pragma unroll
    for (int it = 0; it < 16; ++it) {
        int nl = it * 4 + r4; int n = n0 + nl;
        tile[nl][d] = (n < N_) ? src[(size_t)n * 64 + d] : 0.f;
    }
    __syncthreads();
    size_t base = (size_t)(i * 96 + m) * 64 * 512 + n0;
    int dl = threadIdx.x >> 2, ng = threadIdx.x & 3;
    #pragma unroll
    for (int half = 0; half < 2; ++half) {
        int nlb = ng * 16 + half * 8;
        short8 hv, lv;
        #pragma unroll
        for (int q = 0; q < 8; ++q) {
            ushort h, l; split_bf16(tile[nlb + q][dl], h, l);
            hv[q] = (short)h; lv[q] = (short)l;
        }
        *(short8*)(XT_hi + base + (size_t)dl * 512 + nlb) = hv;
        *(short8*)(XT_lo + base + (size_t)dl * 512 + nlb) = lv;
    }
}

// ---------------- K3c: aggregation via MFMA, LDS-free (round-8 proven) ----------------
__global__ __launch_bounds__(64) void aggregate_mfma(
        const ushort* __restrict__ AT_hi, const ushort* __restrict__ AT_lo,
        const ushort* __restrict__ XT_hi, const ushort* __restrict__ XT_lo,
        float* __restrict__ agg) {
    int w = (blockIdx.x & 7) * 384 + (blockIdx.x >> 3);
    const int mm0 = (w & 7) * 64;
    int g = w >> 3;                  // 0..383
    const int m = g % 96;
    const int cmb = g / 96;          // t*2 + j
    const int t = cmb >> 1, j = cmb & 1;
    const int lane = threadIdx.x;
    const int lr = lane & 15;
    const int lk = (lane >> 4) * 8;

    const ushort* __restrict__ A_h = AT_hi + (size_t)t * 262144 + (size_t)(mm0 + lr) * 512 + lk;
    const ushort* __restrict__ A_l = AT_lo + (size_t)t * 262144 + (size_t)(mm0 + lr) * 512 + lk;
    const ushort* __restrict__ B_h = XT_hi + ((size_t)(j * 96 + m) * 64 + lr) * 512 + lk;
    const ushort* __restrict__ B_l = XT_lo + ((size_t)(j * 96 + m) * 64 + lr) * 512 + lk;

    f32x4 acc[4][4] = {};

    for (int k0 = 0; k0 < 512; k0 += 32) {
        bf16x8 ah[4], al[4], bh[4], bl[4];
        #pragma unroll
        for (int f = 0; f < 4; ++f) {
            ah[f] = *(const bf16x8*)(A_h + (size_t)f * 8192 + k0);
            al[f] = *(const bf16x8*)(A_l + (size_t)f * 8192 + k0);
            bh[f] = *(const bf16x8*)(B_h + (size_t)f * 8192 + k0);
            bl[f] = *(const bf16x8*)(B_l + (size_t)f * 8192 + k0);
        }
        #pragma unroll
        for (int fi = 0; fi < 4; ++fi)
            #pragma unroll
            for (int fj = 0; fj < 4; ++fj)
                acc[fi][fj] = __builtin_amdgcn_mfma_f32_16x16x32_bf16(ah[fi], bh[fj], acc[fi][fj], 0, 0, 0);
        #pragma unroll
        for (int fi = 0; fi < 4; ++fi)
            #pragma unroll
            for (int fj = 0; fj < 4; ++fj)
                acc[fi][fj] = __builtin_amdgcn_mfma_f32_16x16x32_bf16(ah[fi], bl[fj], acc[fi][fj], 0, 0, 0);
        #pragma unroll
        for (int fi = 0; fi < 4; ++fi)
            #pragma unroll
            for (int fj = 0; fj < 4; ++fj)
                acc[fi][fj] = __builtin_amdgcn_mfma_f32_16x16x32_bf16(al[fi], bh[fj], acc[fi][fj], 0, 0, 0);
    }

    float* __restrict__ O = agg + (size_t)cmb * MND_ + (size_t)m * 32000;
    #pragma unroll
    for (int fi = 0; fi < 4; ++fi) {
        #pragma unroll
        for (int reg = 0; reg < 4; ++reg) {
            int row = mm0 + fi * 16 + (lane >> 4) * 4 + reg;
            if (row < N_) {
                #pragma unroll
                for (int fj = 0; fj < 4; ++fj)
                    O[(size_t)row * 64 + fj * 16 + lr] = acc[fi][fj][reg];
            }
        }
    }
}

// ---------------- K4: combine (round-8 proven) ----------------
__global__ __launch_bounds__(256) void combine(
        const float* __restrict__ agg,
        const float* __restrict__ wc, const float* __restrict__ wd,
        const float* __restrict__ bcv, const float* __restrict__ bdv,
        float* __restrict__ xs_out, int l) {
    const int i = blockIdx.y;
    const int row0 = blockIdx.x * 64;
    const int tid = threadIdx.x;
    const int ty = tid >> 4;
    const int tx = tid & 15;
    const int d0 = tx * 4;
    const size_t rbase = (size_t)(row0 + ty * 4) * 64;
    float hacc[4][4] = {};

    for (int t = 0; t < 2; ++t) {
        #pragma unroll
        for (int j = 0; j < 2; ++j) {
            const int rel = (t * 2 + i) * 2 + j;
            const float* __restrict__ Wc = wc + (size_t)(rel * 2 + l) * 4096 + d0;
            const float* __restrict__ Aj = agg + (size_t)(t * 2 + j) * MND_ + rbase;
            f4 cacc[4];
            {
                f4 bv = *(const f4*)&bcv[(rel * 2 + l) * 64 + d0];
                #pragma unroll
                for (int r = 0; r < 4; ++r) cacc[r] = bv;
            }
            if (j != i) {
                const float* __restrict__ Wd = wd + (size_t)(rel * 2 + l) * 4096 + d0;
                const float* __restrict__ Ai = agg + (size_t)(t * 2 + i) * MND_ + rbase;
                f4 dacc[4];
                f4 bv = *(const f4*)&bdv[(rel * 2 + l) * 64 + d0];
                #pragma unroll
                for (int r = 0; r < 4; ++r) dacc[r] = bv;
                for (int k4 = 0; k4 < 16; ++k4) {
                    f4 aj[4], ai[4], wcv[4], wdv[4];
                    #pragma unroll
                    for (int r = 0; r < 4; ++r) aj[r] = *(const f4*)&Aj[(size_t)r * 64 + k4 * 4];
                    #pragma unroll
                    for (int r = 0; r < 4; ++r) ai[r] = *(const f4*)&Ai[(size_t)r * 64 + k4 * 4];
                    #pragma unroll
                    for (int kk = 0; kk < 4; ++kk) wcv[kk] = *(const f4*)&Wc[(size_t)(k4 * 4 + kk) * 64];
                    #pragma unroll
                    for (int kk = 0; kk < 4; ++kk) wdv[kk] = *(const f4*)&Wd[(size_t)(k4 * 4 + kk) * 64];
                    #pragma unroll
                    for (int r = 0; r < 4; ++r) {
                        f4 df = aj[r] - ai[r];
                        #pragma unroll
                        for (int kk = 0; kk < 4; ++kk) {
                            cacc[r] += aj[r][kk] * wcv[kk];
                            dacc[r] += df[kk] * wdv[kk];
                        }
                    }
                }
                #pragma unroll
                for (int r = 0; r < 4; ++r)
                    #pragma unroll
                    for (int dd = 0; dd < 4; ++dd) {
                        hacc[r][dd] += fmaxf(cacc[r][dd], 0.f);
                        hacc[r][dd] += fast_tanh(dacc[r][dd]);
                    }
            } else {
                for (int k4 = 0; k4 < 16; ++k4) {
                    f4 a[4], w[4];
                    #pragma unroll
                    for (int r = 0; r < 4; ++r) a[r] = *(const f4*)&Aj[(size_t)r * 64 + k4 * 4];
                    #pragma unroll
                    for (int kk = 0; kk < 4; ++kk) w[kk] = *(const f4*)&Wc[(size_t)(k4 * 4 + kk) * 64];
                    #pragma unroll
                    for (int r = 0; r < 4; ++r)
                        #pragma unroll
                        for (int kk = 0; kk < 4; ++kk)
                            cacc[r] += a[r][kk] * w[kk];
                }
                f4 bv = *(const f4*)&bdv[(rel * 2 + l) * 64 + d0];
                float tb[4];
                #pragma unroll
                for (int dd = 0; dd < 4; ++dd) tb[dd] = fast_tanh(bv[dd]);
                #pragma unroll
                for (int r = 0; r < 4; ++r)
                    #pragma unroll
                    for (int dd = 0; dd < 4; ++dd) {
                        hacc[r][dd] += fmaxf(cacc[r][dd], 0.f);
                        hacc[r][dd] += tb[dd];
                    }
            }
        }
    }
    float* __restrict__ Ho = xs_out + (size_t)i * MND_ + rbase + d0;
    #pragma unroll
    for (int r = 0; r < 4; ++r) {
        f4 v;
        #pragma unroll
        for (int dd = 0; dd < 4; ++dd) v[dd] = hacc[r][dd];
        *(f4*)&Ho[(size_t)r * 64] = v;
    }
}

// ---------------- K4b: cast all 6 XS slices to bf16 (for summarize gather) ----------------
// 6*MND = 18,432,000 elems; 4 per thread; grid 18000 x 256 exact.
__global__ __launch_bounds__(256) void xs_to_bf16(
        const float* __restrict__ xs, ushort* __restrict__ xsb) {
    size_t idx = ((size_t)blockIdx.x * 256 + threadIdx.x) * 4;
    f4 v = *(const f4*)(xs + idx);
    us4 o;
    #pragma unroll
    for (int q = 0; q < 4; ++q) {
        __hip_bfloat16 bv = __float2bfloat16(v[q]);
        o[q] = *reinterpret_cast<ushort*>(&bv);
    }
    *(us4*)(xsb + idx) = o;
}

// ---------------- K5: summarize (bf16 gather + stage-split work units) ----------------
// Block = one (i, b, stage l, graph t, 24-node tile); 192 threads = 3 waves,
// wave `sub` owns 4 nodes per half. Proven inner shape kept: 4 independent
// 20-FMA chains sharing one nb/w fetch; 2 barrier-pairs total.
// l-major work order per (i,b) group -> resident blocks span <1 stage slice
// (~0.77MB bf16) => L2-resident, no thrash. staged[ch][p] layout:
// write stride 145 (bank-conflict-free), flush reads stride-1 576B runs.
__global__ __launch_bounds__(192) void summarize(
        const ushort* __restrict__ XSB, const int* __restrict__ nbr,
        const float* __restrict__ nw, float* __restrict__ out) {
    // grid = 2016 = 8 XCD * 252
    int wg = (blockIdx.x & 7) * 252 + (blockIdx.x >> 3);
    int grp = wg / 126;            // 0..15 = i*8+b
    int rem = wg % 126;            // l*42 + t*21 + tile
    int i = grp >> 3, b = grp & 7;
    int l = rem / 42;
    int rem2 = rem % 42;
    int t = rem2 / 21;
    int tile = rem2 % 21;
    int n0 = tile * 24;
    int tid = threadIdx.x;
    int sub = tid >> 6;            // wave 0..2
    int d = tid & 63;

    __shared__ int   nb_s[24][20];
    __shared__ float w_s[24][20];
    __shared__ float staged[64][145];   // 37.1 KB, [channel][p]

    for (int e = tid; e < 480; e += 192) {
        int nn = e / 20, k = e % 20;
        int n = n0 + nn;
        nb_s[nn][k] = (n < N_) ? nbr[((size_t)t * N_ + n) * K_ + k] : 0;
        w_s[nn][k]  = (n < N_) ? nw[((size_t)t * N_ + n) * K_ + k] : 0.f;
    }
    __syncthreads();

    const ushort* __restrict__ Xbase = XSB + ((size_t)l * 2 + i) * MND_
                                     + (size_t)b * T_ * N_ * D_ + d;
    size_t obase = ((size_t)((i * 8 + b) * 384 + t * 192 + l * 64)) * 6000
                 + (size_t)n0 * 12;

    #pragma unroll
    for (int half = 0; half < 2; ++half) {
        // compute: wave sub handles block-nodes half*12 + sub*4 + (0..3)
        #pragma unroll
        for (int nn2 = 0; nn2 < 4; ++nn2) {
            int pl = sub * 4 + nn2;            // in-half node index 0..11
            int nl = half * 12 + pl;           // block-local node
            #pragma unroll
            for (int tt0 = 0; tt0 < 12; tt0 += 4) {
                const ushort* __restrict__ Xm0 = Xbase + (size_t)(tt0 + 0) * N_ * D_;
                const ushort* __restrict__ Xm1 = Xbase + (size_t)(tt0 + 1) * N_ * D_;
                const ushort* __restrict__ Xm2 = Xbase + (size_t)(tt0 + 2) * N_ * D_;
                const ushort* __restrict__ Xm3 = Xbase + (size_t)(tt0 + 3) * N_ * D_;
                float a0 = 0.f, a1 = 0.f, a2 = 0.f, a3 = 0.f;
                #pragma unroll
                for (int k = 0; k < K_; ++k) {
                    size_t off = (size_t)nb_s[nl][k] * D_;
                    float w = w_s[nl][k];
                    a0 = fmaf(__uint_as_float((uint)Xm0[off] << 16), w, a0);
                    a1 = fmaf(__uint_as_float((uint)Xm1[off] << 16), w, a1);
                    a2 = fmaf(__uint_as_float((uint)Xm2[off] << 16), w, a2);
                    a3 = fmaf(__uint_as_float((uint)Xm3[off] << 16), w, a3);
                }
                staged[d][pl * 12 + tt0 + 0] = a0;
                staged[d][pl * 12 + tt0 + 1] = a1;
                staged[d][pl * 12 + tt0 + 2] = a2;
                staged[d][pl * 12 + tt0 + 3] = a3;
            }
        }
        __syncthreads();
        // flush: 64 ch x 144 q; out runs of 144 floats per channel
        int base_n = n0 + half * 12;
        int plim = (N_ - base_n) * 12;
        if (plim > 144) plim = 144;
        if (plim > 0) {
            for (int it = 0; it < 48; ++it) {
                int e = it * 192 + tid;
                int c2 = e / 144, q = e % 144;
                if (q < plim)
                    out[obase + (size_t)c2 * 6000 + (size_t)half * 144 + q] = staged[c2][q];
            }
        }
        __syncthreads();
    }
}

extern "C" void kernel_launch(void* const* d_in, const int* in_sizes, int n_in,
                              void* d_out, int out_size, void* d_ws, size_t ws_size,
                              hipStream_t stream) {
    const float* x0     = (const float*)d_in[0];
    const float* x1     = (const float*)d_in[1];
    const float* graphs = (const float*)d_in[2];
    const int*   nbr    = (const int*)d_in[3];
    const float* nwt    = (const float*)d_in[4];
    const float* aw     = (const float*)d_in[5];
    const float* Bw     = (const float*)d_in[6];
    const float* ab     = (const float*)d_in[7];
    const float* Bb     = (const float*)d_in[8];
    float* out = (float*)d_out;
    float* ws  = (float*)d_ws;

    float* XS  = ws + XS_OFF;
    float* AGG = ws + AGG_OFF;
    float* WC  = ws + WC_OFF;
    float* WD  = ws + WD_OFF;
    float* BC  = ws + BC_OFF;
    float* BD  = ws + BD_OFF;
    ushort* ATh = (ushort*)(ws + AT_HI_OFF);
    ushort* ATl = (ushort*)(ws + AT_LO_OFF);
    ushort* XTh = (ushort*)(ws + XT_HI_OFF);
    ushort* XTl = (ushort*)(ws + XT_LO_OFF);
    ushort* XSB = (ushort*)AGG;   // AGG dead after combine l=1; 37MB <= 49MB

    fuse_weights<<<520, 256, 0, stream>>>(aw, Bw, ab, Bb, WC, WD, BC, BD);
    transpose_in<<<8000, 256, 0, stream>>>(x0, x1, XS);
    adj_prep<<<dim3(16, 16, 2), 256, 0, stream>>>(graphs, ATh, ATl);
    for (int l = 0; l < 2; ++l) {
        xt_cast<<<dim3(8, 96, 2), 256, 0, stream>>>(XS + (size_t)l * 2 * MND_, XTh, XTl);
        aggregate_mfma<<<3072, 64, 0, stream>>>(ATh, ATl, XTh, XTl, AGG);
        combine<<<dim3(750, 2), 256, 0, stream>>>(AGG, WC, WD, BC, BD,
                                                  XS + (size_t)(l + 1) * 2 * MND_, l);
    }
    xs_to_bf16<<<18000, 256, 0, stream>>>(XS, XSB);
    summarize<<<2016, 192, 0, stream>>>(XSB, nbr, nwt, out);
}

// Round 10
// 530.158 us; speedup vs baseline: 2.2598x; 1.2956x over previous
//
#include <hip/hip_runtime.h>
#include <hip/hip_bf16.h>
#include <math.h>

#define B_ 8
#define T_ 12
#define N_ 500
#define D_ 64
#define K_ 20
#define M_ (B_*T_)              // 96
#define MND_ 3072000            // M_*N_*D_

// workspace layout (float offsets)
#define XS_OFF  0ul                     // 3 stages x 2 mix x MND_
#define AGG_OFF (6ul*MND_)              // agg bf16 hi (4*MND ushort = 2*MND f) + lo (2*MND f); reused as XSB after layers
#define AGL_OFF (AGG_OFF + 2ul*MND_)
#define WC_OFF  (AGG_OFF + 4ul*MND_)    // 8*2*4096 fp32 (legacy, unused by compute now)
#define WD_OFF  (WC_OFF + 65536ul)
#define BC_OFF  (WD_OFF + 65536ul)      // 8*2*64
#define BD_OFF  (BC_OFF + 1024ul)
// bf16 hi/lo buffers (sized in float units; 2 ushorts per float unit)
#define AT_HI_OFF (BD_OFF + 1024ul)         // 2*512*512 ushort = 262144 f-units
#define AT_LO_OFF (AT_HI_OFF + 262144ul)
#define XT_HI_OFF (AT_LO_OFF + 262144ul)    // 2*96*64*512 ushort = 3145728 f-units
#define XT_LO_OFF (XT_HI_OFF + 3145728ul)
#define WCT_OFF (XT_LO_OFF + 3145728ul)     // 16*4096 bf16 = 32768 f-units
#define WDT_OFF (WCT_OFF + 32768ul)
// end: ~150.9 MB

using f4 = __attribute__((ext_vector_type(4))) float;
typedef __attribute__((ext_vector_type(8))) short bf16x8;
typedef __attribute__((ext_vector_type(8))) short short8;
typedef __attribute__((ext_vector_type(4))) float f32x4;
typedef __attribute__((ext_vector_type(4))) unsigned short us4;

__device__ inline void split_bf16(float v, ushort& h, ushort& l) {
    __hip_bfloat16 bh = __float2bfloat16(v);
    float fh = __bfloat162float(bh);
    __hip_bfloat16 bl = __float2bfloat16(v - fh);
    h = *reinterpret_cast<ushort*>(&bh);
    l = *reinterpret_cast<ushort*>(&bl);
}
__device__ inline ushort to_bf16u(float v) {
    __hip_bfloat16 b = __float2bfloat16(v);
    return *reinterpret_cast<ushort*>(&b);
}

// fast tanh: 1 - 2/(e^{2x}+1)
__device__ inline float fast_tanh(float x) {
    float u = __expf(2.0f * x);
    return 1.0f - 2.0f * __builtin_amdgcn_rcpf(u + 1.0f);
}

// ---------------- K1: fuse head-mixture weights (+ transposed bf16 copies) ----------------
__global__ __launch_bounds__(256) void fuse_weights(
        const float* __restrict__ aw, const float* __restrict__ Bw,
        const float* __restrict__ ab, const float* __restrict__ Bb,
        float* __restrict__ bc, float* __restrict__ bd,
        ushort* __restrict__ wct, ushort* __restrict__ wdt) {
    int e = blockIdx.x * 256 + threadIdx.x;
    if (e < 131072) {
        int dd = e & 4095; int l = (e >> 12) & 1; int r = (e >> 13) & 7; int cd = e >> 16;
        float s = 0.f;
        #pragma unroll
        for (int h = 0; h < 4; ++h)
            s += aw[((cd*8 + r)*4 + h)*2 + l] * Bw[(h*2 + l)*4096 + dd];
        // dd = k*64 + d ; transposed index = d*64 + k
        int tidx = (r*2 + l)*4096 + (dd & 63)*64 + (dd >> 6);
        (cd ? wdt : wct)[tidx] = to_bf16u(s);
    } else {
        int e2 = e - 131072;
        if (e2 < 2048) {
            int d = e2 & 63; int l = (e2 >> 6) & 1; int r = (e2 >> 7) & 7; int cd = e2 >> 10;
            float s = 0.f;
            #pragma unroll
            for (int h = 0; h < 4; ++h)
                s += ab[((cd*8 + r)*4 + h)*2 + l] * Bb[(h*2 + l)*64 + d];
            (cd ? bd : bc)[(r*2 + l)*64 + d] = s;
        }
    }
}

// ---------------- K2: [B,D,N,T] -> [M,N,D] transpose ----------------
__global__ __launch_bounds__(256) void transpose_in(
        const float* __restrict__ x0, const float* __restrict__ x1,
        float* __restrict__ xs) {
    int bid = blockIdx.x;
    int n = bid % N_; int b = (bid / N_) % B_; int i = bid / (N_ * B_);
    const float* __restrict__ x = i ? x1 : x0;
    float* __restrict__ xo = xs + (size_t)i * MND_;
    __shared__ float tile[64][13];
    #pragma unroll
    for (int q = 0; q < 3; ++q) {
        int e = q * 256 + threadIdx.x;
        int d = e / 12, t = e % 12;
        tile[d][t] = x[(((size_t)b * D_ + d) * N_ + n) * T_ + t];
    }
    __syncthreads();
    #pragma unroll
    for (int q = 0; q < 3; ++q) {
        int e = q * 256 + threadIdx.x;
        int t = e >> 6, d = e & 63;
        xo[(((size_t)b * T_ + t) * N_ + n) * D_ + d] = tile[d][t];
    }
}

// ---------------- K3a: adjT bf16 hi/lo prep ----------------
__global__ __launch_bounds__(256) void adj_prep(
        const float* __restrict__ graphs,
        ushort* __restrict__ AT_hi, ushort* __restrict__ AT_lo) {
    int t = blockIdx.z;
    int n0 = blockIdx.x * 32, mm0 = blockIdx.y * 32;
    __shared__ float tile[32][33];
    int cc = threadIdx.x & 31, rr = threadIdx.x >> 5;
    #pragma unroll
    for (int it = 0; it < 4; ++it) {
        int n = n0 + it * 8 + rr, mm = mm0 + cc;
        tile[it * 8 + rr][cc] = (n < N_ && mm < N_)
            ? graphs[(size_t)t * 250000 + (size_t)n * 500 + mm] : 0.f;
    }
    __syncthreads();
    #pragma unroll
    for (int it = 0; it < 4; ++it) {
        int mml = it * 8 + rr, nl = cc;
        float v = tile[nl][mml];
        ushort h, l; split_bf16(v, h, l);
        size_t idx = (size_t)t * 262144 + (size_t)(mm0 + mml) * 512 + n0 + nl;
        AT_hi[idx] = h; AT_lo[idx] = l;
    }
}

// ---------------- K3b: X transpose-cast (short8 vector stores) ----------------
__global__ __launch_bounds__(256) void xt_cast(
        const float* __restrict__ xs,
        ushort* __restrict__ XT_hi, ushort* __restrict__ XT_lo) {
    int i = blockIdx.z, m = blockIdx.y, c = blockIdx.x;
    int n0 = c * 64;
    __shared__ float tile[64][65];
    int d = threadIdx.x & 63, r4 = threadIdx.x >> 6;
    const float* __restrict__ src = xs + (size_t)i * MND_ + (size_t)m * 32000;
    #pragma unroll
    for (int it = 0; it < 16; ++it) {
        int nl = it * 4 + r4; int n = n0 + nl;
        tile[nl][d] = (n < N_) ? src[(size_t)n * 64 + d] : 0.f;
    }
    __syncthreads();
    size_t base = (size_t)(i * 96 + m) * 64 * 512 + n0;
    int dl = threadIdx.x >> 2, ng = threadIdx.x & 3;
    #pragma unroll
    for (int half = 0; half < 2; ++half) {
        int nlb = ng * 16 + half * 8;
        short8 hv, lv;
        #pragma unroll
        for (int q = 0; q < 8; ++q) {
            ushort h, l; split_bf16(tile[nlb + q][dl], h, l);
            hv[q] = (short)h; lv[q] = (short)l;
        }
        *(short8*)(XT_hi + base + (size_t)dl * 512 + nlb) = hv;
        *(short8*)(XT_lo + base + (size_t)dl * 512 + nlb) = lv;
    }
}

// ---------------- K3c: aggregation via MFMA; epilogue writes agg as bf16 hi/lo ----------------
__global__ __launch_bounds__(64) void aggregate_mfma(
        const ushort* __restrict__ AT_hi, const ushort* __restrict__ AT_lo,
        const ushort* __restrict__ XT_hi, const ushort* __restrict__ XT_lo,
        ushort* __restrict__ aggh, ushort* __restrict__ aggl) {
    int w = (blockIdx.x & 7) * 384 + (blockIdx.x >> 3);
    const int mm0 = (w & 7) * 64;
    int g = w >> 3;
    const int m = g % 96;
    const int cmb = g / 96;
    const int t = cmb >> 1, j = cmb & 1;
    const int lane = threadIdx.x;
    const int lr = lane & 15;
    const int lk = (lane >> 4) * 8;

    const ushort* __restrict__ A_h = AT_hi + (size_t)t * 262144 + (size_t)(mm0 + lr) * 512 + lk;
    const ushort* __restrict__ A_l = AT_lo + (size_t)t * 262144 + (size_t)(mm0 + lr) * 512 + lk;
    const ushort* __restrict__ B_h = XT_hi + ((size_t)(j * 96 + m) * 64 + lr) * 512 + lk;
    const ushort* __restrict__ B_l = XT_lo + ((size_t)(j * 96 + m) * 64 + lr) * 512 + lk;

    f32x4 acc[4][4] = {};

    for (int k0 = 0; k0 < 512; k0 += 32) {
        bf16x8 ah[4], al[4], bh[4], bl[4];
        #pragma unroll
        for (int f = 0; f < 4; ++f) {
            ah[f] = *(const bf16x8*)(A_h + (size_t)f * 8192 + k0);
            al[f] = *(const bf16x8*)(A_l + (size_t)f * 8192 + k0);
            bh[f] = *(const bf16x8*)(B_h + (size_t)f * 8192 + k0);
            bl[f] = *(const bf16x8*)(B_l + (size_t)f * 8192 + k0);
        }
        #pragma unroll
        for (int fi = 0; fi < 4; ++fi)
            #pragma unroll
            for (int fj = 0; fj < 4; ++fj)
                acc[fi][fj] = __builtin_amdgcn_mfma_f32_16x16x32_bf16(ah[fi], bh[fj], acc[fi][fj], 0, 0, 0);
        #pragma unroll
        for (int fi = 0; fi < 4; ++fi)
            #pragma unroll
            for (int fj = 0; fj < 4; ++fj)
                acc[fi][fj] = __builtin_amdgcn_mfma_f32_16x16x32_bf16(ah[fi], bl[fj], acc[fi][fj], 0, 0, 0);
        #pragma unroll
        for (int fi = 0; fi < 4; ++fi)
            #pragma unroll
            for (int fj = 0; fj < 4; ++fj)
                acc[fi][fj] = __builtin_amdgcn_mfma_f32_16x16x32_bf16(al[fi], bh[fj], acc[fi][fj], 0, 0, 0);
    }

    size_t obase = (size_t)cmb * MND_ + (size_t)m * 32000;
    #pragma unroll
    for (int fi = 0; fi < 4; ++fi) {
        #pragma unroll
        for (int reg = 0; reg < 4; ++reg) {
            int row = mm0 + fi * 16 + (lane >> 4) * 4 + reg;
            if (row < N_) {
                #pragma unroll
                for (int fj = 0; fj < 4; ++fj) {
                    ushort h, l; split_bf16(acc[fi][fj][reg], h, l);
                    size_t idx = obase + (size_t)row * 64 + fj * 16 + lr;
                    aggh[idx] = h; aggl[idx] = l;
                }
            }
        }
    }
}

// ---------------- K4: combine via MFMA ----------------
// h[i][row,:] = sum_{t,j} relu(aggj@wc + bc) + tanh((aggj-aggi)@wd + bd)
// Block = 1 wave, 32 rows (flat over [m][row]) x 64 cols. A = agg bf16 hi/lo
// (hi/lo exact to 2^-17); B = WT bf16 rows=out-d, k contig. Bias preloaded as
// MFMA C-input. aggi terms negated via sign-bit XOR (linearity).
__global__ __launch_bounds__(64) void combine_mfma(
        const ushort* __restrict__ aggh, const ushort* __restrict__ aggl,
        const ushort* __restrict__ wct, const ushort* __restrict__ wdt,
        const float* __restrict__ bcv, const float* __restrict__ bdv,
        float* __restrict__ xs_out, int l) {
    const int i = blockIdx.y;
    const int r0 = blockIdx.x * 32;
    const int lane = threadIdx.x;
    const int lr = lane & 15;
    const int lk = (lane >> 4) * 8;

    f32x4 hacc[2][4] = {};

    for (int t = 0; t < 2; ++t) {
        #pragma unroll
        for (int j = 0; j < 2; ++j) {
            const int rel = (t * 2 + i) * 2 + j;
            const int wb = (rel * 2 + l) * 4096;
            const ushort* __restrict__ Ajh = aggh + (size_t)(t * 2 + j) * MND_ + (size_t)(r0 + lr) * 64 + lk;
            const ushort* __restrict__ Ajl = aggl + (size_t)(t * 2 + j) * MND_ + (size_t)(r0 + lr) * 64 + lk;
            const ushort* __restrict__ Wc = wct + wb + lr * 64 + lk;

            f32x4 cacc[2][4];
            #pragma unroll
            for (int fj = 0; fj < 4; ++fj) {
                float bv = bcv[(rel * 2 + l) * 64 + fj * 16 + lr];
                #pragma unroll
                for (int fi = 0; fi < 2; ++fi) cacc[fi][fj] = f32x4{bv, bv, bv, bv};
            }

            if (j != i) {
                const ushort* __restrict__ Aih = aggh + (size_t)(t * 2 + i) * MND_ + (size_t)(r0 + lr) * 64 + lk;
                const ushort* __restrict__ Ail = aggl + (size_t)(t * 2 + i) * MND_ + (size_t)(r0 + lr) * 64 + lk;
                const ushort* __restrict__ Wd = wdt + wb + lr * 64 + lk;
                f32x4 dacc[2][4];
                #pragma unroll
                for (int fj = 0; fj < 4; ++fj) {
                    float bv = bdv[(rel * 2 + l) * 64 + fj * 16 + lr];
                    #pragma unroll
                    for (int fi = 0; fi < 2; ++fi) dacc[fi][fj] = f32x4{bv, bv, bv, bv};
                }
                #pragma unroll
                for (int k0 = 0; k0 < 64; k0 += 32) {
                    bf16x8 ajh[2], ajl[2], nih[2], nil[2], wcf[4], wdf[4];
                    #pragma unroll
                    for (int fi = 0; fi < 2; ++fi) {
                        ajh[fi] = *(const bf16x8*)(Ajh + fi * 1024 + k0);
                        ajl[fi] = *(const bf16x8*)(Ajl + fi * 1024 + k0);
                        bf16x8 ih = *(const bf16x8*)(Aih + fi * 1024 + k0);
                        bf16x8 il = *(const bf16x8*)(Ail + fi * 1024 + k0);
                        #pragma unroll
                        for (int q = 0; q < 8; ++q) {
                            nih[fi][q] = ih[q] ^ (short)0x8000;
                            nil[fi][q] = il[q] ^ (short)0x8000;
                        }
                    }
                    #pragma unroll
                    for (int fj = 0; fj < 4; ++fj) {
                        wcf[fj] = *(const bf16x8*)(Wc + fj * 1024 + k0);
                        wdf[fj] = *(const bf16x8*)(Wd + fj * 1024 + k0);
                    }
                    #pragma unroll
                    for (int fi = 0; fi < 2; ++fi)
                        #pragma unroll
                        for (int fj = 0; fj < 4; ++fj) {
                            cacc[fi][fj] = __builtin_amdgcn_mfma_f32_16x16x32_bf16(ajh[fi], wcf[fj], cacc[fi][fj], 0, 0, 0);
                            cacc[fi][fj] = __builtin_amdgcn_mfma_f32_16x16x32_bf16(ajl[fi], wcf[fj], cacc[fi][fj], 0, 0, 0);
                            dacc[fi][fj] = __builtin_amdgcn_mfma_f32_16x16x32_bf16(ajh[fi], wdf[fj], dacc[fi][fj], 0, 0, 0);
                            dacc[fi][fj] = __builtin_amdgcn_mfma_f32_16x16x32_bf16(ajl[fi], wdf[fj], dacc[fi][fj], 0, 0, 0);
                            dacc[fi][fj] = __builtin_amdgcn_mfma_f32_16x16x32_bf16(nih[fi], wdf[fj], dacc[fi][fj], 0, 0, 0);
                            dacc[fi][fj] = __builtin_amdgcn_mfma_f32_16x16x32_bf16(nil[fi], wdf[fj], dacc[fi][fj], 0, 0, 0);
                        }
                }
                #pragma unroll
                for (int fi = 0; fi < 2; ++fi)
                    #pragma unroll
                    for (int fj = 0; fj < 4; ++fj)
                        #pragma unroll
                        for (int reg = 0; reg < 4; ++reg) {
                            hacc[fi][fj][reg] += fmaxf(cacc[fi][fj][reg], 0.f);
                            hacc[fi][fj][reg] += fast_tanh(dacc[fi][fj][reg]);
                        }
            } else {
                #pragma unroll
                for (int k0 = 0; k0 < 64; k0 += 32) {
                    bf16x8 ajh[2], ajl[2], wcf[4];
                    #pragma unroll
                    for (int fi = 0; fi < 2; ++fi) {
                        ajh[fi] = *(const bf16x8*)(Ajh + fi * 1024 + k0);
                        ajl[fi] = *(const bf16x8*)(Ajl + fi * 1024 + k0);
                    }
                    #pragma unroll
                    for (int fj = 0; fj < 4; ++fj)
                        wcf[fj] = *(const bf16x8*)(Wc + fj * 1024 + k0);
                    #pragma unroll
                    for (int fi = 0; fi < 2; ++fi)
                        #pragma unroll
                        for (int fj = 0; fj < 4; ++fj) {
                            cacc[fi][fj] = __builtin_amdgcn_mfma_f32_16x16x32_bf16(ajh[fi], wcf[fj], cacc[fi][fj], 0, 0, 0);
                            cacc[fi][fj] = __builtin_amdgcn_mfma_f32_16x16x32_bf16(ajl[fi], wcf[fj], cacc[fi][fj], 0, 0, 0);
                        }
                }
                #pragma unroll
                for (int fj = 0; fj < 4; ++fj) {
                    float tb = fast_tanh(bdv[(rel * 2 + l) * 64 + fj * 16 + lr]);
                    #pragma unroll
                    for (int fi = 0; fi < 2; ++fi)
                        #pragma unroll
                        for (int reg = 0; reg < 4; ++reg) {
                            hacc[fi][fj][reg] += fmaxf(cacc[fi][fj][reg], 0.f);
                            hacc[fi][fj][reg] += tb;
                        }
                }
            }
        }
    }

    float* __restrict__ Ho = xs_out + (size_t)i * MND_;
    #pragma unroll
    for (int fi = 0; fi < 2; ++fi)
        #pragma unroll
        for (int reg = 0; reg < 4; ++reg) {
            int row = r0 + fi * 16 + (lane >> 4) * 4 + reg;
            #pragma unroll
            for (int fj = 0; fj < 4; ++fj)
                Ho[(size_t)row * 64 + fj * 16 + lr] = hacc[fi][fj][reg];
        }
}

// ---------------- K4b: cast all 6 XS slices to bf16 (for summarize gather) ----------------
__global__ __launch_bounds__(256) void xs_to_bf16(
        const float* __restrict__ xs, ushort* __restrict__ xsb) {
    size_t idx = ((size_t)blockIdx.x * 256 + threadIdx.x) * 4;
    f4 v = *(const f4*)(xs + idx);
    us4 o;
    #pragma unroll
    for (int q = 0; q < 4; ++q) o[q] = to_bf16u(v[q]);
    *(us4*)(xsb + idx) = o;
}

// ---------------- K5: summarize (round-9 proven version) ----------------
__global__ __launch_bounds__(192) void summarize(
        const ushort* __restrict__ XSB, const int* __restrict__ nbr,
        const float* __restrict__ nw, float* __restrict__ out) {
    int wg = (blockIdx.x & 7) * 252 + (blockIdx.x >> 3);
    int grp = wg / 126;
    int rem = wg % 126;
    int i = grp >> 3, b = grp & 7;
    int l = rem / 42;
    int rem2 = rem % 42;
    int t = rem2 / 21;
    int tile = rem2 % 21;
    int n0 = tile * 24;
    int tid = threadIdx.x;
    int sub = tid >> 6;
    int d = tid & 63;

    __shared__ int   nb_s[24][20];
    __shared__ float w_s[24][20];
    __shared__ float staged[64][145];

    for (int e = tid; e < 480; e += 192) {
        int nn = e / 20, k = e % 20;
        int n = n0 + nn;
        nb_s[nn][k] = (n < N_) ? nbr[((size_t)t * N_ + n) * K_ + k] : 0;
        w_s[nn][k]  = (n < N_) ? nw[((size_t)t * N_ + n) * K_ + k] : 0.f;
    }
    __syncthreads();

    const ushort* __restrict__ Xbase = XSB + ((size_t)l * 2 + i) * MND_
                                     + (size_t)b * T_ * N_ * D_ + d;
    size_t obase = ((size_t)((i * 8 + b) * 384 + t * 192 + l * 64)) * 6000
                 + (size_t)n0 * 12;

    #pragma unroll
    for (int half = 0; half < 2; ++half) {
        #pragma unroll
        for (int nn2 = 0; nn2 < 4; ++nn2) {
            int pl = sub * 4 + nn2;
            int nl = half * 12 + pl;
            #pragma unroll
            for (int tt0 = 0; tt0 < 12; tt0 += 4) {
                const ushort* __restrict__ Xm0 = Xbase + (size_t)(tt0 + 0) * N_ * D_;
                const ushort* __restrict__ Xm1 = Xbase + (size_t)(tt0 + 1) * N_ * D_;
                const ushort* __restrict__ Xm2 = Xbase + (size_t)(tt0 + 2) * N_ * D_;
                const ushort* __restrict__ Xm3 = Xbase + (size_t)(tt0 + 3) * N_ * D_;
                float a0 = 0.f, a1 = 0.f, a2 = 0.f, a3 = 0.f;
                #pragma unroll
                for (int k = 0; k < K_; ++k) {
                    size_t off = (size_t)nb_s[nl][k] * D_;
                    float w = w_s[nl][k];
                    a0 = fmaf(__uint_as_float((uint)Xm0[off] << 16), w, a0);
                    a1 = fmaf(__uint_as_float((uint)Xm1[off] << 16), w, a1);
                    a2 = fmaf(__uint_as_float((uint)Xm2[off] << 16), w, a2);
                    a3 = fmaf(__uint_as_float((uint)Xm3[off] << 16), w, a3);
                }
                staged[d][pl * 12 + tt0 + 0] = a0;
                staged[d][pl * 12 + tt0 + 1] = a1;
                staged[d][pl * 12 + tt0 + 2] = a2;
                staged[d][pl * 12 + tt0 + 3] = a3;
            }
        }
        __syncthreads();
        int base_n = n0 + half * 12;
        int plim = (N_ - base_n) * 12;
        if (plim > 144) plim = 144;
        if (plim > 0) {
            for (int it = 0; it < 48; ++it) {
                int e = it * 192 + tid;
                int c2 = e / 144, q = e % 144;
                if (q < plim)
                    out[obase + (size_t)c2 * 6000 + (size_t)half * 144 + q] = staged[c2][q];
            }
        }
        __syncthreads();
    }
}

extern "C" void kernel_launch(void* const* d_in, const int* in_sizes, int n_in,
                              void* d_out, int out_size, void* d_ws, size_t ws_size,
                              hipStream_t stream) {
    const float* x0     = (const float*)d_in[0];
    const float* x1     = (const float*)d_in[1];
    const float* graphs = (const float*)d_in[2];
    const int*   nbr    = (const int*)d_in[3];
    const float* nwt    = (const float*)d_in[4];
    const float* aw     = (const float*)d_in[5];
    const float* Bw     = (const float*)d_in[6];
    const float* ab     = (const float*)d_in[7];
    const float* Bb     = (const float*)d_in[8];
    float* out = (float*)d_out;
    float* ws  = (float*)d_ws;

    float* XS  = ws + XS_OFF;
    float* BC  = ws + BC_OFF;
    float* BD  = ws + BD_OFF;
    ushort* AGh = (ushort*)(ws + AGG_OFF);
    ushort* AGl = (ushort*)(ws + AGL_OFF);
    ushort* ATh = (ushort*)(ws + AT_HI_OFF);
    ushort* ATl = (ushort*)(ws + AT_LO_OFF);
    ushort* XTh = (ushort*)(ws + XT_HI_OFF);
    ushort* XTl = (ushort*)(ws + XT_LO_OFF);
    ushort* WCT = (ushort*)(ws + WCT_OFF);
    ushort* WDT = (ushort*)(ws + WDT_OFF);
    ushort* XSB = (ushort*)(ws + AGG_OFF);   // agg region dead after layer loop

    fuse_weights<<<520, 256, 0, stream>>>(aw, Bw, ab, Bb, BC, BD, WCT, WDT);
    transpose_in<<<8000, 256, 0, stream>>>(x0, x1, XS);
    adj_prep<<<dim3(16, 16, 2), 256, 0, stream>>>(graphs, ATh, ATl);
    for (int l = 0; l < 2; ++l) {
        xt_cast<<<dim3(8, 96, 2), 256, 0, stream>>>(XS + (size_t)l * 2 * MND_, XTh, XTl);
        aggregate_mfma<<<3072, 64, 0, stream>>>(ATh, ATl, XTh, XTl, AGh, AGl);
        combine_mfma<<<dim3(1500, 2), 64, 0, stream>>>(AGh, AGl, WCT, WDT, BC, BD,
                                                       XS + (size_t)(l + 1) * 2 * MND_, l);
    }
    xs_to_bf16<<<18000, 256, 0, stream>>>(XS, XSB);
    summarize<<<2016, 192, 0, stream>>>(XSB, nbr, nwt, out);
}

// Round 11
// 502.635 us; speedup vs baseline: 2.3835x; 1.0548x over previous
//
#include <hip/hip_runtime.h>
#include <hip/hip_bf16.h>
#include <math.h>

#define B_ 8
#define T_ 12
#define N_ 500
#define D_ 64
#define K_ 20
#define M_ (B_*T_)              // 96
#define MND_ 3072000            // M_*N_*D_

// workspace layout (float offsets)
#define XS_OFF  0ul                     // stage0 fp32 x 2 mix (stages 1/2 region reused as XSB)
#define XSB_OFF (2ul*MND_)              // 6 slices x MND ushort = 3*MND f (inside dead fp32 stage1/2 region)
#define AGG_OFF (6ul*MND_)              // agg bf16 hi (2*MND f) + lo (2*MND f)
#define AGL_OFF (AGG_OFF + 2ul*MND_)
#define BC_OFF  (AGG_OFF + 4ul*MND_)    // 8*2*64
#define BD_OFF  (BC_OFF + 1024ul)
#define AT_HI_OFF (BD_OFF + 1024ul)         // 2*512*512 ushort = 262144 f-units
#define AT_LO_OFF (AT_HI_OFF + 262144ul)
#define XT_HI_OFF (AT_LO_OFF + 262144ul)    // 2*96*64*512 ushort = 3145728 f-units
#define XT_LO_OFF (XT_HI_OFF + 3145728ul)
#define WCT_OFF (XT_LO_OFF + 3145728ul)     // 16*4096 bf16 = 32768 f-units
#define WDT_OFF (WCT_OFF + 32768ul)

using f4 = __attribute__((ext_vector_type(4))) float;
typedef __attribute__((ext_vector_type(8))) short bf16x8;
typedef __attribute__((ext_vector_type(8))) short short8;
typedef __attribute__((ext_vector_type(4))) float f32x4;

__device__ inline void split_bf16(float v, ushort& h, ushort& l) {
    __hip_bfloat16 bh = __float2bfloat16(v);
    float fh = __bfloat162float(bh);
    __hip_bfloat16 bl = __float2bfloat16(v - fh);
    h = *reinterpret_cast<ushort*>(&bh);
    l = *reinterpret_cast<ushort*>(&bl);
}
__device__ inline ushort to_bf16u(float v) {
    __hip_bfloat16 b = __float2bfloat16(v);
    return *reinterpret_cast<ushort*>(&b);
}

// fast tanh: 1 - 2/(e^{2x}+1)
__device__ inline float fast_tanh(float x) {
    float u = __expf(2.0f * x);
    return 1.0f - 2.0f * __builtin_amdgcn_rcpf(u + 1.0f);
}

// ---------------- K1: fuse head-mixture weights (transposed bf16 + fp32 biases) ----------------
__global__ __launch_bounds__(256) void fuse_weights(
        const float* __restrict__ aw, const float* __restrict__ Bw,
        const float* __restrict__ ab, const float* __restrict__ Bb,
        float* __restrict__ bc, float* __restrict__ bd,
        ushort* __restrict__ wct, ushort* __restrict__ wdt) {
    int e = blockIdx.x * 256 + threadIdx.x;
    if (e < 131072) {
        int dd = e & 4095; int l = (e >> 12) & 1; int r = (e >> 13) & 7; int cd = e >> 16;
        float s = 0.f;
        #pragma unroll
        for (int h = 0; h < 4; ++h)
            s += aw[((cd*8 + r)*4 + h)*2 + l] * Bw[(h*2 + l)*4096 + dd];
        int tidx = (r*2 + l)*4096 + (dd & 63)*64 + (dd >> 6);
        (cd ? wdt : wct)[tidx] = to_bf16u(s);
    } else {
        int e2 = e - 131072;
        if (e2 < 2048) {
            int d = e2 & 63; int l = (e2 >> 6) & 1; int r = (e2 >> 7) & 7; int cd = e2 >> 10;
            float s = 0.f;
            #pragma unroll
            for (int h = 0; h < 4; ++h)
                s += ab[((cd*8 + r)*4 + h)*2 + l] * Bb[(h*2 + l)*64 + d];
            (cd ? bd : bc)[(r*2 + l)*64 + d] = s;
        }
    }
}

// ---------------- K2: [B,D,N,T] -> [M,N,D] transpose; also emits XSB stage-0 bf16 ----------------
__global__ __launch_bounds__(256) void transpose_in(
        const float* __restrict__ x0, const float* __restrict__ x1,
        float* __restrict__ xs, ushort* __restrict__ xsb0) {
    int bid = blockIdx.x;
    int n = bid % N_; int b = (bid / N_) % B_; int i = bid / (N_ * B_);
    const float* __restrict__ x = i ? x1 : x0;
    float* __restrict__ xo = xs + (size_t)i * MND_;
    ushort* __restrict__ xbo = xsb0 + (size_t)i * MND_;
    __shared__ float tile[64][13];
    #pragma unroll
    for (int q = 0; q < 3; ++q) {
        int e = q * 256 + threadIdx.x;
        int d = e / 12, t = e % 12;
        tile[d][t] = x[(((size_t)b * D_ + d) * N_ + n) * T_ + t];
    }
    __syncthreads();
    #pragma unroll
    for (int q = 0; q < 3; ++q) {
        int e = q * 256 + threadIdx.x;
        int t = e >> 6, d = e & 63;
        float v = tile[d][t];
        size_t idx = (((size_t)b * T_ + t) * N_ + n) * D_ + d;
        xo[idx] = v;
        xbo[idx] = to_bf16u(v);
    }
}

// ---------------- K3a: adjT bf16 hi/lo prep ----------------
__global__ __launch_bounds__(256) void adj_prep(
        const float* __restrict__ graphs,
        ushort* __restrict__ AT_hi, ushort* __restrict__ AT_lo) {
    int t = blockIdx.z;
    int n0 = blockIdx.x * 32, mm0 = blockIdx.y * 32;
    __shared__ float tile[32][33];
    int cc = threadIdx.x & 31, rr = threadIdx.x >> 5;
    #pragma unroll
    for (int it = 0; it < 4; ++it) {
        int n = n0 + it * 8 + rr, mm = mm0 + cc;
        tile[it * 8 + rr][cc] = (n < N_ && mm < N_)
            ? graphs[(size_t)t * 250000 + (size_t)n * 500 + mm] : 0.f;
    }
    __syncthreads();
    #pragma unroll
    for (int it = 0; it < 4; ++it) {
        int mml = it * 8 + rr, nl = cc;
        float v = tile[nl][mml];
        ushort h, l; split_bf16(v, h, l);
        size_t idx = (size_t)t * 262144 + (size_t)(mm0 + mml) * 512 + n0 + nl;
        AT_hi[idx] = h; AT_lo[idx] = l;
    }
}

// ---------------- K3b: X transpose-cast for layer 0 only ----------------
__global__ __launch_bounds__(256) void xt_cast(
        const float* __restrict__ xs,
        ushort* __restrict__ XT_hi, ushort* __restrict__ XT_lo) {
    int i = blockIdx.z, m = blockIdx.y, c = blockIdx.x;
    int n0 = c * 64;
    __shared__ float tile[64][65];
    int d = threadIdx.x & 63, r4 = threadIdx.x >> 6;
    const float* __restrict__ src = xs + (size_t)i * MND_ + (size_t)m * 32000;
    #pragma unroll
    for (int it = 0; it < 16; ++it) {
        int nl = it * 4 + r4; int n = n0 + nl;
        tile[nl][d] = (n < N_) ? src[(size_t)n * 64 + d] : 0.f;
    }
    __syncthreads();
    size_t base = (size_t)(i * 96 + m) * 64 * 512 + n0;
    int dl = threadIdx.x >> 2, ng = threadIdx.x & 3;
    #pragma unroll
    for (int half = 0; half < 2; ++half) {
        int nlb = ng * 16 + half * 8;
        short8 hv, lv;
        #pragma unroll
        for (int q = 0; q < 8; ++q) {
            ushort h, l; split_bf16(tile[nlb + q][dl], h, l);
            hv[q] = (short)h; lv[q] = (short)l;
        }
        *(short8*)(XT_hi + base + (size_t)dl * 512 + nlb) = hv;
        *(short8*)(XT_lo + base + (size_t)dl * 512 + nlb) = lv;
    }
}

// ---------------- K3c: aggregation via MFMA (round-10 proven) ----------------
__global__ __launch_bounds__(64) void aggregate_mfma(
        const ushort* __restrict__ AT_hi, const ushort* __restrict__ AT_lo,
        const ushort* __restrict__ XT_hi, const ushort* __restrict__ XT_lo,
        ushort* __restrict__ aggh, ushort* __restrict__ aggl) {
    int w = (blockIdx.x & 7) * 384 + (blockIdx.x >> 3);
    const int mm0 = (w & 7) * 64;
    int g = w >> 3;
    const int m = g % 96;
    const int cmb = g / 96;
    const int t = cmb >> 1, j = cmb & 1;
    const int lane = threadIdx.x;
    const int lr = lane & 15;
    const int lk = (lane >> 4) * 8;

    const ushort* __restrict__ A_h = AT_hi + (size_t)t * 262144 + (size_t)(mm0 + lr) * 512 + lk;
    const ushort* __restrict__ A_l = AT_lo + (size_t)t * 262144 + (size_t)(mm0 + lr) * 512 + lk;
    const ushort* __restrict__ B_h = XT_hi + ((size_t)(j * 96 + m) * 64 + lr) * 512 + lk;
    const ushort* __restrict__ B_l = XT_lo + ((size_t)(j * 96 + m) * 64 + lr) * 512 + lk;

    f32x4 acc[4][4] = {};

    for (int k0 = 0; k0 < 512; k0 += 32) {
        bf16x8 ah[4], al[4], bh[4], bl[4];
        #pragma unroll
        for (int f = 0; f < 4; ++f) {
            ah[f] = *(const bf16x8*)(A_h + (size_t)f * 8192 + k0);
            al[f] = *(const bf16x8*)(A_l + (size_t)f * 8192 + k0);
            bh[f] = *(const bf16x8*)(B_h + (size_t)f * 8192 + k0);
            bl[f] = *(const bf16x8*)(B_l + (size_t)f * 8192 + k0);
        }
        #pragma unroll
        for (int fi = 0; fi < 4; ++fi)
            #pragma unroll
            for (int fj = 0; fj < 4; ++fj)
                acc[fi][fj] = __builtin_amdgcn_mfma_f32_16x16x32_bf16(ah[fi], bh[fj], acc[fi][fj], 0, 0, 0);
        #pragma unroll
        for (int fi = 0; fi < 4; ++fi)
            #pragma unroll
            for (int fj = 0; fj < 4; ++fj)
                acc[fi][fj] = __builtin_amdgcn_mfma_f32_16x16x32_bf16(ah[fi], bl[fj], acc[fi][fj], 0, 0, 0);
        #pragma unroll
        for (int fi = 0; fi < 4; ++fi)
            #pragma unroll
            for (int fj = 0; fj < 4; ++fj)
                acc[fi][fj] = __builtin_amdgcn_mfma_f32_16x16x32_bf16(al[fi], bh[fj], acc[fi][fj], 0, 0, 0);
    }

    size_t obase = (size_t)cmb * MND_ + (size_t)m * 32000;
    #pragma unroll
    for (int fi = 0; fi < 4; ++fi) {
        #pragma unroll
        for (int reg = 0; reg < 4; ++reg) {
            int row = mm0 + fi * 16 + (lane >> 4) * 4 + reg;
            if (row < N_) {
                #pragma unroll
                for (int fj = 0; fj < 4; ++fj) {
                    ushort h, l; split_bf16(acc[fi][fj][reg], h, l);
                    size_t idx = obase + (size_t)row * 64 + fj * 16 + lr;
                    aggh[idx] = h; aggl[idx] = l;
                }
            }
        }
    }
}

// ---------------- K4: combine via MFMA; epilogue emits XSB bf16 + (l=0) XT hi/lo ----------------
// Block = (tile 0..15, m 0..95, i 0..1); 1 wave; 32 rows (n0..n0+31 of m) x 64 d.
__global__ __launch_bounds__(64) void combine_mfma(
        const ushort* __restrict__ aggh, const ushort* __restrict__ aggl,
        const ushort* __restrict__ wct, const ushort* __restrict__ wdt,
        const float* __restrict__ bcv, const float* __restrict__ bdv,
        ushort* __restrict__ xsb_out,            // stage l+1 base (kernel adds i*MND)
        ushort* __restrict__ xt_hi, ushort* __restrict__ xt_lo,
        int l, int write_xt) {
    const int tile = blockIdx.x;
    const int m = blockIdx.y;
    const int i = blockIdx.z;
    const int n0 = tile * 32;
    const int r0 = m * 500 + n0;
    const int lane = threadIdx.x;
    const int lr = lane & 15;
    const int lk = (lane >> 4) * 8;

    f32x4 hacc[2][4] = {};

    for (int t = 0; t < 2; ++t) {
        #pragma unroll
        for (int j = 0; j < 2; ++j) {
            const int rel = (t * 2 + i) * 2 + j;
            const int wb = (rel * 2 + l) * 4096;
            const ushort* __restrict__ Ajh = aggh + (size_t)(t * 2 + j) * MND_ + (size_t)(r0 + lr) * 64 + lk;
            const ushort* __restrict__ Ajl = aggl + (size_t)(t * 2 + j) * MND_ + (size_t)(r0 + lr) * 64 + lk;
            const ushort* __restrict__ Wc = wct + wb + lr * 64 + lk;

            f32x4 cacc[2][4];
            #pragma unroll
            for (int fj = 0; fj < 4; ++fj) {
                float bv = bcv[(rel * 2 + l) * 64 + fj * 16 + lr];
                #pragma unroll
                for (int fi = 0; fi < 2; ++fi) cacc[fi][fj] = f32x4{bv, bv, bv, bv};
            }

            if (j != i) {
                const ushort* __restrict__ Aih = aggh + (size_t)(t * 2 + i) * MND_ + (size_t)(r0 + lr) * 64 + lk;
                const ushort* __restrict__ Ail = aggl + (size_t)(t * 2 + i) * MND_ + (size_t)(r0 + lr) * 64 + lk;
                const ushort* __restrict__ Wd = wdt + wb + lr * 64 + lk;
                f32x4 dacc[2][4];
                #pragma unroll
                for (int fj = 0; fj < 4; ++fj) {
                    float bv = bdv[(rel * 2 + l) * 64 + fj * 16 + lr];
                    #pragma unroll
                    for (int fi = 0; fi < 2; ++fi) dacc[fi][fj] = f32x4{bv, bv, bv, bv};
                }
                #pragma unroll
                for (int k0 = 0; k0 < 64; k0 += 32) {
                    bf16x8 ajh[2], ajl[2], nih[2], nil[2], wcf[4], wdf[4];
                    #pragma unroll
                    for (int fi = 0; fi < 2; ++fi) {
                        ajh[fi] = *(const bf16x8*)(Ajh + fi * 1024 + k0);
                        ajl[fi] = *(const bf16x8*)(Ajl + fi * 1024 + k0);
                        bf16x8 ih = *(const bf16x8*)(Aih + fi * 1024 + k0);
                        bf16x8 il = *(const bf16x8*)(Ail + fi * 1024 + k0);
                        #pragma unroll
                        for (int q = 0; q < 8; ++q) {
                            nih[fi][q] = ih[q] ^ (short)0x8000;
                            nil[fi][q] = il[q] ^ (short)0x8000;
                        }
                    }
                    #pragma unroll
                    for (int fj = 0; fj < 4; ++fj) {
                        wcf[fj] = *(const bf16x8*)(Wc + fj * 1024 + k0);
                        wdf[fj] = *(const bf16x8*)(Wd + fj * 1024 + k0);
                    }
                    #pragma unroll
                    for (int fi = 0; fi < 2; ++fi)
                        #pragma unroll
                        for (int fj = 0; fj < 4; ++fj) {
                            cacc[fi][fj] = __builtin_amdgcn_mfma_f32_16x16x32_bf16(ajh[fi], wcf[fj], cacc[fi][fj], 0, 0, 0);
                            cacc[fi][fj] = __builtin_amdgcn_mfma_f32_16x16x32_bf16(ajl[fi], wcf[fj], cacc[fi][fj], 0, 0, 0);
                            dacc[fi][fj] = __builtin_amdgcn_mfma_f32_16x16x32_bf16(ajh[fi], wdf[fj], dacc[fi][fj], 0, 0, 0);
                            dacc[fi][fj] = __builtin_amdgcn_mfma_f32_16x16x32_bf16(ajl[fi], wdf[fj], dacc[fi][fj], 0, 0, 0);
                            dacc[fi][fj] = __builtin_amdgcn_mfma_f32_16x16x32_bf16(nih[fi], wdf[fj], dacc[fi][fj], 0, 0, 0);
                            dacc[fi][fj] = __builtin_amdgcn_mfma_f32_16x16x32_bf16(nil[fi], wdf[fj], dacc[fi][fj], 0, 0, 0);
                        }
                }
                #pragma unroll
                for (int fi = 0; fi < 2; ++fi)
                    #pragma unroll
                    for (int fj = 0; fj < 4; ++fj)
                        #pragma unroll
                        for (int reg = 0; reg < 4; ++reg) {
                            hacc[fi][fj][reg] += fmaxf(cacc[fi][fj][reg], 0.f);
                            hacc[fi][fj][reg] += fast_tanh(dacc[fi][fj][reg]);
                        }
            } else {
                #pragma unroll
                for (int k0 = 0; k0 < 64; k0 += 32) {
                    bf16x8 ajh[2], ajl[2], wcf[4];
                    #pragma unroll
                    for (int fi = 0; fi < 2; ++fi) {
                        ajh[fi] = *(const bf16x8*)(Ajh + fi * 1024 + k0);
                        ajl[fi] = *(const bf16x8*)(Ajl + fi * 1024 + k0);
                    }
                    #pragma unroll
                    for (int fj = 0; fj < 4; ++fj)
                        wcf[fj] = *(const bf16x8*)(Wc + fj * 1024 + k0);
                    #pragma unroll
                    for (int fi = 0; fi < 2; ++fi)
                        #pragma unroll
                        for (int fj = 0; fj < 4; ++fj) {
                            cacc[fi][fj] = __builtin_amdgcn_mfma_f32_16x16x32_bf16(ajh[fi], wcf[fj], cacc[fi][fj], 0, 0, 0);
                            cacc[fi][fj] = __builtin_amdgcn_mfma_f32_16x16x32_bf16(ajl[fi], wcf[fj], cacc[fi][fj], 0, 0, 0);
                        }
                }
                #pragma unroll
                for (int fj = 0; fj < 4; ++fj) {
                    float tb = fast_tanh(bdv[(rel * 2 + l) * 64 + fj * 16 + lr]);
                    #pragma unroll
                    for (int fi = 0; fi < 2; ++fi)
                        #pragma unroll
                        for (int reg = 0; reg < 4; ++reg) {
                            hacc[fi][fj][reg] += fmaxf(cacc[fi][fj][reg], 0.f);
                            hacc[fi][fj][reg] += tb;
                        }
                }
            }
        }
    }

    // ---- epilogue: stage tile in LDS (zero pad rows n>=500), emit XSB bf16 (+ XT hi/lo) ----
    __shared__ float staged[32][65];
    #pragma unroll
    for (int fi = 0; fi < 2; ++fi)
        #pragma unroll
        for (int reg = 0; reg < 4; ++reg) {
            int rloc = fi * 16 + (lane >> 4) * 4 + reg;
            bool ok = (n0 + rloc) < N_;
            #pragma unroll
            for (int fj = 0; fj < 4; ++fj)
                staged[rloc][fj * 16 + lr] = ok ? hacc[fi][fj][reg] : 0.f;
        }
    __syncthreads();

    ushort* __restrict__ Xb = xsb_out + (size_t)i * MND_;
    #pragma unroll
    for (int q = 0; q < 32; ++q) {
        if (n0 + q < N_)
            Xb[(size_t)(r0 + q) * 64 + lane] = to_bf16u(staged[q][lane]);
    }
    if (write_xt) {
        size_t tb = ((size_t)(i * 96 + m) * 64 + lane) * 512 + n0;
        #pragma unroll
        for (int g = 0; g < 4; ++g) {
            short8 hv, lv;
            #pragma unroll
            for (int q = 0; q < 8; ++q) {
                ushort h, l2; split_bf16(staged[g * 8 + q][lane], h, l2);
                hv[q] = (short)h; lv[q] = (short)l2;
            }
            *(short8*)(xt_hi + tb + g * 8) = hv;
            *(short8*)(xt_lo + tb + g * 8) = lv;
        }
    }
}

// ---------------- K5: summarize (round-10 proven version) ----------------
__global__ __launch_bounds__(192) void summarize(
        const ushort* __restrict__ XSB, const int* __restrict__ nbr,
        const float* __restrict__ nw, float* __restrict__ out) {
    int wg = (blockIdx.x & 7) * 252 + (blockIdx.x >> 3);
    int grp = wg / 126;
    int rem = wg % 126;
    int i = grp >> 3, b = grp & 7;
    int l = rem / 42;
    int rem2 = rem % 42;
    int t = rem2 / 21;
    int tile = rem2 % 21;
    int n0 = tile * 24;
    int tid = threadIdx.x;
    int sub = tid >> 6;
    int d = tid & 63;

    __shared__ int   nb_s[24][20];
    __shared__ float w_s[24][20];
    __shared__ float staged[64][145];

    for (int e = tid; e < 480; e += 192) {
        int nn = e / 20, k = e % 20;
        int n = n0 + nn;
        nb_s[nn][k] = (n < N_) ? nbr[((size_t)t * N_ + n) * K_ + k] : 0;
        w_s[nn][k]  = (n < N_) ? nw[((size_t)t * N_ + n) * K_ + k] : 0.f;
    }
    __syncthreads();

    const ushort* __restrict__ Xbase = XSB + ((size_t)l * 2 + i) * MND_
                                     + (size_t)b * T_ * N_ * D_ + d;
    size_t obase = ((size_t)((i * 8 + b) * 384 + t * 192 + l * 64)) * 6000
                 + (size_t)n0 * 12;

    #pragma unroll
    for (int half = 0; half < 2; ++half) {
        #pragma unroll
        for (int nn2 = 0; nn2 < 4; ++nn2) {
            int pl = sub * 4 + nn2;
            int nl = half * 12 + pl;
            #pragma unroll
            for (int tt0 = 0; tt0 < 12; tt0 += 4) {
                const ushort* __restrict__ Xm0 = Xbase + (size_t)(tt0 + 0) * N_ * D_;
                const ushort* __restrict__ Xm1 = Xbase + (size_t)(tt0 + 1) * N_ * D_;
                const ushort* __restrict__ Xm2 = Xbase + (size_t)(tt0 + 2) * N_ * D_;
                const ushort* __restrict__ Xm3 = Xbase + (size_t)(tt0 + 3) * N_ * D_;
                float a0 = 0.f, a1 = 0.f, a2 = 0.f, a3 = 0.f;
                #pragma unroll
                for (int k = 0; k < K_; ++k) {
                    size_t off = (size_t)nb_s[nl][k] * D_;
                    float w = w_s[nl][k];
                    a0 = fmaf(__uint_as_float((uint)Xm0[off] << 16), w, a0);
                    a1 = fmaf(__uint_as_float((uint)Xm1[off] << 16), w, a1);
                    a2 = fmaf(__uint_as_float((uint)Xm2[off] << 16), w, a2);
                    a3 = fmaf(__uint_as_float((uint)Xm3[off] << 16), w, a3);
                }
                staged[d][pl * 12 + tt0 + 0] = a0;
                staged[d][pl * 12 + tt0 + 1] = a1;
                staged[d][pl * 12 + tt0 + 2] = a2;
                staged[d][pl * 12 + tt0 + 3] = a3;
            }
        }
        __syncthreads();
        int base_n = n0 + half * 12;
        int plim = (N_ - base_n) * 12;
        if (plim > 144) plim = 144;
        if (plim > 0) {
            for (int it = 0; it < 48; ++it) {
                int e = it * 192 + tid;
                int c2 = e / 144, q = e % 144;
                if (q < plim)
                    out[obase + (size_t)c2 * 6000 + (size_t)half * 144 + q] = staged[c2][q];
            }
        }
        __syncthreads();
    }
}

extern "C" void kernel_launch(void* const* d_in, const int* in_sizes, int n_in,
                              void* d_out, int out_size, void* d_ws, size_t ws_size,
                              hipStream_t stream) {
    const float* x0     = (const float*)d_in[0];
    const float* x1     = (const float*)d_in[1];
    const float* graphs = (const float*)d_in[2];
    const int*   nbr    = (const int*)d_in[3];
    const float* nwt    = (const float*)d_in[4];
    const float* aw     = (const float*)d_in[5];
    const float* Bw     = (const float*)d_in[6];
    const float* ab     = (const float*)d_in[7];
    const float* Bb     = (const float*)d_in[8];
    float* out = (float*)d_out;
    float* ws  = (float*)d_ws;

    float* XS  = ws + XS_OFF;
    float* BC  = ws + BC_OFF;
    float* BD  = ws + BD_OFF;
    ushort* XSB = (ushort*)(ws + XSB_OFF);   // 6 slices x MND ushort
    ushort* AGh = (ushort*)(ws + AGG_OFF);
    ushort* AGl = (ushort*)(ws + AGL_OFF);
    ushort* ATh = (ushort*)(ws + AT_HI_OFF);
    ushort* ATl = (ushort*)(ws + AT_LO_OFF);
    ushort* XTh = (ushort*)(ws + XT_HI_OFF);
    ushort* XTl = (ushort*)(ws + XT_LO_OFF);
    ushort* WCT = (ushort*)(ws + WCT_OFF);
    ushort* WDT = (ushort*)(ws + WDT_OFF);

    fuse_weights<<<520, 256, 0, stream>>>(aw, Bw, ab, Bb, BC, BD, WCT, WDT);
    transpose_in<<<8000, 256, 0, stream>>>(x0, x1, XS, XSB);
    adj_prep<<<dim3(16, 16, 2), 256, 0, stream>>>(graphs, ATh, ATl);
    xt_cast<<<dim3(8, 96, 2), 256, 0, stream>>>(XS, XTh, XTl);   // layer 0 only
    for (int l = 0; l < 2; ++l) {
        aggregate_mfma<<<3072, 64, 0, stream>>>(ATh, ATl, XTh, XTl, AGh, AGl);
        combine_mfma<<<dim3(16, 96, 2), 64, 0, stream>>>(
            AGh, AGl, WCT, WDT, BC, BD,
            XSB + (size_t)(l + 1) * 2 * MND_, XTh, XTl, l, (l == 0) ? 1 : 0);
    }
    summarize<<<2016, 192, 0, stream>>>(XSB, nbr, nwt, out);
}

// Round 13
// 395.215 us; speedup vs baseline: 3.0313x; 1.2718x over previous
//
#include <hip/hip_runtime.h>
#include <hip/hip_bf16.h>
#include <math.h>

#define B_ 8
#define T_ 12
#define N_ 500
#define D_ 64
#define K_ 20
#define M_ (B_*T_)              // 96
#define MND_ 3072000            // M_*N_*D_

// workspace layout (float units)
#define XSB_OFF 0ul                         // 6 slices x MND ushort = 3*MND f
#define AGH_OFF (3ul*MND_)                  // 4*MND ushort = 2*MND f (agg single bf16)
#define AT_HI_OFF (5ul*MND_)                // 2*512*512 ushort = 262144 f
#define AT_LO_OFF (AT_HI_OFF + 262144ul)
#define XT_OFF    (AT_LO_OFF + 262144ul)    // 2*96*64*512 ushort = 3145728 f (single bf16)
#define WCT_OFF   (XT_OFF + 3145728ul)      // 16*4096 bf16 = 32768 f
#define WDT_OFF   (WCT_OFF + 32768ul)
#define BC_OFF    (WDT_OFF + 32768ul)       // 8*2*64 fp32
#define BD_OFF    (BC_OFF + 1024ul)
// end ~76 MB

using f4 = __attribute__((ext_vector_type(4))) float;
typedef __attribute__((ext_vector_type(8))) short bf16x8;
typedef __attribute__((ext_vector_type(8))) short short8;
typedef __attribute__((ext_vector_type(4))) float f32x4;

__device__ inline void split_bf16(float v, ushort& h, ushort& l) {
    __hip_bfloat16 bh = __float2bfloat16(v);
    float fh = __bfloat162float(bh);
    __hip_bfloat16 bl = __float2bfloat16(v - fh);
    h = *reinterpret_cast<ushort*>(&bh);
    l = *reinterpret_cast<ushort*>(&bl);
}
__device__ inline ushort to_bf16u(float v) {
    __hip_bfloat16 b = __float2bfloat16(v);
    return *reinterpret_cast<ushort*>(&b);
}

// fast tanh: 1 - 2/(e^{2x}+1)
__device__ inline float fast_tanh(float x) {
    float u = __expf(2.0f * x);
    return 1.0f - 2.0f * __builtin_amdgcn_rcpf(u + 1.0f);
}

// ---------------- K1: fuse head-mixture weights (transposed bf16 + fp32 biases) ----------------
__global__ __launch_bounds__(256) void fuse_weights(
        const float* __restrict__ aw, const float* __restrict__ Bw,
        const float* __restrict__ ab, const float* __restrict__ Bb,
        float* __restrict__ bc, float* __restrict__ bd,
        ushort* __restrict__ wct, ushort* __restrict__ wdt) {
    int e = blockIdx.x * 256 + threadIdx.x;
    if (e < 131072) {
        int dd = e & 4095; int l = (e >> 12) & 1; int r = (e >> 13) & 7; int cd = e >> 16;
        float s = 0.f;
        #pragma unroll
        for (int h = 0; h < 4; ++h)
            s += aw[((cd*8 + r)*4 + h)*2 + l] * Bw[(h*2 + l)*4096 + dd];
        int tidx = (r*2 + l)*4096 + (dd & 63)*64 + (dd >> 6);
        (cd ? wdt : wct)[tidx] = to_bf16u(s);
    } else {
        int e2 = e - 131072;
        if (e2 < 2048) {
            int d = e2 & 63; int l = (e2 >> 6) & 1; int r = (e2 >> 7) & 7; int cd = e2 >> 10;
            float s = 0.f;
            #pragma unroll
            for (int h = 0; h < 4; ++h)
                s += ab[((cd*8 + r)*4 + h)*2 + l] * Bb[(h*2 + l)*64 + d];
            (cd ? bd : bc)[(r*2 + l)*64 + d] = s;
        }
    }
}

// ---------------- K2: [B,D,N,T] -> [M,N,D] transpose, bf16 output only ----------------
__global__ __launch_bounds__(256) void transpose_in(
        const float* __restrict__ x0, const float* __restrict__ x1,
        ushort* __restrict__ xsb0) {
    int bid = blockIdx.x;
    int n = bid % N_; int b = (bid / N_) % B_; int i = bid / (N_ * B_);
    const float* __restrict__ x = i ? x1 : x0;
    ushort* __restrict__ xbo = xsb0 + (size_t)i * MND_;
    __shared__ float tile[64][13];
    #pragma unroll
    for (int q = 0; q < 3; ++q) {
        int e = q * 256 + threadIdx.x;
        int d = e / 12, t = e % 12;
        tile[d][t] = x[(((size_t)b * D_ + d) * N_ + n) * T_ + t];
    }
    __syncthreads();
    #pragma unroll
    for (int q = 0; q < 3; ++q) {
        int e = q * 256 + threadIdx.x;
        int t = e >> 6, d = e & 63;
        xbo[(((size_t)b * T_ + t) * N_ + n) * D_ + d] = to_bf16u(tile[d][t]);
    }
}

// ---------------- K3a: adjT bf16 hi/lo prep (adj keeps hi/lo: unattenuated operand) ----------------
__global__ __launch_bounds__(256) void adj_prep(
        const float* __restrict__ graphs,
        ushort* __restrict__ AT_hi, ushort* __restrict__ AT_lo) {
    int t = blockIdx.z;
    int n0 = blockIdx.x * 32, mm0 = blockIdx.y * 32;
    __shared__ float tile[32][33];
    int cc = threadIdx.x & 31, rr = threadIdx.x >> 5;
    #pragma unroll
    for (int it = 0; it < 4; ++it) {
        int n = n0 + it * 8 + rr, mm = mm0 + cc;
        tile[it * 8 + rr][cc] = (n < N_ && mm < N_)
            ? graphs[(size_t)t * 250000 + (size_t)n * 500 + mm] : 0.f;
    }
    __syncthreads();
    #pragma unroll
    for (int it = 0; it < 4; ++it) {
        int mml = it * 8 + rr, nl = cc;
        float v = tile[nl][mml];
        ushort h, l; split_bf16(v, h, l);
        size_t idx = (size_t)t * 262144 + (size_t)(mm0 + mml) * 512 + n0 + nl;
        AT_hi[idx] = h; AT_lo[idx] = l;
    }
}

// ---------------- K3b: XT from XSB stage-0 — pure ushort transpose (layer 0 only) ----------------
__global__ __launch_bounds__(256) void xt_cast(
        const ushort* __restrict__ xsb,
        ushort* __restrict__ XT) {
    int i = blockIdx.z, m = blockIdx.y, c = blockIdx.x;   // c = n-chunk (0..7)
    int n0 = c * 64;
    __shared__ ushort tile[64][65];
    int d = threadIdx.x & 63, r4 = threadIdx.x >> 6;
    const ushort* __restrict__ src = xsb + (size_t)i * MND_ + (size_t)m * 32000;
    #pragma unroll
    for (int it = 0; it < 16; ++it) {
        int nl = it * 4 + r4; int n = n0 + nl;
        tile[nl][d] = (n < N_) ? src[(size_t)n * 64 + d] : (ushort)0;
    }
    __syncthreads();
    size_t base = (size_t)(i * 96 + m) * 64 * 512 + n0;
    int dl = threadIdx.x >> 2, ng = threadIdx.x & 3;
    #pragma unroll
    for (int half = 0; half < 2; ++half) {
        int nlb = ng * 16 + half * 8;
        short8 hv;
        #pragma unroll
        for (int q = 0; q < 8; ++q) hv[q] = (short)tile[nlb + q][dl];
        *(short8*)(XT + base + (size_t)dl * 512 + nlb) = hv;
    }
}

// ---------------- K3c: aggregation via MFMA, 2-product (adj hi/lo x bf16 X) ----------------
__global__ __launch_bounds__(64) void aggregate_mfma(
        const ushort* __restrict__ AT_hi, const ushort* __restrict__ AT_lo,
        const ushort* __restrict__ XT, ushort* __restrict__ aggh) {
    int w = (blockIdx.x & 7) * 384 + (blockIdx.x >> 3);
    const int mm0 = (w & 7) * 64;
    int g = w >> 3;
    const int m = g % 96;
    const int cmb = g / 96;
    const int t = cmb >> 1, j = cmb & 1;
    const int lane = threadIdx.x;
    const int lr = lane & 15;
    const int lk = (lane >> 4) * 8;

    const ushort* __restrict__ A_h = AT_hi + (size_t)t * 262144 + (size_t)(mm0 + lr) * 512 + lk;
    const ushort* __restrict__ A_l = AT_lo + (size_t)t * 262144 + (size_t)(mm0 + lr) * 512 + lk;
    const ushort* __restrict__ Bx  = XT + ((size_t)(j * 96 + m) * 64 + lr) * 512 + lk;

    f32x4 acc[4][4] = {};

    for (int k0 = 0; k0 < 512; k0 += 32) {
        bf16x8 ah[4], al[4], bh[4];
        #pragma unroll
        for (int f = 0; f < 4; ++f) {
            ah[f] = *(const bf16x8*)(A_h + (size_t)f * 8192 + k0);
            al[f] = *(const bf16x8*)(A_l + (size_t)f * 8192 + k0);
            bh[f] = *(const bf16x8*)(Bx  + (size_t)f * 8192 + k0);
        }
        #pragma unroll
        for (int fi = 0; fi < 4; ++fi)
            #pragma unroll
            for (int fj = 0; fj < 4; ++fj)
                acc[fi][fj] = __builtin_amdgcn_mfma_f32_16x16x32_bf16(ah[fi], bh[fj], acc[fi][fj], 0, 0, 0);
        #pragma unroll
        for (int fi = 0; fi < 4; ++fi)
            #pragma unroll
            for (int fj = 0; fj < 4; ++fj)
                acc[fi][fj] = __builtin_amdgcn_mfma_f32_16x16x32_bf16(al[fi], bh[fj], acc[fi][fj], 0, 0, 0);
    }

    size_t obase = (size_t)cmb * MND_ + (size_t)m * 32000;
    #pragma unroll
    for (int fi = 0; fi < 4; ++fi) {
        #pragma unroll
        for (int reg = 0; reg < 4; ++reg) {
            int row = mm0 + fi * 16 + (lane >> 4) * 4 + reg;
            if (row < N_) {
                #pragma unroll
                for (int fj = 0; fj < 4; ++fj)
                    aggh[obase + (size_t)row * 64 + fj * 16 + lr] = to_bf16u(acc[fi][fj][reg]);
            }
        }
    }
}

// ---------------- K4: combine via MFMA, single-bf16 agg operand ----------------
__global__ __launch_bounds__(64) void combine_mfma(
        const ushort* __restrict__ aggh,
        const ushort* __restrict__ wct, const ushort* __restrict__ wdt,
        const float* __restrict__ bcv, const float* __restrict__ bdv,
        ushort* __restrict__ xsb_out,
        ushort* __restrict__ xt_out, int l, int write_xt) {
    const int tile = blockIdx.x;
    const int m = blockIdx.y;
    const int i = blockIdx.z;
    const int n0 = tile * 32;
    const int r0 = m * 500 + n0;
    const int lane = threadIdx.x;
    const int lr = lane & 15;
    const int lk = (lane >> 4) * 8;

    f32x4 hacc[2][4] = {};

    for (int t = 0; t < 2; ++t) {
        #pragma unroll
        for (int j = 0; j < 2; ++j) {
            const int rel = (t * 2 + i) * 2 + j;
            const int wb = (rel * 2 + l) * 4096;
            const ushort* __restrict__ Ajh = aggh + (size_t)(t * 2 + j) * MND_ + (size_t)(r0 + lr) * 64 + lk;
            const ushort* __restrict__ Wc = wct + wb + lr * 64 + lk;

            f32x4 cacc[2][4];
            #pragma unroll
            for (int fj = 0; fj < 4; ++fj) {
                float bv = bcv[(rel * 2 + l) * 64 + fj * 16 + lr];
                #pragma unroll
                for (int fi = 0; fi < 2; ++fi) cacc[fi][fj] = f32x4{bv, bv, bv, bv};
            }

            if (j != i) {
                const ushort* __restrict__ Aih = aggh + (size_t)(t * 2 + i) * MND_ + (size_t)(r0 + lr) * 64 + lk;
                const ushort* __restrict__ Wd = wdt + wb + lr * 64 + lk;
                f32x4 dacc[2][4];
                #pragma unroll
                for (int fj = 0; fj < 4; ++fj) {
                    float bv = bdv[(rel * 2 + l) * 64 + fj * 16 + lr];
                    #pragma unroll
                    for (int fi = 0; fi < 2; ++fi) dacc[fi][fj] = f32x4{bv, bv, bv, bv};
                }
                #pragma unroll
                for (int k0 = 0; k0 < 64; k0 += 32) {
                    bf16x8 ajh[2], nih[2], wcf[4], wdf[4];
                    #pragma unroll
                    for (int fi = 0; fi < 2; ++fi) {
                        ajh[fi] = *(const bf16x8*)(Ajh + fi * 1024 + k0);
                        bf16x8 ih = *(const bf16x8*)(Aih + fi * 1024 + k0);
                        #pragma unroll
                        for (int q = 0; q < 8; ++q) nih[fi][q] = ih[q] ^ (short)0x8000;
                    }
                    #pragma unroll
                    for (int fj = 0; fj < 4; ++fj) {
                        wcf[fj] = *(const bf16x8*)(Wc + fj * 1024 + k0);
                        wdf[fj] = *(const bf16x8*)(Wd + fj * 1024 + k0);
                    }
                    #pragma unroll
                    for (int fi = 0; fi < 2; ++fi)
                        #pragma unroll
                        for (int fj = 0; fj < 4; ++fj) {
                            cacc[fi][fj] = __builtin_amdgcn_mfma_f32_16x16x32_bf16(ajh[fi], wcf[fj], cacc[fi][fj], 0, 0, 0);
                            dacc[fi][fj] = __builtin_amdgcn_mfma_f32_16x16x32_bf16(ajh[fi], wdf[fj], dacc[fi][fj], 0, 0, 0);
                            dacc[fi][fj] = __builtin_amdgcn_mfma_f32_16x16x32_bf16(nih[fi], wdf[fj], dacc[fi][fj], 0, 0, 0);
                        }
                }
                #pragma unroll
                for (int fi = 0; fi < 2; ++fi)
                    #pragma unroll
                    for (int fj = 0; fj < 4; ++fj)
                        #pragma unroll
                        for (int reg = 0; reg < 4; ++reg) {
                            hacc[fi][fj][reg] += fmaxf(cacc[fi][fj][reg], 0.f);
                            hacc[fi][fj][reg] += fast_tanh(dacc[fi][fj][reg]);
                        }
            } else {
                #pragma unroll
                for (int k0 = 0; k0 < 64; k0 += 32) {
                    bf16x8 ajh[2], wcf[4];
                    #pragma unroll
                    for (int fi = 0; fi < 2; ++fi)
                        ajh[fi] = *(const bf16x8*)(Ajh + fi * 1024 + k0);
                    #pragma unroll
                    for (int fj = 0; fj < 4; ++fj)
                        wcf[fj] = *(const bf16x8*)(Wc + fj * 1024 + k0);
                    #pragma unroll
                    for (int fi = 0; fi < 2; ++fi)
                        #pragma unroll
                        for (int fj = 0; fj < 4; ++fj)
                            cacc[fi][fj] = __builtin_amdgcn_mfma_f32_16x16x32_bf16(ajh[fi], wcf[fj], cacc[fi][fj], 0, 0, 0);
                }
                #pragma unroll
                for (int fj = 0; fj < 4; ++fj) {
                    float tb = fast_tanh(bdv[(rel * 2 + l) * 64 + fj * 16 + lr]);
                    #pragma unroll
                    for (int fi = 0; fi < 2; ++fi)
                        #pragma unroll
                        for (int reg = 0; reg < 4; ++reg) {
                            hacc[fi][fj][reg] += fmaxf(cacc[fi][fj][reg], 0.f);
                            hacc[fi][fj][reg] += tb;
                        }
                }
            }
        }
    }

    // ---- epilogue: stage in LDS (zero pad rows n>=500), emit XSB bf16 (+ XT for l=0) ----
    __shared__ float staged[32][65];
    #pragma unroll
    for (int fi = 0; fi < 2; ++fi)
        #pragma unroll
        for (int reg = 0; reg < 4; ++reg) {
            int rloc = fi * 16 + (lane >> 4) * 4 + reg;
            bool ok = (n0 + rloc) < N_;
            #pragma unroll
            for (int fj = 0; fj < 4; ++fj)
                staged[rloc][fj * 16 + lr] = ok ? hacc[fi][fj][reg] : 0.f;
        }
    __syncthreads();

    ushort* __restrict__ Xb = xsb_out + (size_t)i * MND_;
    #pragma unroll
    for (int q = 0; q < 32; ++q) {
        if (n0 + q < N_)
            Xb[(size_t)(r0 + q) * 64 + lane] = to_bf16u(staged[q][lane]);
    }
    if (write_xt) {
        size_t tb = ((size_t)(i * 96 + m) * 64 + lane) * 512 + n0;
        #pragma unroll
        for (int g = 0; g < 4; ++g) {
            short8 hv;
            #pragma unroll
            for (int q = 0; q < 8; ++q)
                hv[q] = (short)to_bf16u(staged[g * 8 + q][lane]);
            *(short8*)(xt_out + tb + g * 8) = hv;
        }
    }
}

// ---------------- K5: summarize (round-10/11 proven version) ----------------
__global__ __launch_bounds__(192) void summarize(
        const ushort* __restrict__ XSB, const int* __restrict__ nbr,
        const float* __restrict__ nw, float* __restrict__ out) {
    int wg = (blockIdx.x & 7) * 252 + (blockIdx.x >> 3);
    int grp = wg / 126;
    int rem = wg % 126;
    int i = grp >> 3, b = grp & 7;
    int l = rem / 42;
    int rem2 = rem % 42;
    int t = rem2 / 21;
    int tile = rem2 % 21;
    int n0 = tile * 24;
    int tid = threadIdx.x;
    int sub = tid >> 6;
    int d = tid & 63;

    __shared__ int   nb_s[24][20];
    __shared__ float w_s[24][20];
    __shared__ float staged[64][145];

    for (int e = tid; e < 480; e += 192) {
        int nn = e / 20, k = e % 20;
        int n = n0 + nn;
        nb_s[nn][k] = (n < N_) ? nbr[((size_t)t * N_ + n) * K_ + k] : 0;
        w_s[nn][k]  = (n < N_) ? nw[((size_t)t * N_ + n) * K_ + k] : 0.f;
    }
    __syncthreads();

    const ushort* __restrict__ Xbase = XSB + ((size_t)l * 2 + i) * MND_
                                     + (size_t)b * T_ * N_ * D_ + d;
    size_t obase = ((size_t)((i * 8 + b) * 384 + t * 192 + l * 64)) * 6000
                 + (size_t)n0 * 12;

    #pragma unroll
    for (int half = 0; half < 2; ++half) {
        #pragma unroll
        for (int nn2 = 0; nn2 < 4; ++nn2) {
            int pl = sub * 4 + nn2;
            int nl = half * 12 + pl;
            #pragma unroll
            for (int tt0 = 0; tt0 < 12; tt0 += 4) {
                const ushort* __restrict__ Xm0 = Xbase + (size_t)(tt0 + 0) * N_ * D_;
                const ushort* __restrict__ Xm1 = Xbase + (size_t)(tt0 + 1) * N_ * D_;
                const ushort* __restrict__ Xm2 = Xbase + (size_t)(tt0 + 2) * N_ * D_;
                const ushort* __restrict__ Xm3 = Xbase + (size_t)(tt0 + 3) * N_ * D_;
                float a0 = 0.f, a1 = 0.f, a2 = 0.f, a3 = 0.f;
                #pragma unroll
                for (int k = 0; k < K_; ++k) {
                    size_t off = (size_t)nb_s[nl][k] * D_;
                    float w = w_s[nl][k];
                    a0 = fmaf(__uint_as_float((uint)Xm0[off] << 16), w, a0);
                    a1 = fmaf(__uint_as_float((uint)Xm1[off] << 16), w, a1);
                    a2 = fmaf(__uint_as_float((uint)Xm2[off] << 16), w, a2);
                    a3 = fmaf(__uint_as_float((uint)Xm3[off] << 16), w, a3);
                }
                staged[d][pl * 12 + tt0 + 0] = a0;
                staged[d][pl * 12 + tt0 + 1] = a1;
                staged[d][pl * 12 + tt0 + 2] = a2;
                staged[d][pl * 12 + tt0 + 3] = a3;
            }
        }
        __syncthreads();
        int base_n = n0 + half * 12;
        int plim = (N_ - base_n) * 12;
        if (plim > 144) plim = 144;
        if (plim > 0) {
            for (int it = 0; it < 48; ++it) {
                int e = it * 192 + tid;
                int c2 = e / 144, q = e % 144;
                if (q < plim)
                    out[obase + (size_t)c2 * 6000 + (size_t)half * 144 + q] = staged[c2][q];
            }
        }
        __syncthreads();
    }
}

extern "C" void kernel_launch(void* const* d_in, const int* in_sizes, int n_in,
                              void* d_out, int out_size, void* d_ws, size_t ws_size,
                              hipStream_t stream) {
    const float* x0     = (const float*)d_in[0];
    const float* x1     = (const float*)d_in[1];
    const float* graphs = (const float*)d_in[2];
    const int*   nbr    = (const int*)d_in[3];
    const float* nwt    = (const float*)d_in[4];
    const float* aw     = (const float*)d_in[5];
    const float* Bw     = (const float*)d_in[6];
    const float* ab     = (const float*)d_in[7];
    const float* Bb     = (const float*)d_in[8];
    float* out = (float*)d_out;
    float* ws  = (float*)d_ws;

    ushort* XSB = (ushort*)(ws + XSB_OFF);
    ushort* AGh = (ushort*)(ws + AGH_OFF);
    ushort* ATh = (ushort*)(ws + AT_HI_OFF);
    ushort* ATl = (ushort*)(ws + AT_LO_OFF);
    ushort* XT  = (ushort*)(ws + XT_OFF);
    ushort* WCT = (ushort*)(ws + WCT_OFF);
    ushort* WDT = (ushort*)(ws + WDT_OFF);
    float*  BC  = ws + BC_OFF;
    float*  BD  = ws + BD_OFF;

    fuse_weights<<<520, 256, 0, stream>>>(aw, Bw, ab, Bb, BC, BD, WCT, WDT);
    transpose_in<<<8000, 256, 0, stream>>>(x0, x1, XSB);
    adj_prep<<<dim3(16, 16, 2), 256, 0, stream>>>(graphs, ATh, ATl);
    xt_cast<<<dim3(8, 96, 2), 256, 0, stream>>>(XSB, XT);   // layer 0 only
    for (int l = 0; l < 2; ++l) {
        aggregate_mfma<<<3072, 64, 0, stream>>>(ATh, ATl, XT, AGh);
        combine_mfma<<<dim3(16, 96, 2), 64, 0, stream>>>(
            AGh, WCT, WDT, BC, BD,
            XSB + (size_t)(l + 1) * 2 * MND_, XT, l, (l == 0) ? 1 : 0);
    }
    summarize<<<2016, 192, 0, stream>>>(XSB, nbr, nwt, out);
}

// Round 14
// 325.516 us; speedup vs baseline: 3.6804x; 1.2141x over previous
//
#include <hip/hip_runtime.h>
#include <hip/hip_bf16.h>
#include <math.h>

#define B_ 8
#define T_ 12
#define N_ 500
#define D_ 64
#define K_ 20
#define M_ (B_*T_)              // 96
#define MND_ 3072000            // M_*N_*D_

// workspace layout (float units)
#define XSB_OFF 0ul                         // 6 slices x MND ushort = 3*MND f
#define AGH_OFF (3ul*MND_)                  // 4*MND ushort = 2*MND f (agg single bf16)
#define AT_HI_OFF (5ul*MND_)                // 2*512*512 ushort = 262144 f (adj single bf16)
#define XT_OFF    (AT_HI_OFF + 262144ul)    // 2*96*64*512 ushort = 3145728 f
#define WCT_OFF   (XT_OFF + 3145728ul)      // 16*4096 bf16 = 32768 f
#define WDT_OFF   (WCT_OFF + 32768ul)
#define BC_OFF    (WDT_OFF + 32768ul)       // 8*2*64 fp32
#define BD_OFF    (BC_OFF + 1024ul)
// end ~75 MB

using f4 = __attribute__((ext_vector_type(4))) float;
typedef __attribute__((ext_vector_type(8))) short bf16x8;
typedef __attribute__((ext_vector_type(8))) short short8;
typedef __attribute__((ext_vector_type(4))) float f32x4;

__device__ inline ushort to_bf16u(float v) {
    __hip_bfloat16 b = __float2bfloat16(v);
    return *reinterpret_cast<ushort*>(&b);
}

// fast tanh: 1 - 2/(e^{2x}+1)
__device__ inline float fast_tanh(float x) {
    float u = __expf(2.0f * x);
    return 1.0f - 2.0f * __builtin_amdgcn_rcpf(u + 1.0f);
}

// ---------------- K1: fuse head-mixture weights (transposed bf16 + fp32 biases) ----------------
__global__ __launch_bounds__(256) void fuse_weights(
        const float* __restrict__ aw, const float* __restrict__ Bw,
        const float* __restrict__ ab, const float* __restrict__ Bb,
        float* __restrict__ bc, float* __restrict__ bd,
        ushort* __restrict__ wct, ushort* __restrict__ wdt) {
    int e = blockIdx.x * 256 + threadIdx.x;
    if (e < 131072) {
        int dd = e & 4095; int l = (e >> 12) & 1; int r = (e >> 13) & 7; int cd = e >> 16;
        float s = 0.f;
        #pragma unroll
        for (int h = 0; h < 4; ++h)
            s += aw[((cd*8 + r)*4 + h)*2 + l] * Bw[(h*2 + l)*4096 + dd];
        int tidx = (r*2 + l)*4096 + (dd & 63)*64 + (dd >> 6);
        (cd ? wdt : wct)[tidx] = to_bf16u(s);
    } else {
        int e2 = e - 131072;
        if (e2 < 2048) {
            int d = e2 & 63; int l = (e2 >> 6) & 1; int r = (e2 >> 7) & 7; int cd = e2 >> 10;
            float s = 0.f;
            #pragma unroll
            for (int h = 0; h < 4; ++h)
                s += ab[((cd*8 + r)*4 + h)*2 + l] * Bb[(h*2 + l)*64 + d];
            (cd ? bd : bc)[(r*2 + l)*64 + d] = s;
        }
    }
}

// ---------------- K2: [B,D,N,T] -> [M,N,D] transpose, bf16 output only ----------------
__global__ __launch_bounds__(256) void transpose_in(
        const float* __restrict__ x0, const float* __restrict__ x1,
        ushort* __restrict__ xsb0) {
    int bid = blockIdx.x;
    int n = bid % N_; int b = (bid / N_) % B_; int i = bid / (N_ * B_);
    const float* __restrict__ x = i ? x1 : x0;
    ushort* __restrict__ xbo = xsb0 + (size_t)i * MND_;
    __shared__ float tile[64][13];
    #pragma unroll
    for (int q = 0; q < 3; ++q) {
        int e = q * 256 + threadIdx.x;
        int d = e / 12, t = e % 12;
        tile[d][t] = x[(((size_t)b * D_ + d) * N_ + n) * T_ + t];
    }
    __syncthreads();
    #pragma unroll
    for (int q = 0; q < 3; ++q) {
        int e = q * 256 + threadIdx.x;
        int t = e >> 6, d = e & 63;
        xbo[(((size_t)b * T_ + t) * N_ + n) * D_ + d] = to_bf16u(tile[d][t]);
    }
}

// ---------------- K3a: adjT bf16 prep (single bf16) ----------------
__global__ __launch_bounds__(256) void adj_prep(
        const float* __restrict__ graphs,
        ushort* __restrict__ AT_hi) {
    int t = blockIdx.z;
    int n0 = blockIdx.x * 32, mm0 = blockIdx.y * 32;
    __shared__ float tile[32][33];
    int cc = threadIdx.x & 31, rr = threadIdx.x >> 5;
    #pragma unroll
    for (int it = 0; it < 4; ++it) {
        int n = n0 + it * 8 + rr, mm = mm0 + cc;
        tile[it * 8 + rr][cc] = (n < N_ && mm < N_)
            ? graphs[(size_t)t * 250000 + (size_t)n * 500 + mm] : 0.f;
    }
    __syncthreads();
    #pragma unroll
    for (int it = 0; it < 4; ++it) {
        int mml = it * 8 + rr, nl = cc;
        size_t idx = (size_t)t * 262144 + (size_t)(mm0 + mml) * 512 + n0 + nl;
        AT_hi[idx] = to_bf16u(tile[nl][mml]);
    }
}

// ---------------- K3b: XT from XSB stage-0 — pure ushort transpose (layer 0 only) ----------------
__global__ __launch_bounds__(256) void xt_cast(
        const ushort* __restrict__ xsb,
        ushort* __restrict__ XT) {
    int i = blockIdx.z, m = blockIdx.y, c = blockIdx.x;   // c = n-chunk (0..7)
    int n0 = c * 64;
    __shared__ ushort tile[64][65];
    int d = threadIdx.x & 63, r4 = threadIdx.x >> 6;
    const ushort* __restrict__ src = xsb + (size_t)i * MND_ + (size_t)m * 32000;
    #pragma unroll
    for (int it = 0; it < 16; ++it) {
        int nl = it * 4 + r4; int n = n0 + nl;
        tile[nl][d] = (n < N_) ? src[(size_t)n * 64 + d] : (ushort)0;
    }
    __syncthreads();
    size_t base = (size_t)(i * 96 + m) * 64 * 512 + n0;
    int dl = threadIdx.x >> 2, ng = threadIdx.x & 3;
    #pragma unroll
    for (int half = 0; half < 2; ++half) {
        int nlb = ng * 16 + half * 8;
        short8 hv;
        #pragma unroll
        for (int q = 0; q < 8; ++q) hv[q] = (short)tile[nlb + q][dl];
        *(short8*)(XT + base + (size_t)dl * 512 + nlb) = hv;
    }
}

// ---------------- K3c: aggregation via MFMA, single product (bf16 adj x bf16 X) ----------------
__global__ __launch_bounds__(64) void aggregate_mfma(
        const ushort* __restrict__ AT_hi,
        const ushort* __restrict__ XT, ushort* __restrict__ aggh) {
    int w = (blockIdx.x & 7) * 384 + (blockIdx.x >> 3);
    const int mm0 = (w & 7) * 64;
    int g = w >> 3;
    const int m = g % 96;
    const int cmb = g / 96;
    const int t = cmb >> 1, j = cmb & 1;
    const int lane = threadIdx.x;
    const int lr = lane & 15;
    const int lk = (lane >> 4) * 8;

    const ushort* __restrict__ A_h = AT_hi + (size_t)t * 262144 + (size_t)(mm0 + lr) * 512 + lk;
    const ushort* __restrict__ Bx  = XT + ((size_t)(j * 96 + m) * 64 + lr) * 512 + lk;

    f32x4 acc[4][4] = {};

    for (int k0 = 0; k0 < 512; k0 += 32) {
        bf16x8 ah[4], bh[4];
        #pragma unroll
        for (int f = 0; f < 4; ++f) {
            ah[f] = *(const bf16x8*)(A_h + (size_t)f * 8192 + k0);
            bh[f] = *(const bf16x8*)(Bx  + (size_t)f * 8192 + k0);
        }
        #pragma unroll
        for (int fi = 0; fi < 4; ++fi)
            #pragma unroll
            for (int fj = 0; fj < 4; ++fj)
                acc[fi][fj] = __builtin_amdgcn_mfma_f32_16x16x32_bf16(ah[fi], bh[fj], acc[fi][fj], 0, 0, 0);
    }

    size_t obase = (size_t)cmb * MND_ + (size_t)m * 32000;
    #pragma unroll
    for (int fi = 0; fi < 4; ++fi) {
        #pragma unroll
        for (int reg = 0; reg < 4; ++reg) {
            int row = mm0 + fi * 16 + (lane >> 4) * 4 + reg;
            if (row < N_) {
                #pragma unroll
                for (int fj = 0; fj < 4; ++fj)
                    aggh[obase + (size_t)row * 64 + fj * 16 + lr] = to_bf16u(acc[fi][fj][reg]);
            }
        }
    }
}

// ---------------- K4: combine via MFMA (round-13 proven) ----------------
__global__ __launch_bounds__(64) void combine_mfma(
        const ushort* __restrict__ aggh,
        const ushort* __restrict__ wct, const ushort* __restrict__ wdt,
        const float* __restrict__ bcv, const float* __restrict__ bdv,
        ushort* __restrict__ xsb_out,
        ushort* __restrict__ xt_out, int l, int write_xt) {
    const int tile = blockIdx.x;
    const int m = blockIdx.y;
    const int i = blockIdx.z;
    const int n0 = tile * 32;
    const int r0 = m * 500 + n0;
    const int lane = threadIdx.x;
    const int lr = lane & 15;
    const int lk = (lane >> 4) * 8;

    f32x4 hacc[2][4] = {};

    for (int t = 0; t < 2; ++t) {
        #pragma unroll
        for (int j = 0; j < 2; ++j) {
            const int rel = (t * 2 + i) * 2 + j;
            const int wb = (rel * 2 + l) * 4096;
            const ushort* __restrict__ Ajh = aggh + (size_t)(t * 2 + j) * MND_ + (size_t)(r0 + lr) * 64 + lk;
            const ushort* __restrict__ Wc = wct + wb + lr * 64 + lk;

            f32x4 cacc[2][4];
            #pragma unroll
            for (int fj = 0; fj < 4; ++fj) {
                float bv = bcv[(rel * 2 + l) * 64 + fj * 16 + lr];
                #pragma unroll
                for (int fi = 0; fi < 2; ++fi) cacc[fi][fj] = f32x4{bv, bv, bv, bv};
            }

            if (j != i) {
                const ushort* __restrict__ Aih = aggh + (size_t)(t * 2 + i) * MND_ + (size_t)(r0 + lr) * 64 + lk;
                const ushort* __restrict__ Wd = wdt + wb + lr * 64 + lk;
                f32x4 dacc[2][4];
                #pragma unroll
                for (int fj = 0; fj < 4; ++fj) {
                    float bv = bdv[(rel * 2 + l) * 64 + fj * 16 + lr];
                    #pragma unroll
                    for (int fi = 0; fi < 2; ++fi) dacc[fi][fj] = f32x4{bv, bv, bv, bv};
                }
                #pragma unroll
                for (int k0 = 0; k0 < 64; k0 += 32) {
                    bf16x8 ajh[2], nih[2], wcf[4], wdf[4];
                    #pragma unroll
                    for (int fi = 0; fi < 2; ++fi) {
                        ajh[fi] = *(const bf16x8*)(Ajh + fi * 1024 + k0);
                        bf16x8 ih = *(const bf16x8*)(Aih + fi * 1024 + k0);
                        #pragma unroll
                        for (int q = 0; q < 8; ++q) nih[fi][q] = ih[q] ^ (short)0x8000;
                    }
                    #pragma unroll
                    for (int fj = 0; fj < 4; ++fj) {
                        wcf[fj] = *(const bf16x8*)(Wc + fj * 1024 + k0);
                        wdf[fj] = *(const bf16x8*)(Wd + fj * 1024 + k0);
                    }
                    #pragma unroll
                    for (int fi = 0; fi < 2; ++fi)
                        #pragma unroll
                        for (int fj = 0; fj < 4; ++fj) {
                            cacc[fi][fj] = __builtin_amdgcn_mfma_f32_16x16x32_bf16(ajh[fi], wcf[fj], cacc[fi][fj], 0, 0, 0);
                            dacc[fi][fj] = __builtin_amdgcn_mfma_f32_16x16x32_bf16(ajh[fi], wdf[fj], dacc[fi][fj], 0, 0, 0);
                            dacc[fi][fj] = __builtin_amdgcn_mfma_f32_16x16x32_bf16(nih[fi], wdf[fj], dacc[fi][fj], 0, 0, 0);
                        }
                }
                #pragma unroll
                for (int fi = 0; fi < 2; ++fi)
                    #pragma unroll
                    for (int fj = 0; fj < 4; ++fj)
                        #pragma unroll
                        for (int reg = 0; reg < 4; ++reg) {
                            hacc[fi][fj][reg] += fmaxf(cacc[fi][fj][reg], 0.f);
                            hacc[fi][fj][reg] += fast_tanh(dacc[fi][fj][reg]);
                        }
            } else {
                #pragma unroll
                for (int k0 = 0; k0 < 64; k0 += 32) {
                    bf16x8 ajh[2], wcf[4];
                    #pragma unroll
                    for (int fi = 0; fi < 2; ++fi)
                        ajh[fi] = *(const bf16x8*)(Ajh + fi * 1024 + k0);
                    #pragma unroll
                    for (int fj = 0; fj < 4; ++fj)
                        wcf[fj] = *(const bf16x8*)(Wc + fj * 1024 + k0);
                    #pragma unroll
                    for (int fi = 0; fi < 2; ++fi)
                        #pragma unroll
                        for (int fj = 0; fj < 4; ++fj)
                            cacc[fi][fj] = __builtin_amdgcn_mfma_f32_16x16x32_bf16(ajh[fi], wcf[fj], cacc[fi][fj], 0, 0, 0);
                }
                #pragma unroll
                for (int fj = 0; fj < 4; ++fj) {
                    float tb = fast_tanh(bdv[(rel * 2 + l) * 64 + fj * 16 + lr]);
                    #pragma unroll
                    for (int fi = 0; fi < 2; ++fi)
                        #pragma unroll
                        for (int reg = 0; reg < 4; ++reg) {
                            hacc[fi][fj][reg] += fmaxf(cacc[fi][fj][reg], 0.f);
                            hacc[fi][fj][reg] += tb;
                        }
                }
            }
        }
    }

    // ---- epilogue: stage in LDS (zero pad rows n>=500), emit XSB bf16 (+ XT for l=0) ----
    __shared__ float staged[32][65];
    #pragma unroll
    for (int fi = 0; fi < 2; ++fi)
        #pragma unroll
        for (int reg = 0; reg < 4; ++reg) {
            int rloc = fi * 16 + (lane >> 4) * 4 + reg;
            bool ok = (n0 + rloc) < N_;
            #pragma unroll
            for (int fj = 0; fj < 4; ++fj)
                staged[rloc][fj * 16 + lr] = ok ? hacc[fi][fj][reg] : 0.f;
        }
    __syncthreads();

    ushort* __restrict__ Xb = xsb_out + (size_t)i * MND_;
    #pragma unroll
    for (int q = 0; q < 32; ++q) {
        if (n0 + q < N_)
            Xb[(size_t)(r0 + q) * 64 + lane] = to_bf16u(staged[q][lane]);
    }
    if (write_xt) {
        size_t tb = ((size_t)(i * 96 + m) * 64 + lane) * 512 + n0;
        #pragma unroll
        for (int g = 0; g < 4; ++g) {
            short8 hv;
            #pragma unroll
            for (int q = 0; q < 8; ++q)
                hv[q] = (short)to_bf16u(staged[g * 8 + q][lane]);
            *(short8*)(xt_out + tb + g * 8) = hv;
        }
    }
}

// ---------------- K5: summarize — pair-channel gather (uint loads, 2 ch/thread) ----------------
// 192 thr = 32 channel-pairs x 6 node-groups; per gather one uint (2 bf16).
// Decomposition, barriers, staged layout, flush all unchanged from round 13.
__global__ __launch_bounds__(192) void summarize(
        const ushort* __restrict__ XSB, const int* __restrict__ nbr,
        const float* __restrict__ nw, float* __restrict__ out) {
    int wg = (blockIdx.x & 7) * 252 + (blockIdx.x >> 3);
    int grp = wg / 126;
    int rem = wg % 126;
    int i = grp >> 3, b = grp & 7;
    int l = rem / 42;
    int rem2 = rem % 42;
    int t = rem2 / 21;
    int tile = rem2 % 21;
    int n0 = tile * 24;
    int tid = threadIdx.x;
    int g6 = tid >> 5;           // node group 0..5
    int d2 = tid & 31;           // channel pair: channels 2*d2, 2*d2+1

    __shared__ int   nb_s[24][20];
    __shared__ float w_s[24][20];
    __shared__ float staged[64][145];

    for (int e = tid; e < 480; e += 192) {
        int nn = e / 20, k = e % 20;
        int n = n0 + nn;
        nb_s[nn][k] = (n < N_) ? nbr[((size_t)t * N_ + n) * K_ + k] : 0;
        w_s[nn][k]  = (n < N_) ? nw[((size_t)t * N_ + n) * K_ + k] : 0.f;
    }
    __syncthreads();

    const uint* __restrict__ Xbase = (const uint*)(XSB + ((size_t)l * 2 + i) * MND_
                                     + (size_t)b * T_ * N_ * D_) + d2;
    size_t obase = ((size_t)((i * 8 + b) * 384 + t * 192 + l * 64)) * 6000
                 + (size_t)n0 * 12;

    #pragma unroll
    for (int half = 0; half < 2; ++half) {
        #pragma unroll
        for (int nn2 = 0; nn2 < 2; ++nn2) {
            int pl = g6 * 2 + nn2;           // in-half node 0..11
            int nl = half * 12 + pl;
            #pragma unroll
            for (int tt0 = 0; tt0 < 12; tt0 += 4) {
                const uint* __restrict__ Xm0 = Xbase + (size_t)(tt0 + 0) * 16000;
                const uint* __restrict__ Xm1 = Xbase + (size_t)(tt0 + 1) * 16000;
                const uint* __restrict__ Xm2 = Xbase + (size_t)(tt0 + 2) * 16000;
                const uint* __restrict__ Xm3 = Xbase + (size_t)(tt0 + 3) * 16000;
                float a0l = 0.f, a0h = 0.f, a1l = 0.f, a1h = 0.f;
                float a2l = 0.f, a2h = 0.f, a3l = 0.f, a3h = 0.f;
                #pragma unroll
                for (int k = 0; k < K_; ++k) {
                    size_t off = (size_t)nb_s[nl][k] * 32;
                    float w = w_s[nl][k];
                    uint u0 = Xm0[off], u1 = Xm1[off], u2 = Xm2[off], u3 = Xm3[off];
                    a0l = fmaf(__uint_as_float(u0 << 16), w, a0l);
                    a0h = fmaf(__uint_as_float(u0 & 0xffff0000u), w, a0h);
                    a1l = fmaf(__uint_as_float(u1 << 16), w, a1l);
                    a1h = fmaf(__uint_as_float(u1 & 0xffff0000u), w, a1h);
                    a2l = fmaf(__uint_as_float(u2 << 16), w, a2l);
                    a2h = fmaf(__uint_as_float(u2 & 0xffff0000u), w, a2h);
                    a3l = fmaf(__uint_as_float(u3 << 16), w, a3l);
                    a3h = fmaf(__uint_as_float(u3 & 0xffff0000u), w, a3h);
                }
                int p = pl * 12 + tt0;
                staged[2 * d2 + 0][p + 0] = a0l;  staged[2 * d2 + 1][p + 0] = a0h;
                staged[2 * d2 + 0][p + 1] = a1l;  staged[2 * d2 + 1][p + 1] = a1h;
                staged[2 * d2 + 0][p + 2] = a2l;  staged[2 * d2 + 1][p + 2] = a2h;
                staged[2 * d2 + 0][p + 3] = a3l;  staged[2 * d2 + 1][p + 3] = a3h;
            }
        }
        __syncthreads();
        int base_n = n0 + half * 12;
        int plim = (N_ - base_n) * 12;
        if (plim > 144) plim = 144;
        if (plim > 0) {
            for (int it = 0; it < 48; ++it) {
                int e = it * 192 + tid;
                int c2 = e / 144, q = e % 144;
                if (q < plim)
                    out[obase + (size_t)c2 * 6000 + (size_t)half * 144 + q] = staged[c2][q];
            }
        }
        __syncthreads();
    }
}

extern "C" void kernel_launch(void* const* d_in, const int* in_sizes, int n_in,
                              void* d_out, int out_size, void* d_ws, size_t ws_size,
                              hipStream_t stream) {
    const float* x0     = (const float*)d_in[0];
    const float* x1     = (const float*)d_in[1];
    const float* graphs = (const float*)d_in[2];
    const int*   nbr    = (const int*)d_in[3];
    const float* nwt    = (const float*)d_in[4];
    const float* aw     = (const float*)d_in[5];
    const float* Bw     = (const float*)d_in[6];
    const float* ab     = (const float*)d_in[7];
    const float* Bb     = (const float*)d_in[8];
    float* out = (float*)d_out;
    float* ws  = (float*)d_ws;

    ushort* XSB = (ushort*)(ws + XSB_OFF);
    ushort* AGh = (ushort*)(ws + AGH_OFF);
    ushort* ATh = (ushort*)(ws + AT_HI_OFF);
    ushort* XT  = (ushort*)(ws + XT_OFF);
    ushort* WCT = (ushort*)(ws + WCT_OFF);
    ushort* WDT = (ushort*)(ws + WDT_OFF);
    float*  BC  = ws + BC_OFF;
    float*  BD  = ws + BD_OFF;

    fuse_weights<<<520, 256, 0, stream>>>(aw, Bw, ab, Bb, BC, BD, WCT, WDT);
    transpose_in<<<8000, 256, 0, stream>>>(x0, x1, XSB);
    adj_prep<<<dim3(16, 16, 2), 256, 0, stream>>>(graphs, ATh);
    xt_cast<<<dim3(8, 96, 2), 256, 0, stream>>>(XSB, XT);   // layer 0 only
    for (int l = 0; l < 2; ++l) {
        aggregate_mfma<<<3072, 64, 0, stream>>>(ATh, XT, AGh);
        combine_mfma<<<dim3(16, 96, 2), 64, 0, stream>>>(
            AGh, WCT, WDT, BC, BD,
            XSB + (size_t)(l + 1) * 2 * MND_, XT, l, (l == 0) ? 1 : 0);
    }
    summarize<<<2016, 192, 0, stream>>>(XSB, nbr, nwt, out);
}

// Round 17
// 288.746 us; speedup vs baseline: 4.1491x; 1.1273x over previous
//
#include <hip/hip_runtime.h>
#include <hip/hip_bf16.h>
#include <math.h>

#define B_ 8
#define T_ 12
#define N_ 500
#define D_ 64
#define K_ 20
#define M_ (B_*T_)              // 96
#define MND_ 3072000            // M_*N_*D_

// workspace layout (float units)
#define XSB_OFF 0ul                         // 6 slices x MND ushort = 3*MND f
#define XTB_OFF (3ul*MND_)                  // XT ping-pong buf B: 3145728 f
#define AT_HI_OFF (5ul*MND_)                // 2*512*512 ushort = 262144 f
#define XT_OFF    (AT_HI_OFF + 262144ul)    // XT buf A: 3145728 f
#define WCT_OFF   (XT_OFF + 3145728ul)
#define WDT_OFF   (WCT_OFF + 32768ul)
#define BC_OFF    (WDT_OFF + 32768ul)
#define BD_OFF    (BC_OFF + 1024ul)

using f4 = __attribute__((ext_vector_type(4))) float;
typedef __attribute__((ext_vector_type(8))) short bf16x8;
typedef __attribute__((ext_vector_type(8))) short short8;
typedef __attribute__((ext_vector_type(4))) float f32x4;

__device__ inline ushort to_bf16u(float v) {
    __hip_bfloat16 b = __float2bfloat16(v);
    return *reinterpret_cast<ushort*>(&b);
}

// fast tanh: 1 - 2/(e^{2x}+1)
__device__ inline float fast_tanh(float x) {
    float u = __expf(2.0f * x);
    return 1.0f - 2.0f * __builtin_amdgcn_rcpf(u + 1.0f);
}

// ---------------- K1: fuse head-mixture weights ----------------
__global__ __launch_bounds__(256) void fuse_weights(
        const float* __restrict__ aw, const float* __restrict__ Bw,
        const float* __restrict__ ab, const float* __restrict__ Bb,
        float* __restrict__ bc, float* __restrict__ bd,
        ushort* __restrict__ wct, ushort* __restrict__ wdt) {
    int e = blockIdx.x * 256 + threadIdx.x;
    if (e < 131072) {
        int dd = e & 4095; int l = (e >> 12) & 1; int r = (e >> 13) & 7; int cd = e >> 16;
        float s = 0.f;
        #pragma unroll
        for (int h = 0; h < 4; ++h)
            s += aw[((cd*8 + r)*4 + h)*2 + l] * Bw[(h*2 + l)*4096 + dd];
        int tidx = (r*2 + l)*4096 + (dd & 63)*64 + (dd >> 6);
        (cd ? wdt : wct)[tidx] = to_bf16u(s);
    } else {
        int e2 = e - 131072;
        if (e2 < 2048) {
            int d = e2 & 63; int l = (e2 >> 6) & 1; int r = (e2 >> 7) & 7; int cd = e2 >> 10;
            float s = 0.f;
            #pragma unroll
            for (int h = 0; h < 4; ++h)
                s += ab[((cd*8 + r)*4 + h)*2 + l] * Bb[(h*2 + l)*64 + d];
            (cd ? bd : bc)[(r*2 + l)*64 + d] = s;
        }
    }
}

// ---------------- K2: [B,D,N,T] -> [M,N,D] transpose, bf16 output ----------------
__global__ __launch_bounds__(256) void transpose_in(
        const float* __restrict__ x0, const float* __restrict__ x1,
        ushort* __restrict__ xsb0) {
    int bid = blockIdx.x;
    int n = bid % N_; int b = (bid / N_) % B_; int i = bid / (N_ * B_);
    const float* __restrict__ x = i ? x1 : x0;
    ushort* __restrict__ xbo = xsb0 + (size_t)i * MND_;
    __shared__ float tile[64][13];
    #pragma unroll
    for (int q = 0; q < 3; ++q) {
        int e = q * 256 + threadIdx.x;
        int d = e / 12, t = e % 12;
        tile[d][t] = x[(((size_t)b * D_ + d) * N_ + n) * T_ + t];
    }
    __syncthreads();
    #pragma unroll
    for (int q = 0; q < 3; ++q) {
        int e = q * 256 + threadIdx.x;
        int t = e >> 6, d = e & 63;
        xbo[(((size_t)b * T_ + t) * N_ + n) * D_ + d] = to_bf16u(tile[d][t]);
    }
}

// ---------------- K3a: adjT bf16 prep ----------------
__global__ __launch_bounds__(256) void adj_prep(
        const float* __restrict__ graphs,
        ushort* __restrict__ AT_hi) {
    int t = blockIdx.z;
    int n0 = blockIdx.x * 32, mm0 = blockIdx.y * 32;
    __shared__ float tile[32][33];
    int cc = threadIdx.x & 31, rr = threadIdx.x >> 5;
    #pragma unroll
    for (int it = 0; it < 4; ++it) {
        int n = n0 + it * 8 + rr, mm = mm0 + cc;
        tile[it * 8 + rr][cc] = (n < N_ && mm < N_)
            ? graphs[(size_t)t * 250000 + (size_t)n * 500 + mm] : 0.f;
    }
    __syncthreads();
    #pragma unroll
    for (int it = 0; it < 4; ++it) {
        int mml = it * 8 + rr, nl = cc;
        size_t idx = (size_t)t * 262144 + (size_t)(mm0 + mml) * 512 + n0 + nl;
        AT_hi[idx] = to_bf16u(tile[nl][mml]);
    }
}

// ---------------- K3b: XT(A) from XSB stage-0 — ushort transpose ----------------
__global__ __launch_bounds__(256) void xt_cast(
        const ushort* __restrict__ xsb,
        ushort* __restrict__ XT) {
    int i = blockIdx.z, m = blockIdx.y, c = blockIdx.x;
    int n0 = c * 64;
    __shared__ ushort tile[64][65];
    int d = threadIdx.x & 63, r4 = threadIdx.x >> 6;
    const ushort* __restrict__ src = xsb + (size_t)i * MND_ + (size_t)m * 32000;
    #pragma unroll
    for (int it = 0; it < 16; ++it) {
        int nl = it * 4 + r4; int n = n0 + nl;
        tile[nl][d] = (n < N_) ? src[(size_t)n * 64 + d] : (ushort)0;
    }
    __syncthreads();
    size_t base = (size_t)(i * 96 + m) * 64 * 512 + n0;
    int dl = threadIdx.x >> 2, ng = threadIdx.x & 3;
    #pragma unroll
    for (int half = 0; half < 2; ++half) {
        int nlb = ng * 16 + half * 8;
        short8 hv;
        #pragma unroll
        for (int q = 0; q < 8; ++q) hv[q] = (short)tile[nlb + q][dl];
        *(short8*)(XT + base + (size_t)dl * 512 + nlb) = hv;
    }
}

// ---------------- K3+4 fused: aggregate (per-wave cmb) -> LDS -> combine ----------------
__global__ __launch_bounds__(256) void agg_combine_mfma(
        const ushort* __restrict__ ATh, const ushort* __restrict__ XT,
        const ushort* __restrict__ wct, const ushort* __restrict__ wdt,
        const float* __restrict__ bcv, const float* __restrict__ bdv,
        ushort* __restrict__ xsb_out, ushort* __restrict__ xt_out,
        int l, int write_xt) {
    const int rt = blockIdx.x;
    const int m = blockIdx.y;
    const int n0 = rt * 64;
    const int tid = threadIdx.x;
    const int w = tid >> 6;
    const int lane = tid & 63;
    const int lr = lane & 15;
    const int lk = (lane >> 4) * 8;

    __shared__ ushort aggL[4][64][72];   // 36 KB

    // ---- phase 1: aggregate cmb = w ----
    {
        const int t = w >> 1, j = w & 1;
        const ushort* __restrict__ A_h = ATh + (size_t)t * 262144 + (size_t)(n0 + lr) * 512 + lk;
        const ushort* __restrict__ Bx  = XT + ((size_t)(j * 96 + m) * 64 + lr) * 512 + lk;
        f32x4 acc[4][4] = {};
        for (int k0 = 0; k0 < 512; k0 += 32) {
            bf16x8 ah[4], bh[4];
            #pragma unroll
            for (int f = 0; f < 4; ++f) {
                ah[f] = *(const bf16x8*)(A_h + (size_t)f * 8192 + k0);
                bh[f] = *(const bf16x8*)(Bx  + (size_t)f * 8192 + k0);
            }
            #pragma unroll
            for (int fi = 0; fi < 4; ++fi)
                #pragma unroll
                for (int fj = 0; fj < 4; ++fj)
                    acc[fi][fj] = __builtin_amdgcn_mfma_f32_16x16x32_bf16(ah[fi], bh[fj], acc[fi][fj], 0, 0, 0);
        }
        #pragma unroll
        for (int fi = 0; fi < 4; ++fi)
            #pragma unroll
            for (int reg = 0; reg < 4; ++reg) {
                int row = fi * 16 + (lane >> 4) * 4 + reg;
                #pragma unroll
                for (int fj = 0; fj < 4; ++fj)
                    aggL[w][row][fj * 16 + lr] = to_bf16u(acc[fi][fj][reg]);
            }
    }
    __syncthreads();

    // ---- phase 2: combine i = w>>1, row half = w&1 ----
    const int iw = w >> 1;
    const int r0l = (w & 1) * 32;
    f32x4 hacc[2][4] = {};

    for (int t = 0; t < 2; ++t) {
        #pragma unroll
        for (int j = 0; j < 2; ++j) {
            const int rel = (t * 2 + iw) * 2 + j;
            const int wb = (rel * 2 + l) * 4096;
            const ushort* __restrict__ Wc = wct + wb + lr * 64 + lk;
            const ushort* __restrict__ AjL = &aggL[t * 2 + j][r0l + lr][lk];

            f32x4 cacc[2][4];
            #pragma unroll
            for (int fj = 0; fj < 4; ++fj) {
                float bv = bcv[(rel * 2 + l) * 64 + fj * 16 + lr];
                #pragma unroll
                for (int fi = 0; fi < 2; ++fi) cacc[fi][fj] = f32x4{bv, bv, bv, bv};
            }

            if (j != iw) {
                const ushort* __restrict__ AiL = &aggL[t * 2 + iw][r0l + lr][lk];
                const ushort* __restrict__ Wd = wdt + wb + lr * 64 + lk;
                f32x4 dacc[2][4];
                #pragma unroll
                for (int fj = 0; fj < 4; ++fj) {
                    float bv = bdv[(rel * 2 + l) * 64 + fj * 16 + lr];
                    #pragma unroll
                    for (int fi = 0; fi < 2; ++fi) dacc[fi][fj] = f32x4{bv, bv, bv, bv};
                }
                #pragma unroll
                for (int k0 = 0; k0 < 64; k0 += 32) {
                    bf16x8 ajh[2], nih[2], wcf[4], wdf[4];
                    #pragma unroll
                    for (int fi = 0; fi < 2; ++fi) {
                        ajh[fi] = *(const bf16x8*)(AjL + fi * 16 * 72 + k0);
                        bf16x8 ih = *(const bf16x8*)(AiL + fi * 16 * 72 + k0);
                        #pragma unroll
                        for (int q = 0; q < 8; ++q) nih[fi][q] = ih[q] ^ (short)0x8000;
                    }
                    #pragma unroll
                    for (int fj = 0; fj < 4; ++fj) {
                        wcf[fj] = *(const bf16x8*)(Wc + fj * 1024 + k0);
                        wdf[fj] = *(const bf16x8*)(Wd + fj * 1024 + k0);
                    }
                    #pragma unroll
                    for (int fi = 0; fi < 2; ++fi)
                        #pragma unroll
                        for (int fj = 0; fj < 4; ++fj) {
                            cacc[fi][fj] = __builtin_amdgcn_mfma_f32_16x16x32_bf16(ajh[fi], wcf[fj], cacc[fi][fj], 0, 0, 0);
                            dacc[fi][fj] = __builtin_amdgcn_mfma_f32_16x16x32_bf16(ajh[fi], wdf[fj], dacc[fi][fj], 0, 0, 0);
                            dacc[fi][fj] = __builtin_amdgcn_mfma_f32_16x16x32_bf16(nih[fi], wdf[fj], dacc[fi][fj], 0, 0, 0);
                        }
                }
                #pragma unroll
                for (int fi = 0; fi < 2; ++fi)
                    #pragma unroll
                    for (int fj = 0; fj < 4; ++fj)
                        #pragma unroll
                        for (int reg = 0; reg < 4; ++reg) {
                            hacc[fi][fj][reg] += fmaxf(cacc[fi][fj][reg], 0.f);
                            hacc[fi][fj][reg] += fast_tanh(dacc[fi][fj][reg]);
                        }
            } else {
                #pragma unroll
                for (int k0 = 0; k0 < 64; k0 += 32) {
                    bf16x8 ajh[2], wcf[4];
                    #pragma unroll
                    for (int fi = 0; fi < 2; ++fi)
                        ajh[fi] = *(const bf16x8*)(AjL + fi * 16 * 72 + k0);
                    #pragma unroll
                    for (int fj = 0; fj < 4; ++fj)
                        wcf[fj] = *(const bf16x8*)(Wc + fj * 1024 + k0);
                    #pragma unroll
                    for (int fi = 0; fi < 2; ++fi)
                        #pragma unroll
                        for (int fj = 0; fj < 4; ++fj)
                            cacc[fi][fj] = __builtin_amdgcn_mfma_f32_16x16x32_bf16(ajh[fi], wcf[fj], cacc[fi][fj], 0, 0, 0);
                }
                #pragma unroll
                for (int fj = 0; fj < 4; ++fj) {
                    float tb = fast_tanh(bdv[(rel * 2 + l) * 64 + fj * 16 + lr]);
                    #pragma unroll
                    for (int fi = 0; fi < 2; ++fi)
                        #pragma unroll
                        for (int reg = 0; reg < 4; ++reg) {
                            hacc[fi][fj][reg] += fmaxf(cacc[fi][fj][reg], 0.f);
                            hacc[fi][fj][reg] += tb;
                        }
                }
            }
        }
    }
    __syncthreads();   // all phase-2 LDS reads done; aggL reusable

    // ---- phase 3: transposed epilogue via LDS overlay ----
    float* stg = ((float*)aggL) + w * 2080;   // 32 x 65 fp32 per wave
    #pragma unroll
    for (int fi = 0; fi < 2; ++fi)
        #pragma unroll
        for (int reg = 0; reg < 4; ++reg) {
            int rloc = fi * 16 + (lane >> 4) * 4 + reg;
            bool ok = (n0 + r0l + rloc) < N_;
            #pragma unroll
            for (int fj = 0; fj < 4; ++fj)
                stg[rloc * 65 + fj * 16 + lr] = ok ? hacc[fi][fj][reg] : 0.f;
        }
    // same-wave LDS raw: ds ops in-order per wave
    ushort* __restrict__ Xb = xsb_out + (size_t)iw * MND_;
    int gbase = m * 500 + n0 + r0l;
    #pragma unroll
    for (int q = 0; q < 32; ++q) {
        if (n0 + r0l + q < N_)
            Xb[(size_t)(gbase + q) * 64 + lane] = to_bf16u(stg[q * 65 + lane]);
    }
    if (write_xt) {
        size_t tb = ((size_t)(iw * 96 + m) * 64 + lane) * 512 + n0 + r0l;
        #pragma unroll
        for (int g2 = 0; g2 < 4; ++g2) {
            short8 hv;
            #pragma unroll
            for (int q = 0; q < 8; ++q)
                hv[q] = (short)to_bf16u(stg[(g2 * 8 + q) * 65 + lane]);
            *(short8*)(xt_out + tb + g2 * 8) = hv;
        }
    }
}

// ---------------- K5: summarize — pair-channel gather, bf16 LDS staging ----------------
// FIX vs r15/16: staged row length stays 144 elements (+pad) — only the
// element SIZE is halved, not the count. ushort[64][145] = 18.6 KB; row
// stride 290B -> dword-bank 17*d2 mod 32 (odd) = permutation, conflict-free.
__global__ __launch_bounds__(192) void summarize(
        const ushort* __restrict__ XSB, const int* __restrict__ nbr,
        const float* __restrict__ nw, float* __restrict__ out) {
    int wg = (blockIdx.x & 7) * 252 + (blockIdx.x >> 3);
    int grp = wg / 126;
    int rem = wg % 126;
    int i = grp >> 3, b = grp & 7;
    int l = rem / 42;
    int rem2 = rem % 42;
    int t = rem2 / 21;
    int tile = rem2 % 21;
    int n0 = tile * 24;
    int tid = threadIdx.x;
    int g6 = tid >> 5;           // node group 0..5
    int d2 = tid & 31;           // channel pair

    __shared__ int    nb_s[24][20];
    __shared__ float  w_s[24][20];
    __shared__ ushort staged[64][145];   // 18.6 KB bf16

    for (int e = tid; e < 480; e += 192) {
        int nn = e / 20, k = e % 20;
        int n = n0 + nn;
        nb_s[nn][k] = (n < N_) ? nbr[((size_t)t * N_ + n) * K_ + k] : 0;
        w_s[nn][k]  = (n < N_) ? nw[((size_t)t * N_ + n) * K_ + k] : 0.f;
    }
    __syncthreads();

    const uint* __restrict__ Xbase = (const uint*)(XSB + ((size_t)l * 2 + i) * MND_
                                     + (size_t)b * T_ * N_ * D_) + d2;
    size_t obase = ((size_t)((i * 8 + b) * 384 + t * 192 + l * 64)) * 6000
                 + (size_t)n0 * 12;

    #pragma unroll
    for (int half = 0; half < 2; ++half) {
        #pragma unroll
        for (int nn2 = 0; nn2 < 2; ++nn2) {
            int pl = g6 * 2 + nn2;
            int nl = half * 12 + pl;
            #pragma unroll
            for (int tt0 = 0; tt0 < 12; tt0 += 4) {
                const uint* __restrict__ Xm0 = Xbase + (size_t)(tt0 + 0) * 16000;
                const uint* __restrict__ Xm1 = Xbase + (size_t)(tt0 + 1) * 16000;
                const uint* __restrict__ Xm2 = Xbase + (size_t)(tt0 + 2) * 16000;
                const uint* __restrict__ Xm3 = Xbase + (size_t)(tt0 + 3) * 16000;
                float a0l = 0.f, a0h = 0.f, a1l = 0.f, a1h = 0.f;
                float a2l = 0.f, a2h = 0.f, a3l = 0.f, a3h = 0.f;
                #pragma unroll
                for (int k = 0; k < K_; ++k) {
                    size_t off = (size_t)nb_s[nl][k] * 32;
                    float w = w_s[nl][k];
                    uint u0 = Xm0[off], u1 = Xm1[off], u2 = Xm2[off], u3 = Xm3[off];
                    a0l = fmaf(__uint_as_float(u0 << 16), w, a0l);
                    a0h = fmaf(__uint_as_float(u0 & 0xffff0000u), w, a0h);
                    a1l = fmaf(__uint_as_float(u1 << 16), w, a1l);
                    a1h = fmaf(__uint_as_float(u1 & 0xffff0000u), w, a1h);
                    a2l = fmaf(__uint_as_float(u2 << 16), w, a2l);
                    a2h = fmaf(__uint_as_float(u2 & 0xffff0000u), w, a2h);
                    a3l = fmaf(__uint_as_float(u3 << 16), w, a3l);
                    a3h = fmaf(__uint_as_float(u3 & 0xffff0000u), w, a3h);
                }
                int p = pl * 12 + tt0;
                staged[2 * d2 + 0][p + 0] = to_bf16u(a0l);  staged[2 * d2 + 1][p + 0] = to_bf16u(a0h);
                staged[2 * d2 + 0][p + 1] = to_bf16u(a1l);  staged[2 * d2 + 1][p + 1] = to_bf16u(a1h);
                staged[2 * d2 + 0][p + 2] = to_bf16u(a2l);  staged[2 * d2 + 1][p + 2] = to_bf16u(a2h);
                staged[2 * d2 + 0][p + 3] = to_bf16u(a3l);  staged[2 * d2 + 1][p + 3] = to_bf16u(a3h);
            }
        }
        __syncthreads();
        int base_n = n0 + half * 12;
        int plim = (N_ - base_n) * 12;
        if (plim > 144) plim = 144;
        if (plim > 0) {
            for (int it = 0; it < 48; ++it) {
                int e = it * 192 + tid;
                int c2 = e / 144, q = e % 144;
                if (q < plim)
                    out[obase + (size_t)c2 * 6000 + (size_t)half * 144 + q] =
                        __uint_as_float((uint)staged[c2][q] << 16);
            }
        }
        __syncthreads();
    }
}

extern "C" void kernel_launch(void* const* d_in, const int* in_sizes, int n_in,
                              void* d_out, int out_size, void* d_ws, size_t ws_size,
                              hipStream_t stream) {
    const float* x0     = (const float*)d_in[0];
    const float* x1     = (const float*)d_in[1];
    const float* graphs = (const float*)d_in[2];
    const int*   nbr    = (const int*)d_in[3];
    const float* nwt    = (const float*)d_in[4];
    const float* aw     = (const float*)d_in[5];
    const float* Bw     = (const float*)d_in[6];
    const float* ab     = (const float*)d_in[7];
    const float* Bb     = (const float*)d_in[8];
    float* out = (float*)d_out;
    float* ws  = (float*)d_ws;

    ushort* XSB = (ushort*)(ws + XSB_OFF);
    ushort* XTb = (ushort*)(ws + XTB_OFF);
    ushort* ATh = (ushort*)(ws + AT_HI_OFF);
    ushort* XTa = (ushort*)(ws + XT_OFF);
    ushort* WCT = (ushort*)(ws + WCT_OFF);
    ushort* WDT = (ushort*)(ws + WDT_OFF);
    float*  BC  = ws + BC_OFF;
    float*  BD  = ws + BD_OFF;

    fuse_weights<<<520, 256, 0, stream>>>(aw, Bw, ab, Bb, BC, BD, WCT, WDT);
    transpose_in<<<8000, 256, 0, stream>>>(x0, x1, XSB);
    adj_prep<<<dim3(16, 16, 2), 256, 0, stream>>>(graphs, ATh);
    xt_cast<<<dim3(8, 96, 2), 256, 0, stream>>>(XSB, XTa);
    agg_combine_mfma<<<dim3(8, 96), 256, 0, stream>>>(
        ATh, XTa, WCT, WDT, BC, BD, XSB + 2ul * MND_, XTb, 0, 1);
    agg_combine_mfma<<<dim3(8, 96), 256, 0, stream>>>(
        ATh, XTb, WCT, WDT, BC, BD, XSB + 4ul * MND_, XTb, 1, 0);
    summarize<<<2016, 192, 0, stream>>>(XSB, nbr, nwt, out);
}